// Round 13
// baseline (1658.778 us; speedup 1.0000x reference)
//
#include <hip/hip_runtime.h>
#include <math.h>

#define CH 24

typedef __attribute__((ext_vector_type(8))) short short8v;
typedef __attribute__((ext_vector_type(4))) float f32x4;
typedef unsigned short ushort_t;
typedef unsigned int uint_t;

__device__ inline ushort_t bf16r(float f){
  uint_t u = __float_as_uint(f);
  u += 0x7FFF + ((u>>16)&1);
  return (ushort_t)(u>>16);
}

// ================= weight reorder kernels =================
__global__ void k_r_res(const float* __restrict__ w, float* __restrict__ wT, int K){
  int i = blockIdx.x*256 + threadIdx.x;
  int n = 576*K*K; if (i >= n) return;
  int co = i % 24, ci = (i/24) % 24, kk = i/576;
  int ky = kk / K, kx = kk % K;
  wT[i] = w[((co*24+ci)*K+ky)*K+kx];
}
__global__ void k_r_pw(const float* __restrict__ w, float* __restrict__ wT, int CIN){
  int i = blockIdx.x*256 + threadIdx.x;
  if (i >= CIN*24) return;
  int co = i % 24, ci = i/24;
  wT[i] = w[co*CIN+ci];
}
// MFMA-ready bf16 B-frags (OIHW source): wb[tap*1024 + t*512 + l*8 + j] = W[ci][co]
__global__ void k_rmfma(const float* __restrict__ w, ushort_t* __restrict__ wb, int K){
  int i = blockIdx.x*256 + threadIdx.x;
  int n = K*K*1024; if (i >= n) return;
  int j = i & 7, l = (i>>3) & 63, t = (i>>9) & 1, tap = i >> 10;
  int ci = (l>>4)*8 + j, co = t*16 + (l&15);
  int ky = tap / K, kx = tap % K;
  float v = (ci<24 && co<24) ? w[((co*24+ci)*K+ky)*K+kx] : 0.f;
  wb[i] = bf16r(v);
}
// MFMA-ready bf16 B-frags for convT (torch [in][out][4][4] source), 16 taps
__global__ void k_rmfma4(const float* __restrict__ w, ushort_t* __restrict__ wb){
  int i = blockIdx.x*256 + threadIdx.x;
  if (i >= 16384) return;
  int j = i & 7, l = (i>>3) & 63, t = (i>>9) & 1, tap = i >> 10;
  int ci = (l>>4)*8 + j, co = t*16 + (l&15);
  int ky = tap >> 2, kx = tap & 3;
  float v = (ci<24 && co<24) ? w[((ci*24+co)*4+ky)*4+kx] : 0.f;
  wb[i] = bf16r(v);
}

// ================= compute kernels =================

__global__ void k_lap(const float* __restrict__ x, float* __restrict__ xl, int H, int W){
  int idx = blockIdx.x*256 + threadIdx.x;
  int HW = H*W;
  if (idx >= HW) return;
  const float* xb = x + (size_t)blockIdx.z*3*HW;
  float* xo = xl + (size_t)blockIdx.z*HW;
  int px = idx % W, py = idx / W;
#define MEANV(yy,xx) (((yy)>=0&&(yy)<H&&(xx)>=0&&(xx)<W) ? (xb[(yy)*W+(xx)]+xb[HW+(yy)*W+(xx)]+xb[2*HW+(yy)*W+(xx)])*(1.f/3.f) : 0.f)
  float v = 4.f*MEANV(py,px) - MEANV(py-1,px) - MEANV(py+1,px) - MEANV(py,px-1) - MEANV(py,px+1);
#undef MEANV
  xo[idx] = v;
}

// ---------- MFMA KxK conv 24->24 (pad K/2) FUSED with 1x1 pw conv + mean/max maps ----------
// 48B records (24 real channels, 3x16B chunks). kg=3 lanes (zero B-weights) alias kg=2's
// address -> broadcast, free. 16B-aligned ds_read_b128/ds_write_b128, linear offsets.
template<int K, bool EXPAND>
__launch_bounds__(512)
__global__ void k_conv_mfma(const float* __restrict__ in, const ushort_t* __restrict__ wb,
                            const ushort_t* __restrict__ wbpw, const float* __restrict__ wexp,
                            float* __restrict__ out, float* __restrict__ mm,
                            int H, int W, int istrIn, int istrOut, int istrMM){
  constexpr int SW_T = 32 + K - 1;
  constexpr int SH = 16 + K - 1;
  constexpr int NPX = SH*SW_T;
  __shared__ ushort_t lds[NPX*24];
  __shared__ uint_t sc[8][16*20];
  int tid = threadIdx.x;
  const float* inb = in + (size_t)blockIdx.z*istrIn;
  int x0g = blockIdx.x*32 - K/2, y0g = blockIdx.y*16 - K/2;
  int HW = H*W;
  for (int i = tid; i < NPX*3; i += 512){
    int q = i / NPX;                 // 16B chunk: channels 8q..8q+7
    int pp = i - q*NPX;
    int row = pp / SW_T, col = pp - row*SW_T;
    int gy = y0g + row, gx = x0g + col;
    uint4 w4; w4.x=0u; w4.y=0u; w4.z=0u; w4.w=0u;
    if (gy >= 0 && gy < H && gx >= 0 && gx < W){
      size_t base = (size_t)gy*W + gx;
      int c0 = q*8;
      if (EXPAND){
        float val = inb[base];
        w4.x = (uint_t)bf16r(val*wexp[c0+0]) | ((uint_t)bf16r(val*wexp[c0+1])<<16);
        w4.y = (uint_t)bf16r(val*wexp[c0+2]) | ((uint_t)bf16r(val*wexp[c0+3])<<16);
        w4.z = (uint_t)bf16r(val*wexp[c0+4]) | ((uint_t)bf16r(val*wexp[c0+5])<<16);
        w4.w = (uint_t)bf16r(val*wexp[c0+6]) | ((uint_t)bf16r(val*wexp[c0+7])<<16);
      } else {
        w4.x = (uint_t)bf16r(inb[(size_t)(c0+0)*HW+base]) | ((uint_t)bf16r(inb[(size_t)(c0+1)*HW+base])<<16);
        w4.y = (uint_t)bf16r(inb[(size_t)(c0+2)*HW+base]) | ((uint_t)bf16r(inb[(size_t)(c0+3)*HW+base])<<16);
        w4.z = (uint_t)bf16r(inb[(size_t)(c0+4)*HW+base]) | ((uint_t)bf16r(inb[(size_t)(c0+5)*HW+base])<<16);
        w4.w = (uint_t)bf16r(inb[(size_t)(c0+6)*HW+base]) | ((uint_t)bf16r(inb[(size_t)(c0+7)*HW+base])<<16);
      }
    }
    *(uint4*)(lds + (size_t)pp*24 + q*8) = w4;
  }
  __syncthreads();
  int l = tid & 63, wid = tid >> 6;
  int kg = l >> 4, li = l & 15;
  int kgc = (kg < 3) ? kg : 2;      // kg=3 -> zero B-weights; alias kg=2 addr (broadcast)
  f32x4 zero = {0.f,0.f,0.f,0.f};
  f32x4 acc[4][2];
  #pragma unroll
  for (int i=0;i<4;i++){ acc[i][0]=zero; acc[i][1]=zero; }

  const ushort_t* aln = lds + li*24 + kgc*8 + (size_t)wid*SW_T*24;

  #pragma unroll
  for (int ky=0; ky<K; ky++){
    #pragma unroll
    for (int kx=0; kx<K; kx++){
      int tap = ky*K + kx;
      const ushort_t* wp = wb + (size_t)tap*1024;
      short8v b0 = *(const short8v*)(wp + l*8);
      short8v b1 = *(const short8v*)(wp + 512 + l*8);
      #pragma unroll
      for (int i=0;i<4;i++){
        const ushort_t* ap = aln + (((i&1)*8 + ky)*SW_T + (i>>1)*16 + kx)*24;
        short8v a = *(const short8v*)ap;
        acc[i][0] = __builtin_amdgcn_mfma_f32_16x16x32_bf16(a, b0, acc[i][0], 0, 0, 0);
        acc[i][1] = __builtin_amdgcn_mfma_f32_16x16x32_bf16(a, b1, acc[i][1], 0, 0, 0);
      }
    }
  }
  // ---- stage 2: pw 1x1 via second MFMA, + mean/max ----
  short8v bpw0 = *(const short8v*)(wbpw + l*8);
  short8v bpw1 = *(const short8v*)(wbpw + 512 + l*8);
  uint_t* s = sc[wid];
  float* outb = out + (size_t)blockIdx.z*istrOut;
  float* mmb = mm + (size_t)blockIdx.z*istrMM;
  #pragma unroll 1
  for (int i=0;i<4;i++){
    __asm__ volatile("s_waitcnt lgkmcnt(0)" ::: "memory");
    __builtin_amdgcn_sched_barrier(0);
    #pragma unroll
    for (int reg=0; reg<4; reg++){
      float v0 = acc[i][0][reg], v1 = acc[i][1][reg];
      float v0n = __shfl_xor(v0, 1, 64);
      float v1n = __shfl_xor(v1, 1, 64);
      int pxr = kg*4 + reg;
      uint_t packed; int uidx;
      if ((li & 1) == 0){
        packed = (uint_t)bf16r(v0) | ((uint_t)bf16r(v0n) << 16);
        uidx = li >> 1;
      } else {
        packed = (uint_t)bf16r(v1n) | ((uint_t)bf16r(v1) << 16);
        uidx = 8 + (li >> 1);
      }
      s[pxr*20 + uidx] = packed;
    }
    __asm__ volatile("s_waitcnt lgkmcnt(0)" ::: "memory");
    __builtin_amdgcn_sched_barrier(0);
    short8v a2 = *(const short8v*)((const ushort_t*)s + li*40 + kg*8);
    f32x4 d0 = __builtin_amdgcn_mfma_f32_16x16x32_bf16(a2, bpw0, zero, 0, 0, 0);
    f32x4 d1 = __builtin_amdgcn_mfma_f32_16x16x32_bf16(a2, bpw1, zero, 0, 0, 0);
    int gy = blockIdx.y*16 + wid + (i&1)*8;
    int gx = blockIdx.x*32 + (i>>1)*16 + kg*4;
    float* o0 = outb + (size_t)li*HW + (size_t)gy*W + gx;
    *(f32x4*)o0 = d0;
    if (li < 8){
      float* o1 = outb + (size_t)(16+li)*HW + (size_t)gy*W + gx;
      *(f32x4*)o1 = d1;
    }
    f32x4 sm, mx;
    #pragma unroll
    for (int reg=0; reg<4; reg++){
      sm[reg] = d0[reg] + d1[reg];
      mx[reg] = fmaxf(d0[reg], (li<8) ? d1[reg] : -3.4e38f);
    }
    #pragma unroll
    for (int m=1; m<16; m<<=1){
      #pragma unroll
      for (int reg=0; reg<4; reg++){
        sm[reg] += __shfl_xor(sm[reg], m, 64);
        mx[reg] = fmaxf(mx[reg], __shfl_xor(mx[reg], m, 64));
      }
    }
    if (li == 0){
      f32x4 me; me[0]=sm[0]*(1.f/24.f); me[1]=sm[1]*(1.f/24.f); me[2]=sm[2]*(1.f/24.f); me[3]=sm[3]*(1.f/24.f);
      *(f32x4*)(mmb + (size_t)gy*W + gx) = me;
      *(f32x4*)(mmb + (size_t)HW + (size_t)gy*W + gx) = mx;
    }
  }
}

// ---------- MFMA ConvTranspose2d(k=4,s=2,p=1), 32x16 output tile, 8 waves ----------
__launch_bounds__(512)
__global__ void k_convT_mfma(const float* __restrict__ in, const ushort_t* __restrict__ wb,
                             float* __restrict__ out, int Ho, int Wo, int istrIn, int istrOut){
  const int Hi = Ho>>1, Wi = Wo>>1;
  constexpr int SW_T = 18, NPX = 180;
  __shared__ ushort_t lds[NPX*24];
  int tid = threadIdx.x;
  const float* inb = in + (size_t)blockIdx.z*istrIn;
  int X0 = blockIdx.x*32, Y0 = blockIdx.y*16;
  int ix0 = (X0>>1) - 1, iy0 = (Y0>>1) - 1;
  int HWi = Hi*Wi;
  for (int i = tid; i < NPX*3; i += 512){
    int q = i / NPX;
    int pp = i - q*NPX;
    int row = pp / SW_T, col = pp - row*SW_T;
    int gy = iy0 + row, gx = ix0 + col;
    uint4 w4; w4.x=0u; w4.y=0u; w4.z=0u; w4.w=0u;
    if (gy>=0 && gy<Hi && gx>=0 && gx<Wi){
      size_t base = (size_t)gy*Wi + gx;
      int c0 = q*8;
      w4.x = (uint_t)bf16r(inb[(size_t)(c0+0)*HWi+base]) | ((uint_t)bf16r(inb[(size_t)(c0+1)*HWi+base])<<16);
      w4.y = (uint_t)bf16r(inb[(size_t)(c0+2)*HWi+base]) | ((uint_t)bf16r(inb[(size_t)(c0+3)*HWi+base])<<16);
      w4.z = (uint_t)bf16r(inb[(size_t)(c0+4)*HWi+base]) | ((uint_t)bf16r(inb[(size_t)(c0+5)*HWi+base])<<16);
      w4.w = (uint_t)bf16r(inb[(size_t)(c0+6)*HWi+base]) | ((uint_t)bf16r(inb[(size_t)(c0+7)*HWi+base])<<16);
    }
    *(uint4*)(lds + (size_t)pp*24 + q*8) = w4;
  }
  __syncthreads();
  int l = tid & 63, wid = tid >> 6;
  int kg = l >> 4, li = l & 15;
  int kgc = (kg < 3) ? kg : 2;
  f32x4 zero = {0.f,0.f,0.f,0.f};
  f32x4 acc[4][2];
  #pragma unroll
  for (int i=0;i<4;i++){ acc[i][0]=zero; acc[i][1]=zero; }

  const ushort_t* aln = lds + li*24 + kgc*8;

  #pragma unroll
  for (int i=0;i<4;i++){
    int g = wid + 8*i;
    int r = g & 15, q = g >> 4;
    int ky0 = (r+1)&1;
    #pragma unroll
    for (int t2=0;t2<2;t2++){
      int ky = ky0 + 2*t2;
      int liy = ((r+1-ky)>>1) + 1;
      #pragma unroll
      for (int u=0;u<2;u++){
        int kx = (q ? 0 : 1) + 2*u;
        int lixb = ((q+1-kx)>>1) + 1;
        int tap = ky*4 + kx;
        const ushort_t* wp = wb + (size_t)tap*1024;
        short8v b0 = *(const short8v*)(wp + l*8);
        short8v b1 = *(const short8v*)(wp + 512 + l*8);
        short8v a = *(const short8v*)(aln + (liy*SW_T + lixb)*24);
        acc[i][0] = __builtin_amdgcn_mfma_f32_16x16x32_bf16(a, b0, acc[i][0], 0, 0, 0);
        acc[i][1] = __builtin_amdgcn_mfma_f32_16x16x32_bf16(a, b1, acc[i][1], 0, 0, 0);
      }
    }
  }
  float* outb = out + (size_t)blockIdx.z*istrOut;
  int HWo = Ho*Wo;
  #pragma unroll
  for (int i=0;i<4;i++){
    int g = wid + 8*i;
    int r = g & 15, q = g >> 4;
    int oy = Y0 + r;
    #pragma unroll
    for (int reg=0; reg<4; reg++){
      int ox = X0 + 2*(kg*4 + reg) + q;
      outb[(size_t)li*HWo + (size_t)oy*Wo + ox] = acc[i][0][reg];
      if (li < 8)
        outb[(size_t)(16+li)*HWo + (size_t)oy*Wo + ox] = acc[i][1][reg];
    }
  }
}

// ---------- MFMA 4x4 s2 p1 downsample, 16x8 output tile, parity-deinterleaved halo ----------
__launch_bounds__(512)
__global__ void k_down_mfma(const float* __restrict__ in, const ushort_t* __restrict__ wb,
                            float* __restrict__ out, int Ho, int Wo, int istrIn, int istrOut){
  const int Hi = Ho*2, Wi = Wo*2;
  constexpr int NPX = 18*34;
  __shared__ ushort_t lds[NPX*24];
  int tid = threadIdx.x;
  const float* inb = in + (size_t)blockIdx.z*istrIn;
  int X0 = blockIdx.x*16, Y0 = blockIdx.y*8;
  int ix0 = 2*X0 - 1, iy0 = 2*Y0 - 1;
  int HWi = Hi*Wi;
  for (int i = tid; i < NPX*3; i += 512){
    int q = i / NPX;
    int pp = i - q*NPX;
    int row = pp / 34;
    int rem = pp - row*34;
    int par = (rem >= 17) ? 1 : 0;
    int sub = rem - par*17;
    int gx = ix0 + 2*sub + par;
    int gy = iy0 + row;
    uint4 w4; w4.x=0u; w4.y=0u; w4.z=0u; w4.w=0u;
    if (gy>=0 && gy<Hi && gx>=0 && gx<Wi){
      size_t base = (size_t)gy*Wi + gx;
      int c0 = q*8;
      w4.x = (uint_t)bf16r(inb[(size_t)(c0+0)*HWi+base]) | ((uint_t)bf16r(inb[(size_t)(c0+1)*HWi+base])<<16);
      w4.y = (uint_t)bf16r(inb[(size_t)(c0+2)*HWi+base]) | ((uint_t)bf16r(inb[(size_t)(c0+3)*HWi+base])<<16);
      w4.z = (uint_t)bf16r(inb[(size_t)(c0+4)*HWi+base]) | ((uint_t)bf16r(inb[(size_t)(c0+5)*HWi+base])<<16);
      w4.w = (uint_t)bf16r(inb[(size_t)(c0+6)*HWi+base]) | ((uint_t)bf16r(inb[(size_t)(c0+7)*HWi+base])<<16);
    }
    *(uint4*)(lds + (size_t)pp*24 + q*8) = w4;
  }
  __syncthreads();
  int l = tid & 63, wid = tid >> 6;
  int kg = l >> 4, li = l & 15;
  int kgc = (kg < 3) ? kg : 2;
  f32x4 zero = {0.f,0.f,0.f,0.f};
  f32x4 acc0 = zero, acc1 = zero;
  const ushort_t* aln = lds + li*24 + kgc*8 + (size_t)(2*wid)*34*24;
  #pragma unroll
  for (int ky=0; ky<4; ky++){
    #pragma unroll
    for (int kx=0; kx<4; kx++){
      int tap = ky*4 + kx;
      const ushort_t* wp = wb + (size_t)tap*1024;
      short8v b0 = *(const short8v*)(wp + l*8);
      short8v b1 = *(const short8v*)(wp + 512 + l*8);
      short8v a = *(const short8v*)(aln + (ky*34 + (kx&1)*17 + (kx>>1))*24);
      acc0 = __builtin_amdgcn_mfma_f32_16x16x32_bf16(a, b0, acc0, 0, 0, 0);
      acc1 = __builtin_amdgcn_mfma_f32_16x16x32_bf16(a, b1, acc1, 0, 0, 0);
    }
  }
  int HWo = Ho*Wo;
  float* outb = out + (size_t)blockIdx.z*istrOut;
  int oy = Y0 + wid, ox = X0 + kg*4;
  float* o0 = outb + (size_t)li*HWo + (size_t)oy*Wo + ox;
  *(f32x4*)o0 = acc0;
  if (li < 8){
    float* o1 = outb + (size_t)(16+li)*HWo + (size_t)oy*Wo + ox;
    *(f32x4*)o1 = acc1;
  }
}

// KxK conv fp32 (K=3 @128). wT=[ky][kx][ci][co]. Tile 32 x TH.
template<int K, int TH>
__launch_bounds__(256)
__global__ void k_conv(const float* __restrict__ in, const float* __restrict__ wT,
                       float* __restrict__ out, int H, int W, int istrIn, int istrOut){
  constexpr int TW = 32;
  constexpr int PX = (TW*TH)/256;
  constexpr int XT = TW/PX;
  constexpr int SW = TW + K - 1;
  constexpr int SWP = SW | 1;
  constexpr int SH = TH + K - 1;
  constexpr int CC = 8;
  __shared__ float tile[CC*SH*SWP];
  int tx = threadIdx.x % XT, ty = threadIdx.x / XT;
  int x0 = blockIdx.x*TW - K/2, y0 = blockIdx.y*TH - K/2;
  const float* inb = in + (size_t)blockIdx.z*istrIn;
  float acc[CH][PX];
  #pragma unroll
  for (int co=0;co<CH;co++)
    #pragma unroll
    for (int px=0;px<PX;px++) acc[co][px] = 0.f;

  #pragma unroll 1
  for (int c0=0;c0<CH;c0+=CC){
    __syncthreads();
    for (int i=threadIdx.x; i<CC*SH*SW; i+=256){
      int col = i % SW; int rr = i / SW; int row = rr % SH; int c = rr / SH;
      int gy = y0+row, gx = x0+col;
      tile[(c*SH+row)*SWP+col] = (gy>=0 && gy<H && gx>=0 && gx<W)
          ? inb[(size_t)(c0+c)*H*W + (size_t)gy*W + gx] : 0.f;
    }
    __syncthreads();
    #pragma unroll 1
    for (int ci=0;ci<CC;ci++){
      #pragma unroll 1
      for (int ky=0;ky<K;ky++){
        const float* trow = &tile[(ci*SH + ty+ky)*SWP + tx*PX];
        #pragma unroll
        for (int kx=0;kx<K;kx++){
          float v[PX];
          #pragma unroll
          for (int px=0;px<PX;px++) v[px] = trow[kx+px];
          const float* wp = wT + ((ky*K+kx)*24 + c0+ci)*24;
          #pragma unroll
          for (int co=0;co<CH;co++){
            float wv = wp[co];
            #pragma unroll
            for (int px=0;px<PX;px++) acc[co][px] = fmaf(v[px], wv, acc[co][px]);
          }
        }
      }
    }
  }
  int oy = blockIdx.y*TH+ty, ox = blockIdx.x*TW+tx*PX;
  float* ob = out + (size_t)blockIdx.z*istrOut + (size_t)oy*W + ox;
  #pragma unroll
  for (int co=0;co<CH;co++){
    if (PX == 2){
      float2 o; o.x=acc[co][0]; o.y=acc[co][1];
      *(float2*)(ob + (size_t)co*H*W) = o;
    } else {
      ob[(size_t)co*H*W] = acc[co][0];
    }
  }
}

__global__ void k_pw(const float* in, const float* __restrict__ wT,
                     float* out, float* __restrict__ mm, int HW, int istr, int istrMM){
  int p = (blockIdx.x*256 + threadIdx.x)*4;
  if (p >= HW) return;
  const float* ib = in + (size_t)blockIdx.z*istr;
  float acc[CH][4];
  #pragma unroll
  for (int co=0;co<CH;co++){ acc[co][0]=0;acc[co][1]=0;acc[co][2]=0;acc[co][3]=0; }
  #pragma unroll 1
  for (int ci=0;ci<CH;ci++){
    float4 v = *(const float4*)(ib + (size_t)ci*HW + p);
    const float* wp = wT + ci*24;
    #pragma unroll
    for (int co=0;co<CH;co++){
      float wv = wp[co];
      acc[co][0] = fmaf(v.x, wv, acc[co][0]);
      acc[co][1] = fmaf(v.y, wv, acc[co][1]);
      acc[co][2] = fmaf(v.z, wv, acc[co][2]);
      acc[co][3] = fmaf(v.w, wv, acc[co][3]);
    }
  }
  float mean[4]={0,0,0,0}, mx[4]={-3.4e38f,-3.4e38f,-3.4e38f,-3.4e38f};
  #pragma unroll
  for (int co=0;co<CH;co++)
    #pragma unroll
    for (int j=0;j<4;j++){ mean[j]+=acc[co][j]; mx[j]=fmaxf(mx[j],acc[co][j]); }
  float* ob = out + (size_t)blockIdx.z*istr;
  #pragma unroll
  for (int co=0;co<CH;co++){
    float4 o; o.x=acc[co][0]; o.y=acc[co][1]; o.z=acc[co][2]; o.w=acc[co][3];
    *(float4*)(ob + (size_t)co*HW + p) = o;
  }
  float* mb = mm + (size_t)blockIdx.z*istrMM;
  float4 me; me.x=mean[0]*(1.f/24.f); me.y=mean[1]*(1.f/24.f); me.z=mean[2]*(1.f/24.f); me.w=mean[3]*(1.f/24.f);
  float4 mxo; mxo.x=mx[0]; mxo.y=mx[1]; mxo.z=mx[2]; mxo.w=mx[3];
  *(float4*)(mb + p) = me;
  *(float4*)(mb + HW + p) = mxo;
}

__global__ void k_attn_res(const float* __restrict__ R, const float* __restrict__ M,
                           const float* X, const float* __restrict__ wsa,
                           float* out, int H, int W, int istr, int istrMM){
  int p = (blockIdx.x*256 + threadIdx.x)*4;
  int HW = H*W;
  if (p >= HW) return;
  int py = p / W, px0 = p % W;
  const float* Mb = M + (size_t)blockIdx.z*istrMM;
  float s[4]={0,0,0,0};
  #pragma unroll
  for (int cc=0;cc<2;cc++){
    const float* Mc = Mb + (size_t)cc*HW;
    #pragma unroll 1
    for (int ky=0;ky<7;ky++){
      int gy = py+ky-3;
      if (gy<0||gy>=H) continue;
      const float* mr = Mc + (size_t)gy*W;
      float mv[10];
      #pragma unroll
      for (int j=0;j<10;j++){
        int gx = px0-3+j;
        mv[j] = (gx>=0 && gx<W) ? mr[gx] : 0.f;
      }
      const float* wr = wsa + (cc*7+ky)*7;
      #pragma unroll
      for (int kx=0;kx<7;kx++){
        float wv = wr[kx];
        #pragma unroll
        for (int px=0;px<4;px++) s[px] = fmaf(mv[kx+px], wv, s[px]);
      }
    }
  }
  float g[4];
  #pragma unroll
  for (int px=0;px<4;px++) g[px] = 1.f/(1.f+expf(-s[px]));
  const float* Rb = R + (size_t)blockIdx.z*istr;
  const float* Xb = X + (size_t)blockIdx.z*istr;
  float* Ob = out + (size_t)blockIdx.z*istr;
  #pragma unroll
  for (int c=0;c<CH;c++){
    float4 r = *(const float4*)(Rb + (size_t)c*HW + p);
    float4 xv = *(const float4*)(Xb + (size_t)c*HW + p);
    float4 o;
    o.x = xv.x + fmaxf(r.x*g[0], 0.f);
    o.y = xv.y + fmaxf(r.y*g[1], 0.f);
    o.z = xv.z + fmaxf(r.z*g[2], 0.f);
    o.w = xv.w + fmaxf(r.w*g[3], 0.f);
    *(float4*)(Ob + (size_t)c*HW + p) = o;
  }
}

__global__ void k_attn_res_x(const float* __restrict__ R, const float* __restrict__ M,
                             const float* __restrict__ XL, const float* __restrict__ wsa,
                             const float* __restrict__ wexp,
                             float* __restrict__ out, int H, int W, int istr, int istrMM){
  int p = (blockIdx.x*256 + threadIdx.x)*4;
  int HW = H*W;
  if (p >= HW) return;
  int py = p / W, px0 = p % W;
  const float* Mb = M + (size_t)blockIdx.z*istrMM;
  float s[4]={0,0,0,0};
  #pragma unroll
  for (int cc=0;cc<2;cc++){
    const float* Mc = Mb + (size_t)cc*HW;
    #pragma unroll 1
    for (int ky=0;ky<7;ky++){
      int gy = py+ky-3;
      if (gy<0||gy>=H) continue;
      const float* mr = Mc + (size_t)gy*W;
      float mv[10];
      #pragma unroll
      for (int j=0;j<10;j++){
        int gx = px0-3+j;
        mv[j] = (gx>=0 && gx<W) ? mr[gx] : 0.f;
      }
      const float* wr = wsa + (cc*7+ky)*7;
      #pragma unroll
      for (int kx=0;kx<7;kx++){
        float wv = wr[kx];
        #pragma unroll
        for (int px=0;px<4;px++) s[px] = fmaf(mv[kx+px], wv, s[px]);
      }
    }
  }
  float g[4];
  #pragma unroll
  for (int px=0;px<4;px++) g[px] = 1.f/(1.f+expf(-s[px]));
  float4 xl4 = *(const float4*)(XL + (size_t)blockIdx.z*HW + p);
  const float* Rb = R + (size_t)blockIdx.z*istr;
  float* Ob = out + (size_t)blockIdx.z*istr;
  #pragma unroll
  for (int c=0;c<CH;c++){
    float wc = wexp[c];
    float4 r = *(const float4*)(Rb + (size_t)c*HW + p);
    float4 o;
    o.x = xl4.x*wc + fmaxf(r.x*g[0], 0.f);
    o.y = xl4.y*wc + fmaxf(r.y*g[1], 0.f);
    o.z = xl4.z*wc + fmaxf(r.z*g[2], 0.f);
    o.w = xl4.w*wc + fmaxf(r.w*g[3], 0.f);
    *(float4*)(Ob + (size_t)c*HW + p) = o;
  }
}

__global__ void k_squeeze(const float* __restrict__ inA, const float* inB,
                          const float* __restrict__ wT, float* out, int HW, int istr){
  int p = (blockIdx.x*256 + threadIdx.x)*4;
  if (p >= HW) return;
  const float* Ab = inA + (size_t)blockIdx.z*istr;
  const float* Bb = inB + (size_t)blockIdx.z*istr;
  float acc[CH][4];
  #pragma unroll
  for (int co=0;co<CH;co++){ acc[co][0]=0;acc[co][1]=0;acc[co][2]=0;acc[co][3]=0; }
  #pragma unroll 1
  for (int ci=0;ci<48;ci++){
    const float* src = (ci<24) ? (Ab + (size_t)ci*HW) : (Bb + (size_t)(ci-24)*HW);
    float4 v = *(const float4*)(src + p);
    const float* wp = wT + ci*24;
    #pragma unroll
    for (int co=0;co<CH;co++){
      float wv = wp[co];
      acc[co][0] = fmaf(v.x, wv, acc[co][0]);
      acc[co][1] = fmaf(v.y, wv, acc[co][1]);
      acc[co][2] = fmaf(v.z, wv, acc[co][2]);
      acc[co][3] = fmaf(v.w, wv, acc[co][3]);
    }
  }
  float* ob = out + (size_t)blockIdx.z*istr;
  #pragma unroll
  for (int co=0;co<CH;co++){
    float4 o; o.x=acc[co][0]; o.y=acc[co][1]; o.z=acc[co][2]; o.w=acc[co][3];
    *(float4*)(ob + (size_t)co*HW + p) = o;
  }
}

__global__ void k_quant(const float* __restrict__ enc, const float* __restrict__ embed,
                        float* __restrict__ qt, float* __restrict__ diffAcc, int HW, int istr){
  __shared__ float em[256*28];
  __shared__ float red[4];
  {
    int j = threadIdx.x;
    float s = 0.f;
    #pragma unroll
    for (int c=0;c<CH;c++){
      float e = embed[c*256+j];
      em[j*28+c] = -2.0f*e;
      s = fmaf(e,e,s);
    }
    em[j*28+24] = s; em[j*28+25]=0.f; em[j*28+26]=0.f; em[j*28+27]=0.f;
  }
  __syncthreads();
  int p = blockIdx.x*256 + threadIdx.x;
  const float* eb = enc + (size_t)blockIdx.z*istr;
  float f[CH];
  #pragma unroll
  for (int c=0;c<CH;c++) f[c] = eb[(size_t)c*HW + p];
  float best = 3.4e38f; int bj = 0;
  #pragma unroll 1
  for (int j=0;j<256;j++){
    const float4* row = (const float4*)&em[j*28];
    float s = em[j*28+24];
    #pragma unroll
    for (int q4=0;q4<6;q4++){
      float4 r = row[q4];
      s = fmaf(f[q4*4+0], r.x, s);
      s = fmaf(f[q4*4+1], r.y, s);
      s = fmaf(f[q4*4+2], r.z, s);
      s = fmaf(f[q4*4+3], r.w, s);
    }
    if (s < best){ best = s; bj = j; }
  }
  float* qb = qt + (size_t)blockIdx.z*istr;
  float d = 0.f;
  #pragma unroll
  for (int c=0;c<CH;c++){
    float q = embed[c*256+bj];
    qb[(size_t)c*HW + p] = q;
    float e = q - f[c];
    d = fmaf(e,e,d);
  }
  #pragma unroll
  for (int off=32; off>0; off>>=1) d += __shfl_down(d, off, 64);
  int lane = threadIdx.x & 63, wv = threadIdx.x >> 6;
  if (lane==0) red[wv] = d;
  __syncthreads();
  if (threadIdx.x==0) atomicAdd(diffAcc, red[0]+red[1]+red[2]+red[3]);
}

__global__ void k_final(const float* __restrict__ dec1, const float* __restrict__ w,
                        const float* __restrict__ xl, float* __restrict__ outMask,
                        float* __restrict__ outClean, int HW, int dstr){
  int p = (blockIdx.x*256 + threadIdx.x)*4;
  if (p >= HW) return;
  const float* db = dec1 + (size_t)blockIdx.z*dstr;
  float m[4]={0,0,0,0};
  #pragma unroll
  for (int c=0;c<CH;c++){
    float4 d = *(const float4*)(db + (size_t)c*HW + p);
    float wc = w[c];
    m[0]=fmaf(d.x,wc,m[0]); m[1]=fmaf(d.y,wc,m[1]); m[2]=fmaf(d.z,wc,m[2]); m[3]=fmaf(d.w,wc,m[3]);
  }
  float4 xv = *(const float4*)(xl + (size_t)blockIdx.z*HW + p);
  float4 mo; mo.x=m[0]; mo.y=m[1]; mo.z=m[2]; mo.w=m[3];
  float4 co; co.x=xv.x-m[0]; co.y=xv.y-m[1]; co.z=xv.z-m[2]; co.w=xv.w-m[3];
  *(float4*)(outMask + (size_t)blockIdx.z*HW + p) = mo;
  *(float4*)(outClean + (size_t)blockIdx.z*HW + p) = co;
}

__global__ void k_diff(const float* __restrict__ acc, float* __restrict__ out){
  out[0] = acc[0]*(1.f/3145728.f) + acc[1]*(1.f/786432.f);
}

// =======================================================================
extern "C" void kernel_launch(void* const* d_in, const int* in_sizes, int n_in,
                              void* d_out, int out_size, void* d_ws, size_t ws_size,
                              hipStream_t stream) {
  const float* x        = (const float*)d_in[0];
  const float* embed2   = (const float*)d_in[1];
  const float* embed3   = (const float*)d_in[2];
  const float* w_img_in = (const float*)d_in[3];
  const float* w_img_out= (const float*)d_in[4];
  const float* w_out_dd = (const float*)d_in[5];
  const float* w_out_dm = (const float*)d_in[6];
  const float* w_out_dt = (const float*)d_in[7];
  const float* w_out_ed = (const float*)d_in[8];
  const float* w_out_em = (const float*)d_in[9];
  const float* w_out_et = (const float*)d_in[10];
  const float* w_pw_dd  = (const float*)d_in[11];
  const float* w_pw_dm  = (const float*)d_in[12];
  const float* w_pw_dt  = (const float*)d_in[13];
  const float* w_pw_ed  = (const float*)d_in[14];
  const float* w_pw_em  = (const float*)d_in[15];
  const float* w_pw_et  = (const float*)d_in[16];
  const float* w_res_dd = (const float*)d_in[17];
  const float* w_res_dm = (const float*)d_in[18];
  const float* w_res_dt = (const float*)d_in[19];
  const float* w_res_ed = (const float*)d_in[20];
  const float* w_res_em = (const float*)d_in[21];
  const float* w_res_et = (const float*)d_in[22];
  const float* w_sa_dd  = (const float*)d_in[23];
  const float* w_sa_dm  = (const float*)d_in[24];
  const float* w_sa_dt  = (const float*)d_in[25];
  const float* w_sa_ed  = (const float*)d_in[26];
  const float* w_sa_em  = (const float*)d_in[27];
  const float* w_sa_et  = (const float*)d_in[28];
  const float* w_squ1   = (const float*)d_in[29];
  const float* w_squ2   = (const float*)d_in[30];
  (void)in_sizes; (void)n_in; (void)out_size;

  const int HW512 = 512*512, HW256 = 256*256, HW128 = 128*128, HW64 = 64*64;
  const int S512 = 24*HW512, S256 = 24*HW256, S128 = 24*HW128, S64 = 24*HW64;

  float* ws = (float*)d_ws;
  float* OUT = (float*)d_out;
  size_t F = ws_size / sizeof(float);

  // fp32-reordered weights
  float* WT      = ws;
  float* wt_ed3  = WT + 85248;
  float* wt_dd3  = WT + 90432;
  float* wt_pw_ed= WT + 152064;
  float* wt_pw_dd= WT + 152640;
  float* wt_squ1 = WT + 154368;
  float* wt_squ2 = WT + 155520;

  // MFMA bf16 B-frag weights
  ushort_t* WB = (ushort_t*)(ws + 160000);
  ushort_t* wb_et7   = WB;
  ushort_t* wb_dt7   = WB + 50176;
  ushort_t* wb_em5   = WB + 100352;
  ushort_t* wb_dm5   = WB + 125952;
  ushort_t* wb_pw_et = WB + 151552;
  ushort_t* wb_pw_em = WB + 152576;
  ushort_t* wb_pw_dm = WB + 153600;
  ushort_t* wb_pw_dt = WB + 154624;
  ushort_t* wb4_dd   = WB + 155648;
  ushort_t* wb4_dm   = WB + 172032;
  ushort_t* wb4_dt   = WB + 188416;
  ushort_t* wb4d_et  = WB + 204800;
  ushort_t* wb4d_em  = WB + 221184;
  ushort_t* wb4d_ed  = WB + 237568;

  const size_t ABASE = 290000;

  auto needBatched = [&](size_t CB)->size_t{
    size_t u = (CB*(size_t)S512 > (size_t)8*S256) ? CB*(size_t)S512 : (size_t)8*S256;
    return ABASE + 2097152 + 12582912 + 3145728 + 786432 + CB*524288 + 2*u + 2;
  };
  int CB = 0;
  if (F >= needBatched(8)) CB = 8;
  else if (F >= needBatched(4)) CB = 4;
  else if (F >= needBatched(2)) CB = 2;
  const size_t NEED_B = ABASE + 15925250;
  if (CB == 0 && F < NEED_B) return;

  float *XL, *E1, *E2, *Q2, *E3, *Q3, *MM, *DIFF, *U1, *U2;
  if (CB > 0){
    size_t off = ABASE;
    size_t u = (CB*(size_t)S512 > (size_t)8*S256) ? CB*(size_t)S512 : (size_t)8*S256;
    XL = ws + off; off += 2097152;
    E1 = ws + off; off += 12582912;
    Q2 = ws + off; off += 3145728;
    Q3 = ws + off; off += 786432;
    MM = ws + off; off += CB*524288;
    U1 = ws + off; off += u;
    U2 = ws + off; off += u;
    DIFF = ws + off;
    E2 = OUT;
    E3 = OUT + 3145728;
  } else {
    size_t off = ABASE;
    XL = ws + off; off += 262144;
    U1 = ws + off; off += 6291456;
    U2 = ws + off; off += 6291456;
    E1 = ws + off; off += 1572864;
    E2 = ws + off; off += 393216;
    Q2 = ws + off; off += 393216;
    E3 = ws + off; off += 98304;
    Q3 = ws + off; off += 98304;
    MM = ws + off; off += 524288;
    DIFF = ws + off;
  }

  // ---- weight reorders ----
  k_rmfma<<<dim3(196), 256, 0, stream>>>(w_res_et, wb_et7, 7);
  k_rmfma<<<dim3(196), 256, 0, stream>>>(w_res_dt, wb_dt7, 7);
  k_rmfma<<<dim3(100), 256, 0, stream>>>(w_res_em, wb_em5, 5);
  k_rmfma<<<dim3(100), 256, 0, stream>>>(w_res_dm, wb_dm5, 5);
  k_rmfma<<<dim3(4), 256, 0, stream>>>(w_pw_et, wb_pw_et, 1);
  k_rmfma<<<dim3(4), 256, 0, stream>>>(w_pw_em, wb_pw_em, 1);
  k_rmfma<<<dim3(4), 256, 0, stream>>>(w_pw_dm, wb_pw_dm, 1);
  k_rmfma<<<dim3(4), 256, 0, stream>>>(w_pw_dt, wb_pw_dt, 1);
  k_rmfma4<<<dim3(64), 256, 0, stream>>>(w_out_dd, wb4_dd);
  k_rmfma4<<<dim3(64), 256, 0, stream>>>(w_out_dm, wb4_dm);
  k_rmfma4<<<dim3(64), 256, 0, stream>>>(w_out_dt, wb4_dt);
  k_rmfma<<<dim3(64), 256, 0, stream>>>(w_out_et, wb4d_et, 4);
  k_rmfma<<<dim3(64), 256, 0, stream>>>(w_out_em, wb4d_em, 4);
  k_rmfma<<<dim3(64), 256, 0, stream>>>(w_out_ed, wb4d_ed, 4);
  k_r_res<<<dim3((576*9+255)/256), 256, 0, stream>>>(w_res_ed, wt_ed3, 3);
  k_r_res<<<dim3((576*9+255)/256), 256, 0, stream>>>(w_res_dd, wt_dd3, 3);
  k_r_pw<<<dim3(3), 256, 0, stream>>>(w_pw_ed, wt_pw_ed, 24);
  k_r_pw<<<dim3(3), 256, 0, stream>>>(w_pw_dd, wt_pw_dd, 24);
  k_r_pw<<<dim3(5), 256, 0, stream>>>(w_squ1, wt_squ1, 48);
  k_r_pw<<<dim3(5), 256, 0, stream>>>(w_squ2, wt_squ2, 48);

  hipMemsetAsync(DIFF, 0, 2*sizeof(float), stream);

  // ---- phase 1: input -> enc1 ----
  auto phase1 = [&](int c0, int nz, float* XLp, float* E1p){
    k_lap<<<dim3(HW512/256,1,nz), 256, 0, stream>>>(x + (size_t)c0*3*HW512, XLp, 512, 512);
    k_conv_mfma<7,true><<<dim3(16,32,nz), 512, 0, stream>>>(XLp, wb_et7, wb_pw_et, w_img_in,
                                                            U2, MM, 512, 512, HW512, S512, 2*HW512);
    k_attn_res_x<<<dim3(HW512/1024,1,nz), 256, 0, stream>>>(U2, MM, XLp, w_sa_et, w_img_in,
                                                            U1, 512, 512, S512, 2*HW512);
    k_down_mfma<<<dim3(16,32,nz), 512, 0, stream>>>(U1, wb4d_et, E1p, 256, 256, S512, S256);
  };

  // ---- deep: enc1 -> squ1 output ----
  auto deep = [&](int nb, float* E1p, float* SAp, float* SBp, float* E2p, float* Q2p,
                  float* E3p, float* Q3p, float* MMp, float* D1p){
    int mm256 = 2*HW256, mm128 = 2*HW128;
    k_conv_mfma<5,false><<<dim3(8,16,nb), 512, 0, stream>>>(E1p, wb_em5, wb_pw_em, nullptr,
                                                            SAp, MMp, 256, 256, S256, S256, mm256);
    k_attn_res<<<dim3(HW256/1024,1,nb), 256, 0, stream>>>(SAp, MMp, E1p, w_sa_em, SBp, 256, 256, S256, mm256);
    k_down_mfma<<<dim3(8,16,nb), 512, 0, stream>>>(SBp, wb4d_em, E2p, 128, 128, S256, S128);
    k_conv<3,8><<<dim3(4,16,nb), 256, 0, stream>>>(E2p, wt_ed3, SAp, 128, 128, S128, S128);
    k_pw<<<dim3(HW128/1024,1,nb), 256, 0, stream>>>(SAp, wt_pw_ed, SAp, MMp, HW128, S128, mm128);
    k_attn_res<<<dim3(HW128/1024,1,nb), 256, 0, stream>>>(SAp, MMp, E2p, w_sa_ed, SBp, 128, 128, S128, mm128);
    k_down_mfma<<<dim3(4,8,nb), 512, 0, stream>>>(SBp, wb4d_ed, E3p, 64, 64, S128, S64);
    k_quant<<<dim3(HW128/256,1,nb), 256, 0, stream>>>(E2p, embed2, Q2p, DIFF+0, HW128, S128);
    k_quant<<<dim3(HW64/256,1,nb), 256, 0, stream>>>(E3p, embed3, Q3p, DIFF+1, HW64, S64);
    k_convT_mfma<<<dim3(4,8,nb), 512, 0, stream>>>(Q3p, wb4_dd, SAp, 128, 128, S64, S128);
    k_conv<3,8><<<dim3(4,16,nb), 256, 0, stream>>>(SAp, wt_dd3, SBp, 128, 128, S128, S128);
    k_pw<<<dim3(HW128/1024,1,nb), 256, 0, stream>>>(SBp, wt_pw_dd, SBp, MMp, HW128, S128, mm128);
    k_attn_res<<<dim3(HW128/1024,1,nb), 256, 0, stream>>>(SBp, MMp, SAp, w_sa_dd, SAp, 128, 128, S128, mm128);
    k_squeeze<<<dim3(HW128/1024,1,nb), 256, 0, stream>>>(SAp, Q2p, wt_squ2, SBp, HW128, S128);
    k_convT_mfma<<<dim3(8,16,nb), 512, 0, stream>>>(SBp, wb4_dm, SAp, 256, 256, S128, S256);
    k_conv_mfma<5,false><<<dim3(8,16,nb), 512, 0, stream>>>(SAp, wb_dm5, wb_pw_dm, nullptr,
                                                            SBp, MMp, 256, 256, S256, S256, mm256);
    k_attn_res<<<dim3(HW256/1024,1,nb), 256, 0, stream>>>(SBp, MMp, SAp, w_sa_dm, SAp, 256, 256, S256, mm256);
    k_squeeze<<<dim3(HW256/1024,1,nb), 256, 0, stream>>>(SAp, E1p, wt_squ1, D1p, HW256, S256);
  };

  // ---- phase 3: D1 -> outputs ----
  auto phase3 = [&](int c0, int nz, const float* D1p, const float* XLp){
    k_convT_mfma<<<dim3(16,32,nz), 512, 0, stream>>>(D1p, wb4_dt, U1, 512, 512, S256, S512);
    k_conv_mfma<7,false><<<dim3(16,32,nz), 512, 0, stream>>>(U1, wb_dt7, wb_pw_dt, nullptr,
                                                             U2, MM, 512, 512, S512, S512, 2*HW512);
    k_attn_res<<<dim3(HW512/1024,1,nz), 256, 0, stream>>>(U2, MM, U1, w_sa_dt, U1, 512, 512, S512, 2*HW512);
    k_final<<<dim3(HW512/1024,1,nz), 256, 0, stream>>>(U1, w_img_out, XLp,
                                                       OUT + (size_t)c0*HW512,
                                                       OUT + 2097152 + (size_t)c0*HW512,
                                                       HW512, S512);
  };

  if (CB > 0){
    for (int c0=0;c0<8;c0+=CB)
      phase1(c0, CB, XL + (size_t)c0*HW512, E1 + (size_t)c0*S256);
    deep(8, E1, U1, U2, E2, Q2, E3, Q3, MM, E1);
    for (int c0=0;c0<8;c0+=CB)
      phase3(c0, CB, E1 + (size_t)c0*S256, XL + (size_t)c0*HW512);
  } else {
    for (int b=0;b<8;b++){
      phase1(b, 1, XL, E1);
      deep(1, E1, U1, U2, E2, Q2, E3, Q3, MM, U2);
      phase3(b, 1, U2, XL);
    }
  }

  k_diff<<<1, 1, 0, stream>>>(DIFF, OUT + 4194304);
}

// Round 14
// 1472.643 us; speedup vs baseline: 1.1264x; 1.1264x over previous
//
#include <hip/hip_runtime.h>
#include <math.h>

#define CH 24

typedef __attribute__((ext_vector_type(8))) short short8v;
typedef __attribute__((ext_vector_type(4))) float f32x4;
typedef unsigned short ushort_t;
typedef unsigned int uint_t;

__device__ inline ushort_t bf16r(float f){
  uint_t u = __float_as_uint(f);
  u += 0x7FFF + ((u>>16)&1);
  return (ushort_t)(u>>16);
}
__device__ inline float bf2f(uint_t u){ return __uint_as_float(u<<16); }

// ================= weight reorder kernels =================
__global__ void k_r_res(const float* __restrict__ w, float* __restrict__ wT, int K){
  int i = blockIdx.x*256 + threadIdx.x;
  int n = 576*K*K; if (i >= n) return;
  int co = i % 24, ci = (i/24) % 24, kk = i/576;
  int ky = kk / K, kx = kk % K;
  wT[i] = w[((co*24+ci)*K+ky)*K+kx];
}
__global__ void k_r_pw(const float* __restrict__ w, float* __restrict__ wT, int CIN){
  int i = blockIdx.x*256 + threadIdx.x;
  if (i >= CIN*24) return;
  int co = i % 24, ci = i/24;
  wT[i] = w[co*CIN+ci];
}
__global__ void k_rmfma(const float* __restrict__ w, ushort_t* __restrict__ wb, int K){
  int i = blockIdx.x*256 + threadIdx.x;
  int n = K*K*1024; if (i >= n) return;
  int j = i & 7, l = (i>>3) & 63, t = (i>>9) & 1, tap = i >> 10;
  int ci = (l>>4)*8 + j, co = t*16 + (l&15);
  int ky = tap / K, kx = tap % K;
  float v = (ci<24 && co<24) ? w[((co*24+ci)*K+ky)*K+kx] : 0.f;
  wb[i] = bf16r(v);
}
__global__ void k_rmfma4(const float* __restrict__ w, ushort_t* __restrict__ wb){
  int i = blockIdx.x*256 + threadIdx.x;
  if (i >= 16384) return;
  int j = i & 7, l = (i>>3) & 63, t = (i>>9) & 1, tap = i >> 10;
  int ci = (l>>4)*8 + j, co = t*16 + (l&15);
  int ky = tap >> 2, kx = tap & 3;
  float v = (ci<24 && co<24) ? w[((ci*24+co)*4+ky)*4+kx] : 0.f;
  wb[i] = bf16r(v);
}

// ================= compute kernels =================

__global__ void k_lap(const float* __restrict__ x, float* __restrict__ xl, int H, int W){
  int idx = blockIdx.x*256 + threadIdx.x;
  int HW = H*W;
  if (idx >= HW) return;
  const float* xb = x + (size_t)blockIdx.z*3*HW;
  float* xo = xl + (size_t)blockIdx.z*HW;
  int px = idx % W, py = idx / W;
#define MEANV(yy,xx) (((yy)>=0&&(yy)<H&&(xx)>=0&&(xx)<W) ? (xb[(yy)*W+(xx)]+xb[HW+(yy)*W+(xx)]+xb[2*HW+(yy)*W+(xx)])*(1.f/3.f) : 0.f)
  float v = 4.f*MEANV(py,px) - MEANV(py-1,px) - MEANV(py+1,px) - MEANV(py,px-1) - MEANV(py,px+1);
#undef MEANV
  xo[idx] = v;
}

// ---------- MFMA KxK conv 24->24 FUSED with 1x1 pw + mean/max. 48B records. ----------
// INBF: input planes bf16; OUTBF: output planes bf16. mm always fp32.
template<int K, bool EXPAND, bool INBF, bool OUTBF>
__launch_bounds__(512)
__global__ void k_conv_mfma(const void* in, const ushort_t* __restrict__ wb,
                            const ushort_t* __restrict__ wbpw, const float* __restrict__ wexp,
                            void* out, float* __restrict__ mm,
                            int H, int W, int istrIn, int istrOut, int istrMM){
  constexpr int SW_T = 32 + K - 1;
  constexpr int SH = 16 + K - 1;
  constexpr int NPX = SH*SW_T;
  __shared__ ushort_t lds[NPX*24];
  __shared__ uint_t sc[8][16*20];
  int tid = threadIdx.x;
  const float* inb_f = (const float*)in + (size_t)blockIdx.z*istrIn;
  const ushort_t* inb_b = (const ushort_t*)in + (size_t)blockIdx.z*istrIn;
  int x0g = blockIdx.x*32 - K/2, y0g = blockIdx.y*16 - K/2;
  int HW = H*W;
  for (int i = tid; i < NPX*3; i += 512){
    int q = i / NPX;
    int pp = i - q*NPX;
    int row = pp / SW_T, col = pp - row*SW_T;
    int gy = y0g + row, gx = x0g + col;
    uint4 w4; w4.x=0u; w4.y=0u; w4.z=0u; w4.w=0u;
    if (gy >= 0 && gy < H && gx >= 0 && gx < W){
      size_t base = (size_t)gy*W + gx;
      int c0 = q*8;
      if (EXPAND){
        float val = inb_f[base];
        w4.x = (uint_t)bf16r(val*wexp[c0+0]) | ((uint_t)bf16r(val*wexp[c0+1])<<16);
        w4.y = (uint_t)bf16r(val*wexp[c0+2]) | ((uint_t)bf16r(val*wexp[c0+3])<<16);
        w4.z = (uint_t)bf16r(val*wexp[c0+4]) | ((uint_t)bf16r(val*wexp[c0+5])<<16);
        w4.w = (uint_t)bf16r(val*wexp[c0+6]) | ((uint_t)bf16r(val*wexp[c0+7])<<16);
      } else if (INBF){
        uint_t u0=inb_b[(size_t)(c0+0)*HW+base], u1=inb_b[(size_t)(c0+1)*HW+base];
        uint_t u2=inb_b[(size_t)(c0+2)*HW+base], u3=inb_b[(size_t)(c0+3)*HW+base];
        uint_t u4=inb_b[(size_t)(c0+4)*HW+base], u5=inb_b[(size_t)(c0+5)*HW+base];
        uint_t u6=inb_b[(size_t)(c0+6)*HW+base], u7=inb_b[(size_t)(c0+7)*HW+base];
        w4.x = u0 | (u1<<16); w4.y = u2 | (u3<<16); w4.z = u4 | (u5<<16); w4.w = u6 | (u7<<16);
      } else {
        w4.x = (uint_t)bf16r(inb_f[(size_t)(c0+0)*HW+base]) | ((uint_t)bf16r(inb_f[(size_t)(c0+1)*HW+base])<<16);
        w4.y = (uint_t)bf16r(inb_f[(size_t)(c0+2)*HW+base]) | ((uint_t)bf16r(inb_f[(size_t)(c0+3)*HW+base])<<16);
        w4.z = (uint_t)bf16r(inb_f[(size_t)(c0+4)*HW+base]) | ((uint_t)bf16r(inb_f[(size_t)(c0+5)*HW+base])<<16);
        w4.w = (uint_t)bf16r(inb_f[(size_t)(c0+6)*HW+base]) | ((uint_t)bf16r(inb_f[(size_t)(c0+7)*HW+base])<<16);
      }
    }
    *(uint4*)(lds + (size_t)pp*24 + q*8) = w4;
  }
  __syncthreads();
  int l = tid & 63, wid = tid >> 6;
  int kg = l >> 4, li = l & 15;
  int kgc = (kg < 3) ? kg : 2;
  f32x4 zero = {0.f,0.f,0.f,0.f};
  f32x4 acc[4][2];
  #pragma unroll
  for (int i=0;i<4;i++){ acc[i][0]=zero; acc[i][1]=zero; }

  const ushort_t* aln = lds + li*24 + kgc*8 + (size_t)wid*SW_T*24;

  #pragma unroll
  for (int ky=0; ky<K; ky++){
    #pragma unroll
    for (int kx=0; kx<K; kx++){
      int tap = ky*K + kx;
      const ushort_t* wp = wb + (size_t)tap*1024;
      short8v b0 = *(const short8v*)(wp + l*8);
      short8v b1 = *(const short8v*)(wp + 512 + l*8);
      #pragma unroll
      for (int i=0;i<4;i++){
        const ushort_t* ap = aln + (((i&1)*8 + ky)*SW_T + (i>>1)*16 + kx)*24;
        short8v a = *(const short8v*)ap;
        acc[i][0] = __builtin_amdgcn_mfma_f32_16x16x32_bf16(a, b0, acc[i][0], 0, 0, 0);
        acc[i][1] = __builtin_amdgcn_mfma_f32_16x16x32_bf16(a, b1, acc[i][1], 0, 0, 0);
      }
    }
  }
  // ---- stage 2: pw 1x1 via second MFMA, + mean/max ----
  short8v bpw0 = *(const short8v*)(wbpw + l*8);
  short8v bpw1 = *(const short8v*)(wbpw + 512 + l*8);
  uint_t* s = sc[wid];
  float* outb_f = (float*)out + (size_t)blockIdx.z*istrOut;
  ushort_t* outb_b = (ushort_t*)out + (size_t)blockIdx.z*istrOut;
  float* mmb = mm + (size_t)blockIdx.z*istrMM;
  #pragma unroll 1
  for (int i=0;i<4;i++){
    __asm__ volatile("s_waitcnt lgkmcnt(0)" ::: "memory");
    __builtin_amdgcn_sched_barrier(0);
    #pragma unroll
    for (int reg=0; reg<4; reg++){
      float v0 = acc[i][0][reg], v1 = acc[i][1][reg];
      float v0n = __shfl_xor(v0, 1, 64);
      float v1n = __shfl_xor(v1, 1, 64);
      int pxr = kg*4 + reg;
      uint_t packed; int uidx;
      if ((li & 1) == 0){
        packed = (uint_t)bf16r(v0) | ((uint_t)bf16r(v0n) << 16);
        uidx = li >> 1;
      } else {
        packed = (uint_t)bf16r(v1n) | ((uint_t)bf16r(v1) << 16);
        uidx = 8 + (li >> 1);
      }
      s[pxr*20 + uidx] = packed;
    }
    __asm__ volatile("s_waitcnt lgkmcnt(0)" ::: "memory");
    __builtin_amdgcn_sched_barrier(0);
    short8v a2 = *(const short8v*)((const ushort_t*)s + li*40 + kg*8);
    f32x4 d0 = __builtin_amdgcn_mfma_f32_16x16x32_bf16(a2, bpw0, zero, 0, 0, 0);
    f32x4 d1 = __builtin_amdgcn_mfma_f32_16x16x32_bf16(a2, bpw1, zero, 0, 0, 0);
    int gy = blockIdx.y*16 + wid + (i&1)*8;
    int gx = blockIdx.x*32 + (i>>1)*16 + kg*4;
    if (OUTBF){
      uint2 p0; p0.x = (uint_t)bf16r(d0[0]) | ((uint_t)bf16r(d0[1])<<16);
      p0.y = (uint_t)bf16r(d0[2]) | ((uint_t)bf16r(d0[3])<<16);
      *(uint2*)(outb_b + (size_t)li*HW + (size_t)gy*W + gx) = p0;
      if (li < 8){
        uint2 p1; p1.x = (uint_t)bf16r(d1[0]) | ((uint_t)bf16r(d1[1])<<16);
        p1.y = (uint_t)bf16r(d1[2]) | ((uint_t)bf16r(d1[3])<<16);
        *(uint2*)(outb_b + (size_t)(16+li)*HW + (size_t)gy*W + gx) = p1;
      }
    } else {
      *(f32x4*)(outb_f + (size_t)li*HW + (size_t)gy*W + gx) = d0;
      if (li < 8)
        *(f32x4*)(outb_f + (size_t)(16+li)*HW + (size_t)gy*W + gx) = d1;
    }
    f32x4 sm, mx;
    #pragma unroll
    for (int reg=0; reg<4; reg++){
      sm[reg] = d0[reg] + d1[reg];
      mx[reg] = fmaxf(d0[reg], (li<8) ? d1[reg] : -3.4e38f);
    }
    #pragma unroll
    for (int m=1; m<16; m<<=1){
      #pragma unroll
      for (int reg=0; reg<4; reg++){
        sm[reg] += __shfl_xor(sm[reg], m, 64);
        mx[reg] = fmaxf(mx[reg], __shfl_xor(mx[reg], m, 64));
      }
    }
    if (li == 0){
      f32x4 me; me[0]=sm[0]*(1.f/24.f); me[1]=sm[1]*(1.f/24.f); me[2]=sm[2]*(1.f/24.f); me[3]=sm[3]*(1.f/24.f);
      *(f32x4*)(mmb + (size_t)gy*W + gx) = me;
      *(f32x4*)(mmb + (size_t)HW + (size_t)gy*W + gx) = mx;
    }
  }
}

// ---------- MFMA ConvTranspose2d(k=4,s=2,p=1), 32x16 out tile ----------
template<bool INBF, bool OUTBF>
__launch_bounds__(512)
__global__ void k_convT_mfma(const void* in, const ushort_t* __restrict__ wb,
                             void* out, int Ho, int Wo, int istrIn, int istrOut){
  const int Hi = Ho>>1, Wi = Wo>>1;
  constexpr int SW_T = 18, NPX = 180;
  __shared__ ushort_t lds[NPX*24];
  int tid = threadIdx.x;
  const float* inb_f = (const float*)in + (size_t)blockIdx.z*istrIn;
  const ushort_t* inb_b = (const ushort_t*)in + (size_t)blockIdx.z*istrIn;
  int X0 = blockIdx.x*32, Y0 = blockIdx.y*16;
  int ix0 = (X0>>1) - 1, iy0 = (Y0>>1) - 1;
  int HWi = Hi*Wi;
  for (int i = tid; i < NPX*3; i += 512){
    int q = i / NPX;
    int pp = i - q*NPX;
    int row = pp / SW_T, col = pp - row*SW_T;
    int gy = iy0 + row, gx = ix0 + col;
    uint4 w4; w4.x=0u; w4.y=0u; w4.z=0u; w4.w=0u;
    if (gy>=0 && gy<Hi && gx>=0 && gx<Wi){
      size_t base = (size_t)gy*Wi + gx;
      int c0 = q*8;
      if (INBF){
        uint_t u0=inb_b[(size_t)(c0+0)*HWi+base], u1=inb_b[(size_t)(c0+1)*HWi+base];
        uint_t u2=inb_b[(size_t)(c0+2)*HWi+base], u3=inb_b[(size_t)(c0+3)*HWi+base];
        uint_t u4=inb_b[(size_t)(c0+4)*HWi+base], u5=inb_b[(size_t)(c0+5)*HWi+base];
        uint_t u6=inb_b[(size_t)(c0+6)*HWi+base], u7=inb_b[(size_t)(c0+7)*HWi+base];
        w4.x = u0 | (u1<<16); w4.y = u2 | (u3<<16); w4.z = u4 | (u5<<16); w4.w = u6 | (u7<<16);
      } else {
        w4.x = (uint_t)bf16r(inb_f[(size_t)(c0+0)*HWi+base]) | ((uint_t)bf16r(inb_f[(size_t)(c0+1)*HWi+base])<<16);
        w4.y = (uint_t)bf16r(inb_f[(size_t)(c0+2)*HWi+base]) | ((uint_t)bf16r(inb_f[(size_t)(c0+3)*HWi+base])<<16);
        w4.z = (uint_t)bf16r(inb_f[(size_t)(c0+4)*HWi+base]) | ((uint_t)bf16r(inb_f[(size_t)(c0+5)*HWi+base])<<16);
        w4.w = (uint_t)bf16r(inb_f[(size_t)(c0+6)*HWi+base]) | ((uint_t)bf16r(inb_f[(size_t)(c0+7)*HWi+base])<<16);
      }
    }
    *(uint4*)(lds + (size_t)pp*24 + q*8) = w4;
  }
  __syncthreads();
  int l = tid & 63, wid = tid >> 6;
  int kg = l >> 4, li = l & 15;
  int kgc = (kg < 3) ? kg : 2;
  f32x4 zero = {0.f,0.f,0.f,0.f};
  f32x4 acc[4][2];
  #pragma unroll
  for (int i=0;i<4;i++){ acc[i][0]=zero; acc[i][1]=zero; }

  const ushort_t* aln = lds + li*24 + kgc*8;

  #pragma unroll
  for (int i=0;i<4;i++){
    int g = wid + 8*i;
    int r = g & 15, q = g >> 4;
    int ky0 = (r+1)&1;
    #pragma unroll
    for (int t2=0;t2<2;t2++){
      int ky = ky0 + 2*t2;
      int liy = ((r+1-ky)>>1) + 1;
      #pragma unroll
      for (int u=0;u<2;u++){
        int kx = (q ? 0 : 1) + 2*u;
        int lixb = ((q+1-kx)>>1) + 1;
        int tap = ky*4 + kx;
        const ushort_t* wp = wb + (size_t)tap*1024;
        short8v b0 = *(const short8v*)(wp + l*8);
        short8v b1 = *(const short8v*)(wp + 512 + l*8);
        short8v a = *(const short8v*)(aln + (liy*SW_T + lixb)*24);
        acc[i][0] = __builtin_amdgcn_mfma_f32_16x16x32_bf16(a, b0, acc[i][0], 0, 0, 0);
        acc[i][1] = __builtin_amdgcn_mfma_f32_16x16x32_bf16(a, b1, acc[i][1], 0, 0, 0);
      }
    }
  }
  float* outb_f = (float*)out + (size_t)blockIdx.z*istrOut;
  ushort_t* outb_b = (ushort_t*)out + (size_t)blockIdx.z*istrOut;
  int HWo = Ho*Wo;
  #pragma unroll
  for (int i=0;i<4;i++){
    int g = wid + 8*i;
    int r = g & 15, q = g >> 4;
    int oy = Y0 + r;
    #pragma unroll
    for (int reg=0; reg<4; reg++){
      int ox = X0 + 2*(kg*4 + reg) + q;
      if (OUTBF){
        outb_b[(size_t)li*HWo + (size_t)oy*Wo + ox] = bf16r(acc[i][0][reg]);
        if (li < 8)
          outb_b[(size_t)(16+li)*HWo + (size_t)oy*Wo + ox] = bf16r(acc[i][1][reg]);
      } else {
        outb_f[(size_t)li*HWo + (size_t)oy*Wo + ox] = acc[i][0][reg];
        if (li < 8)
          outb_f[(size_t)(16+li)*HWo + (size_t)oy*Wo + ox] = acc[i][1][reg];
      }
    }
  }
}

// ---------- MFMA 4x4 s2 p1 downsample, 16x8 out tile ----------
template<bool INBF>
__launch_bounds__(512)
__global__ void k_down_mfma(const void* in, const ushort_t* __restrict__ wb,
                            float* __restrict__ out, int Ho, int Wo, int istrIn, int istrOut){
  const int Hi = Ho*2, Wi = Wo*2;
  constexpr int NPX = 18*34;
  __shared__ ushort_t lds[NPX*24];
  int tid = threadIdx.x;
  const float* inb_f = (const float*)in + (size_t)blockIdx.z*istrIn;
  const ushort_t* inb_b = (const ushort_t*)in + (size_t)blockIdx.z*istrIn;
  int X0 = blockIdx.x*16, Y0 = blockIdx.y*8;
  int ix0 = 2*X0 - 1, iy0 = 2*Y0 - 1;
  int HWi = Hi*Wi;
  for (int i = tid; i < NPX*3; i += 512){
    int q = i / NPX;
    int pp = i - q*NPX;
    int row = pp / 34;
    int rem = pp - row*34;
    int par = (rem >= 17) ? 1 : 0;
    int sub = rem - par*17;
    int gx = ix0 + 2*sub + par;
    int gy = iy0 + row;
    uint4 w4; w4.x=0u; w4.y=0u; w4.z=0u; w4.w=0u;
    if (gy>=0 && gy<Hi && gx>=0 && gx<Wi){
      size_t base = (size_t)gy*Wi + gx;
      int c0 = q*8;
      if (INBF){
        uint_t u0=inb_b[(size_t)(c0+0)*HWi+base], u1=inb_b[(size_t)(c0+1)*HWi+base];
        uint_t u2=inb_b[(size_t)(c0+2)*HWi+base], u3=inb_b[(size_t)(c0+3)*HWi+base];
        uint_t u4=inb_b[(size_t)(c0+4)*HWi+base], u5=inb_b[(size_t)(c0+5)*HWi+base];
        uint_t u6=inb_b[(size_t)(c0+6)*HWi+base], u7=inb_b[(size_t)(c0+7)*HWi+base];
        w4.x = u0 | (u1<<16); w4.y = u2 | (u3<<16); w4.z = u4 | (u5<<16); w4.w = u6 | (u7<<16);
      } else {
        w4.x = (uint_t)bf16r(inb_f[(size_t)(c0+0)*HWi+base]) | ((uint_t)bf16r(inb_f[(size_t)(c0+1)*HWi+base])<<16);
        w4.y = (uint_t)bf16r(inb_f[(size_t)(c0+2)*HWi+base]) | ((uint_t)bf16r(inb_f[(size_t)(c0+3)*HWi+base])<<16);
        w4.z = (uint_t)bf16r(inb_f[(size_t)(c0+4)*HWi+base]) | ((uint_t)bf16r(inb_f[(size_t)(c0+5)*HWi+base])<<16);
        w4.w = (uint_t)bf16r(inb_f[(size_t)(c0+6)*HWi+base]) | ((uint_t)bf16r(inb_f[(size_t)(c0+7)*HWi+base])<<16);
      }
    }
    *(uint4*)(lds + (size_t)pp*24 + q*8) = w4;
  }
  __syncthreads();
  int l = tid & 63, wid = tid >> 6;
  int kg = l >> 4, li = l & 15;
  int kgc = (kg < 3) ? kg : 2;
  f32x4 zero = {0.f,0.f,0.f,0.f};
  f32x4 acc0 = zero, acc1 = zero;
  const ushort_t* aln = lds + li*24 + kgc*8 + (size_t)(2*wid)*34*24;
  #pragma unroll
  for (int ky=0; ky<4; ky++){
    #pragma unroll
    for (int kx=0; kx<4; kx++){
      int tap = ky*4 + kx;
      const ushort_t* wp = wb + (size_t)tap*1024;
      short8v b0 = *(const short8v*)(wp + l*8);
      short8v b1 = *(const short8v*)(wp + 512 + l*8);
      short8v a = *(const short8v*)(aln + (ky*34 + (kx&1)*17 + (kx>>1))*24);
      acc0 = __builtin_amdgcn_mfma_f32_16x16x32_bf16(a, b0, acc0, 0, 0, 0);
      acc1 = __builtin_amdgcn_mfma_f32_16x16x32_bf16(a, b1, acc1, 0, 0, 0);
    }
  }
  int HWo = Ho*Wo;
  float* outb = out + (size_t)blockIdx.z*istrOut;
  int oy = Y0 + wid, ox = X0 + kg*4;
  float* o0 = outb + (size_t)li*HWo + (size_t)oy*Wo + ox;
  *(f32x4*)o0 = acc0;
  if (li < 8){
    float* o1 = outb + (size_t)(16+li)*HWo + (size_t)oy*Wo + ox;
    *(f32x4*)o1 = acc1;
  }
}

// KxK conv fp32 (K=3 @128). wT=[ky][kx][ci][co]. Tile 32 x TH.
template<int K, int TH>
__launch_bounds__(256)
__global__ void k_conv(const float* __restrict__ in, const float* __restrict__ wT,
                       float* __restrict__ out, int H, int W, int istrIn, int istrOut){
  constexpr int TW = 32;
  constexpr int PX = (TW*TH)/256;
  constexpr int XT = TW/PX;
  constexpr int SW = TW + K - 1;
  constexpr int SWP = SW | 1;
  constexpr int SH = TH + K - 1;
  constexpr int CC = 8;
  __shared__ float tile[CC*SH*SWP];
  int tx = threadIdx.x % XT, ty = threadIdx.x / XT;
  int x0 = blockIdx.x*TW - K/2, y0 = blockIdx.y*TH - K/2;
  const float* inb = in + (size_t)blockIdx.z*istrIn;
  float acc[CH][PX];
  #pragma unroll
  for (int co=0;co<CH;co++)
    #pragma unroll
    for (int px=0;px<PX;px++) acc[co][px] = 0.f;

  #pragma unroll 1
  for (int c0=0;c0<CH;c0+=CC){
    __syncthreads();
    for (int i=threadIdx.x; i<CC*SH*SW; i+=256){
      int col = i % SW; int rr = i / SW; int row = rr % SH; int c = rr / SH;
      int gy = y0+row, gx = x0+col;
      tile[(c*SH+row)*SWP+col] = (gy>=0 && gy<H && gx>=0 && gx<W)
          ? inb[(size_t)(c0+c)*H*W + (size_t)gy*W + gx] : 0.f;
    }
    __syncthreads();
    #pragma unroll 1
    for (int ci=0;ci<CC;ci++){
      #pragma unroll 1
      for (int ky=0;ky<K;ky++){
        const float* trow = &tile[(ci*SH + ty+ky)*SWP + tx*PX];
        #pragma unroll
        for (int kx=0;kx<K;kx++){
          float v[PX];
          #pragma unroll
          for (int px=0;px<PX;px++) v[px] = trow[kx+px];
          const float* wp = wT + ((ky*K+kx)*24 + c0+ci)*24;
          #pragma unroll
          for (int co=0;co<CH;co++){
            float wv = wp[co];
            #pragma unroll
            for (int px=0;px<PX;px++) acc[co][px] = fmaf(v[px], wv, acc[co][px]);
          }
        }
      }
    }
  }
  int oy = blockIdx.y*TH+ty, ox = blockIdx.x*TW+tx*PX;
  float* ob = out + (size_t)blockIdx.z*istrOut + (size_t)oy*W + ox;
  #pragma unroll
  for (int co=0;co<CH;co++){
    if (PX == 2){
      float2 o; o.x=acc[co][0]; o.y=acc[co][1];
      *(float2*)(ob + (size_t)co*H*W) = o;
    } else {
      ob[(size_t)co*H*W] = acc[co][0];
    }
  }
}

__global__ void k_pw(const float* in, const float* __restrict__ wT,
                     float* out, float* __restrict__ mm, int HW, int istr, int istrMM){
  int p = (blockIdx.x*256 + threadIdx.x)*4;
  if (p >= HW) return;
  const float* ib = in + (size_t)blockIdx.z*istr;
  float acc[CH][4];
  #pragma unroll
  for (int co=0;co<CH;co++){ acc[co][0]=0;acc[co][1]=0;acc[co][2]=0;acc[co][3]=0; }
  #pragma unroll 1
  for (int ci=0;ci<CH;ci++){
    float4 v = *(const float4*)(ib + (size_t)ci*HW + p);
    const float* wp = wT + ci*24;
    #pragma unroll
    for (int co=0;co<CH;co++){
      float wv = wp[co];
      acc[co][0] = fmaf(v.x, wv, acc[co][0]);
      acc[co][1] = fmaf(v.y, wv, acc[co][1]);
      acc[co][2] = fmaf(v.z, wv, acc[co][2]);
      acc[co][3] = fmaf(v.w, wv, acc[co][3]);
    }
  }
  float mean[4]={0,0,0,0}, mx[4]={-3.4e38f,-3.4e38f,-3.4e38f,-3.4e38f};
  #pragma unroll
  for (int co=0;co<CH;co++)
    #pragma unroll
    for (int j=0;j<4;j++){ mean[j]+=acc[co][j]; mx[j]=fmaxf(mx[j],acc[co][j]); }
  float* ob = out + (size_t)blockIdx.z*istr;
  #pragma unroll
  for (int co=0;co<CH;co++){
    float4 o; o.x=acc[co][0]; o.y=acc[co][1]; o.z=acc[co][2]; o.w=acc[co][3];
    *(float4*)(ob + (size_t)co*HW + p) = o;
  }
  float* mb = mm + (size_t)blockIdx.z*istrMM;
  float4 me; me.x=mean[0]*(1.f/24.f); me.y=mean[1]*(1.f/24.f); me.z=mean[2]*(1.f/24.f); me.w=mean[3]*(1.f/24.f);
  float4 mxo; mxo.x=mx[0]; mxo.y=mx[1]; mxo.z=mx[2]; mxo.w=mx[3];
  *(float4*)(mb + p) = me;
  *(float4*)(mb + HW + p) = mxo;
}

// spatial attn + sigmoid + relu + residual add; BF: R/X/out are bf16 planes
template<bool BF>
__global__ void k_attn_res(const void* R_, const float* __restrict__ M,
                           const void* X_, const float* __restrict__ wsa,
                           void* out_, int H, int W, int istr, int istrMM){
  int p = (blockIdx.x*256 + threadIdx.x)*4;
  int HW = H*W;
  if (p >= HW) return;
  int py = p / W, px0 = p % W;
  const float* Mb = M + (size_t)blockIdx.z*istrMM;
  float s[4]={0,0,0,0};
  #pragma unroll
  for (int cc=0;cc<2;cc++){
    const float* Mc = Mb + (size_t)cc*HW;
    #pragma unroll 1
    for (int ky=0;ky<7;ky++){
      int gy = py+ky-3;
      if (gy<0||gy>=H) continue;
      const float* mr = Mc + (size_t)gy*W;
      float mv[10];
      #pragma unroll
      for (int j=0;j<10;j++){
        int gx = px0-3+j;
        mv[j] = (gx>=0 && gx<W) ? mr[gx] : 0.f;
      }
      const float* wr = wsa + (cc*7+ky)*7;
      #pragma unroll
      for (int kx=0;kx<7;kx++){
        float wv = wr[kx];
        #pragma unroll
        for (int px=0;px<4;px++) s[px] = fmaf(mv[kx+px], wv, s[px]);
      }
    }
  }
  float g[4];
  #pragma unroll
  for (int px=0;px<4;px++) g[px] = 1.f/(1.f+expf(-s[px]));
  #pragma unroll
  for (int c=0;c<CH;c++){
    float r0,r1,r2,r3, x0v,x1v,x2v,x3v;
    if (BF){
      const ushort_t* Rb = (const ushort_t*)R_ + (size_t)blockIdx.z*istr + (size_t)c*HW + p;
      const ushort_t* Xb = (const ushort_t*)X_ + (size_t)blockIdx.z*istr + (size_t)c*HW + p;
      uint2 rv = *(const uint2*)Rb;
      uint2 xv = *(const uint2*)Xb;
      r0=bf2f(rv.x&0xffffu); r1=bf2f(rv.x>>16); r2=bf2f(rv.y&0xffffu); r3=bf2f(rv.y>>16);
      x0v=bf2f(xv.x&0xffffu); x1v=bf2f(xv.x>>16); x2v=bf2f(xv.y&0xffffu); x3v=bf2f(xv.y>>16);
    } else {
      const float* Rb = (const float*)R_ + (size_t)blockIdx.z*istr + (size_t)c*HW + p;
      const float* Xb = (const float*)X_ + (size_t)blockIdx.z*istr + (size_t)c*HW + p;
      float4 rv = *(const float4*)Rb;
      float4 xv = *(const float4*)Xb;
      r0=rv.x; r1=rv.y; r2=rv.z; r3=rv.w;
      x0v=xv.x; x1v=xv.y; x2v=xv.z; x3v=xv.w;
    }
    float o0 = x0v + fmaxf(r0*g[0], 0.f);
    float o1 = x1v + fmaxf(r1*g[1], 0.f);
    float o2 = x2v + fmaxf(r2*g[2], 0.f);
    float o3 = x3v + fmaxf(r3*g[3], 0.f);
    if (BF){
      ushort_t* Ob = (ushort_t*)out_ + (size_t)blockIdx.z*istr + (size_t)c*HW + p;
      uint2 ov;
      ov.x = (uint_t)bf16r(o0) | ((uint_t)bf16r(o1)<<16);
      ov.y = (uint_t)bf16r(o2) | ((uint_t)bf16r(o3)<<16);
      *(uint2*)Ob = ov;
    } else {
      float* Ob = (float*)out_ + (size_t)blockIdx.z*istr + (size_t)c*HW + p;
      float4 ov; ov.x=o0; ov.y=o1; ov.z=o2; ov.w=o3;
      *(float4*)Ob = ov;
    }
  }
}

// variant: residual computed from XL*wexp; BF: R/out bf16
template<bool BF>
__global__ void k_attn_res_x(const void* R_, const float* __restrict__ M,
                             const float* __restrict__ XL, const float* __restrict__ wsa,
                             const float* __restrict__ wexp,
                             void* out_, int H, int W, int istr, int istrMM){
  int p = (blockIdx.x*256 + threadIdx.x)*4;
  int HW = H*W;
  if (p >= HW) return;
  int py = p / W, px0 = p % W;
  const float* Mb = M + (size_t)blockIdx.z*istrMM;
  float s[4]={0,0,0,0};
  #pragma unroll
  for (int cc=0;cc<2;cc++){
    const float* Mc = Mb + (size_t)cc*HW;
    #pragma unroll 1
    for (int ky=0;ky<7;ky++){
      int gy = py+ky-3;
      if (gy<0||gy>=H) continue;
      const float* mr = Mc + (size_t)gy*W;
      float mv[10];
      #pragma unroll
      for (int j=0;j<10;j++){
        int gx = px0-3+j;
        mv[j] = (gx>=0 && gx<W) ? mr[gx] : 0.f;
      }
      const float* wr = wsa + (cc*7+ky)*7;
      #pragma unroll
      for (int kx=0;kx<7;kx++){
        float wv = wr[kx];
        #pragma unroll
        for (int px=0;px<4;px++) s[px] = fmaf(mv[kx+px], wv, s[px]);
      }
    }
  }
  float g[4];
  #pragma unroll
  for (int px=0;px<4;px++) g[px] = 1.f/(1.f+expf(-s[px]));
  float4 xl4 = *(const float4*)(XL + (size_t)blockIdx.z*HW + p);
  #pragma unroll
  for (int c=0;c<CH;c++){
    float wc = wexp[c];
    float r0,r1,r2,r3;
    if (BF){
      const ushort_t* Rb = (const ushort_t*)R_ + (size_t)blockIdx.z*istr + (size_t)c*HW + p;
      uint2 rv = *(const uint2*)Rb;
      r0=bf2f(rv.x&0xffffu); r1=bf2f(rv.x>>16); r2=bf2f(rv.y&0xffffu); r3=bf2f(rv.y>>16);
    } else {
      const float* Rb = (const float*)R_ + (size_t)blockIdx.z*istr + (size_t)c*HW + p;
      float4 rv = *(const float4*)Rb;
      r0=rv.x; r1=rv.y; r2=rv.z; r3=rv.w;
    }
    float o0 = xl4.x*wc + fmaxf(r0*g[0], 0.f);
    float o1 = xl4.y*wc + fmaxf(r1*g[1], 0.f);
    float o2 = xl4.z*wc + fmaxf(r2*g[2], 0.f);
    float o3 = xl4.w*wc + fmaxf(r3*g[3], 0.f);
    if (BF){
      ushort_t* Ob = (ushort_t*)out_ + (size_t)blockIdx.z*istr + (size_t)c*HW + p;
      uint2 ov;
      ov.x = (uint_t)bf16r(o0) | ((uint_t)bf16r(o1)<<16);
      ov.y = (uint_t)bf16r(o2) | ((uint_t)bf16r(o3)<<16);
      *(uint2*)Ob = ov;
    } else {
      float* Ob = (float*)out_ + (size_t)blockIdx.z*istr + (size_t)c*HW + p;
      float4 ov; ov.x=o0; ov.y=o1; ov.z=o2; ov.w=o3;
      *(float4*)Ob = ov;
    }
  }
}

__global__ void k_squeeze(const float* __restrict__ inA, const float* inB,
                          const float* __restrict__ wT, float* out, int HW, int istr){
  int p = (blockIdx.x*256 + threadIdx.x)*4;
  if (p >= HW) return;
  const float* Ab = inA + (size_t)blockIdx.z*istr;
  const float* Bb = inB + (size_t)blockIdx.z*istr;
  float acc[CH][4];
  #pragma unroll
  for (int co=0;co<CH;co++){ acc[co][0]=0;acc[co][1]=0;acc[co][2]=0;acc[co][3]=0; }
  #pragma unroll 1
  for (int ci=0;ci<48;ci++){
    const float* src = (ci<24) ? (Ab + (size_t)ci*HW) : (Bb + (size_t)(ci-24)*HW);
    float4 v = *(const float4*)(src + p);
    const float* wp = wT + ci*24;
    #pragma unroll
    for (int co=0;co<CH;co++){
      float wv = wp[co];
      acc[co][0] = fmaf(v.x, wv, acc[co][0]);
      acc[co][1] = fmaf(v.y, wv, acc[co][1]);
      acc[co][2] = fmaf(v.z, wv, acc[co][2]);
      acc[co][3] = fmaf(v.w, wv, acc[co][3]);
    }
  }
  float* ob = out + (size_t)blockIdx.z*istr;
  #pragma unroll
  for (int co=0;co<CH;co++){
    float4 o; o.x=acc[co][0]; o.y=acc[co][1]; o.z=acc[co][2]; o.w=acc[co][3];
    *(float4*)(ob + (size_t)co*HW + p) = o;
  }
}

__global__ void k_quant(const float* __restrict__ enc, const float* __restrict__ embed,
                        float* __restrict__ qt, float* __restrict__ diffAcc, int HW, int istr){
  __shared__ float em[256*28];
  __shared__ float red[4];
  {
    int j = threadIdx.x;
    float s = 0.f;
    #pragma unroll
    for (int c=0;c<CH;c++){
      float e = embed[c*256+j];
      em[j*28+c] = -2.0f*e;
      s = fmaf(e,e,s);
    }
    em[j*28+24] = s; em[j*28+25]=0.f; em[j*28+26]=0.f; em[j*28+27]=0.f;
  }
  __syncthreads();
  int p = blockIdx.x*256 + threadIdx.x;
  const float* eb = enc + (size_t)blockIdx.z*istr;
  float f[CH];
  #pragma unroll
  for (int c=0;c<CH;c++) f[c] = eb[(size_t)c*HW + p];
  float best = 3.4e38f; int bj = 0;
  #pragma unroll 1
  for (int j=0;j<256;j++){
    const float4* row = (const float4*)&em[j*28];
    float s = em[j*28+24];
    #pragma unroll
    for (int q4=0;q4<6;q4++){
      float4 r = row[q4];
      s = fmaf(f[q4*4+0], r.x, s);
      s = fmaf(f[q4*4+1], r.y, s);
      s = fmaf(f[q4*4+2], r.z, s);
      s = fmaf(f[q4*4+3], r.w, s);
    }
    if (s < best){ best = s; bj = j; }
  }
  float* qb = qt + (size_t)blockIdx.z*istr;
  float d = 0.f;
  #pragma unroll
  for (int c=0;c<CH;c++){
    float q = embed[c*256+bj];
    qb[(size_t)c*HW + p] = q;
    float e = q - f[c];
    d = fmaf(e,e,d);
  }
  #pragma unroll
  for (int off=32; off>0; off>>=1) d += __shfl_down(d, off, 64);
  int lane = threadIdx.x & 63, wv = threadIdx.x >> 6;
  if (lane==0) red[wv] = d;
  __syncthreads();
  if (threadIdx.x==0) atomicAdd(diffAcc, red[0]+red[1]+red[2]+red[3]);
}

// final: dec1 is bf16 planes; mask = 1x1(24->1), clean = xl - mask
__global__ void k_final(const ushort_t* __restrict__ dec1, const float* __restrict__ w,
                        const float* __restrict__ xl, float* __restrict__ outMask,
                        float* __restrict__ outClean, int HW, int dstr){
  int p = (blockIdx.x*256 + threadIdx.x)*4;
  if (p >= HW) return;
  const ushort_t* db = dec1 + (size_t)blockIdx.z*dstr;
  float m[4]={0,0,0,0};
  #pragma unroll
  for (int c=0;c<CH;c++){
    uint2 dv = *(const uint2*)(db + (size_t)c*HW + p);
    float wc = w[c];
    m[0]=fmaf(bf2f(dv.x&0xffffu),wc,m[0]);
    m[1]=fmaf(bf2f(dv.x>>16),wc,m[1]);
    m[2]=fmaf(bf2f(dv.y&0xffffu),wc,m[2]);
    m[3]=fmaf(bf2f(dv.y>>16),wc,m[3]);
  }
  float4 xv = *(const float4*)(xl + (size_t)blockIdx.z*HW + p);
  float4 mo; mo.x=m[0]; mo.y=m[1]; mo.z=m[2]; mo.w=m[3];
  float4 co; co.x=xv.x-m[0]; co.y=xv.y-m[1]; co.z=xv.z-m[2]; co.w=xv.w-m[3];
  *(float4*)(outMask + (size_t)blockIdx.z*HW + p) = mo;
  *(float4*)(outClean + (size_t)blockIdx.z*HW + p) = co;
}

__global__ void k_diff(const float* __restrict__ acc, float* __restrict__ out){
  out[0] = acc[0]*(1.f/3145728.f) + acc[1]*(1.f/786432.f);
}

// =======================================================================
extern "C" void kernel_launch(void* const* d_in, const int* in_sizes, int n_in,
                              void* d_out, int out_size, void* d_ws, size_t ws_size,
                              hipStream_t stream) {
  const float* x        = (const float*)d_in[0];
  const float* embed2   = (const float*)d_in[1];
  const float* embed3   = (const float*)d_in[2];
  const float* w_img_in = (const float*)d_in[3];
  const float* w_img_out= (const float*)d_in[4];
  const float* w_out_dd = (const float*)d_in[5];
  const float* w_out_dm = (const float*)d_in[6];
  const float* w_out_dt = (const float*)d_in[7];
  const float* w_out_ed = (const float*)d_in[8];
  const float* w_out_em = (const float*)d_in[9];
  const float* w_out_et = (const float*)d_in[10];
  const float* w_pw_dd  = (const float*)d_in[11];
  const float* w_pw_dm  = (const float*)d_in[12];
  const float* w_pw_dt  = (const float*)d_in[13];
  const float* w_pw_ed  = (const float*)d_in[14];
  const float* w_pw_em  = (const float*)d_in[15];
  const float* w_pw_et  = (const float*)d_in[16];
  const float* w_res_dd = (const float*)d_in[17];
  const float* w_res_dm = (const float*)d_in[18];
  const float* w_res_dt = (const float*)d_in[19];
  const float* w_res_ed = (const float*)d_in[20];
  const float* w_res_em = (const float*)d_in[21];
  const float* w_res_et = (const float*)d_in[22];
  const float* w_sa_dd  = (const float*)d_in[23];
  const float* w_sa_dm  = (const float*)d_in[24];
  const float* w_sa_dt  = (const float*)d_in[25];
  const float* w_sa_ed  = (const float*)d_in[26];
  const float* w_sa_em  = (const float*)d_in[27];
  const float* w_sa_et  = (const float*)d_in[28];
  const float* w_squ1   = (const float*)d_in[29];
  const float* w_squ2   = (const float*)d_in[30];
  (void)in_sizes; (void)n_in; (void)out_size;

  const int HW512 = 512*512, HW256 = 256*256, HW128 = 128*128, HW64 = 64*64;
  const int S512 = 24*HW512, S256 = 24*HW256, S128 = 24*HW128, S64 = 24*HW64;

  float* ws = (float*)d_ws;
  float* OUT = (float*)d_out;
  size_t F = ws_size / sizeof(float);

  // fp32-reordered weights
  float* WT      = ws;
  float* wt_ed3  = WT + 85248;
  float* wt_dd3  = WT + 90432;
  float* wt_pw_ed= WT + 152064;
  float* wt_pw_dd= WT + 152640;
  float* wt_squ1 = WT + 154368;
  float* wt_squ2 = WT + 155520;

  // MFMA bf16 B-frag weights
  ushort_t* WB = (ushort_t*)(ws + 160000);
  ushort_t* wb_et7   = WB;
  ushort_t* wb_dt7   = WB + 50176;
  ushort_t* wb_em5   = WB + 100352;
  ushort_t* wb_dm5   = WB + 125952;
  ushort_t* wb_pw_et = WB + 151552;
  ushort_t* wb_pw_em = WB + 152576;
  ushort_t* wb_pw_dm = WB + 153600;
  ushort_t* wb_pw_dt = WB + 154624;
  ushort_t* wb4_dd   = WB + 155648;
  ushort_t* wb4_dm   = WB + 172032;
  ushort_t* wb4_dt   = WB + 188416;
  ushort_t* wb4d_et  = WB + 204800;
  ushort_t* wb4d_em  = WB + 221184;
  ushort_t* wb4d_ed  = WB + 237568;

  const size_t ABASE = 290000;

  auto needBatched = [&](size_t CB)->size_t{
    // U1/U2 union: bf16 @512 (CB*S512 ushorts = CB*S512/2 floats) vs fp32 deep (8*S256 floats)
    size_t u_f = ((CB*(size_t)S512 + 1)/2 > (size_t)8*S256) ? (CB*(size_t)S512+1)/2 : (size_t)8*S256;
    return ABASE + 2097152 + 12582912 + 3145728 + 786432 + CB*524288 + 2*u_f + 2;
  };
  int CB = 0;
  if (F >= needBatched(8)) CB = 8;
  else if (F >= needBatched(4)) CB = 4;
  else if (F >= needBatched(2)) CB = 2;
  const size_t NEED_B = ABASE + 15925250;
  if (CB == 0 && F < NEED_B) return;

  float *XL, *E1, *E2, *Q2, *E3, *Q3, *MM, *DIFF, *U1, *U2;
  if (CB > 0){
    size_t off = ABASE;
    size_t u_f = ((CB*(size_t)S512 + 1)/2 > (size_t)8*S256) ? (CB*(size_t)S512+1)/2 : (size_t)8*S256;
    XL = ws + off; off += 2097152;
    E1 = ws + off; off += 12582912;
    Q2 = ws + off; off += 3145728;
    Q3 = ws + off; off += 786432;
    MM = ws + off; off += CB*524288;
    U1 = ws + off; off += u_f;
    U2 = ws + off; off += u_f;
    DIFF = ws + off;
    E2 = OUT;
    E3 = OUT + 3145728;
  } else {
    size_t off = ABASE;
    XL = ws + off; off += 262144;
    U1 = ws + off; off += 6291456;
    U2 = ws + off; off += 6291456;
    E1 = ws + off; off += 1572864;
    E2 = ws + off; off += 393216;
    Q2 = ws + off; off += 393216;
    E3 = ws + off; off += 98304;
    Q3 = ws + off; off += 98304;
    MM = ws + off; off += 524288;
    DIFF = ws + off;
  }
  ushort_t* U1b = (ushort_t*)U1;
  ushort_t* U2b = (ushort_t*)U2;

  // ---- weight reorders ----
  k_rmfma<<<dim3(196), 256, 0, stream>>>(w_res_et, wb_et7, 7);
  k_rmfma<<<dim3(196), 256, 0, stream>>>(w_res_dt, wb_dt7, 7);
  k_rmfma<<<dim3(100), 256, 0, stream>>>(w_res_em, wb_em5, 5);
  k_rmfma<<<dim3(100), 256, 0, stream>>>(w_res_dm, wb_dm5, 5);
  k_rmfma<<<dim3(4), 256, 0, stream>>>(w_pw_et, wb_pw_et, 1);
  k_rmfma<<<dim3(4), 256, 0, stream>>>(w_pw_em, wb_pw_em, 1);
  k_rmfma<<<dim3(4), 256, 0, stream>>>(w_pw_dm, wb_pw_dm, 1);
  k_rmfma<<<dim3(4), 256, 0, stream>>>(w_pw_dt, wb_pw_dt, 1);
  k_rmfma4<<<dim3(64), 256, 0, stream>>>(w_out_dd, wb4_dd);
  k_rmfma4<<<dim3(64), 256, 0, stream>>>(w_out_dm, wb4_dm);
  k_rmfma4<<<dim3(64), 256, 0, stream>>>(w_out_dt, wb4_dt);
  k_rmfma<<<dim3(64), 256, 0, stream>>>(w_out_et, wb4d_et, 4);
  k_rmfma<<<dim3(64), 256, 0, stream>>>(w_out_em, wb4d_em, 4);
  k_rmfma<<<dim3(64), 256, 0, stream>>>(w_out_ed, wb4d_ed, 4);
  k_r_res<<<dim3((576*9+255)/256), 256, 0, stream>>>(w_res_ed, wt_ed3, 3);
  k_r_res<<<dim3((576*9+255)/256), 256, 0, stream>>>(w_res_dd, wt_dd3, 3);
  k_r_pw<<<dim3(3), 256, 0, stream>>>(w_pw_ed, wt_pw_ed, 24);
  k_r_pw<<<dim3(3), 256, 0, stream>>>(w_pw_dd, wt_pw_dd, 24);
  k_r_pw<<<dim3(5), 256, 0, stream>>>(w_squ1, wt_squ1, 48);
  k_r_pw<<<dim3(5), 256, 0, stream>>>(w_squ2, wt_squ2, 48);

  hipMemsetAsync(DIFF, 0, 2*sizeof(float), stream);

  // ---- phase 1: input -> enc1  (U1/U2 bf16 @512) ----
  auto phase1 = [&](int c0, int nz, float* XLp, float* E1p){
    k_lap<<<dim3(HW512/256,1,nz), 256, 0, stream>>>(x + (size_t)c0*3*HW512, XLp, 512, 512);
    k_conv_mfma<7,true,false,true><<<dim3(16,32,nz), 512, 0, stream>>>(
        XLp, wb_et7, wb_pw_et, w_img_in, U2b, MM, 512, 512, HW512, S512, 2*HW512);
    k_attn_res_x<true><<<dim3(HW512/1024,1,nz), 256, 0, stream>>>(
        U2b, MM, XLp, w_sa_et, w_img_in, U1b, 512, 512, S512, 2*HW512);
    k_down_mfma<true><<<dim3(16,32,nz), 512, 0, stream>>>(U1b, wb4d_et, E1p, 256, 256, S512, S256);
  };

  // ---- deep: enc1 -> squ1 output (fp32 throughout) ----
  auto deep = [&](int nb, float* E1p, float* SAp, float* SBp, float* E2p, float* Q2p,
                  float* E3p, float* Q3p, float* MMp, float* D1p){
    int mm256 = 2*HW256, mm128 = 2*HW128;
    k_conv_mfma<5,false,false,false><<<dim3(8,16,nb), 512, 0, stream>>>(
        E1p, wb_em5, wb_pw_em, nullptr, SAp, MMp, 256, 256, S256, S256, mm256);
    k_attn_res<false><<<dim3(HW256/1024,1,nb), 256, 0, stream>>>(SAp, MMp, E1p, w_sa_em, SBp, 256, 256, S256, mm256);
    k_down_mfma<false><<<dim3(8,16,nb), 512, 0, stream>>>(SBp, wb4d_em, E2p, 128, 128, S256, S128);
    k_conv<3,8><<<dim3(4,16,nb), 256, 0, stream>>>(E2p, wt_ed3, SAp, 128, 128, S128, S128);
    k_pw<<<dim3(HW128/1024,1,nb), 256, 0, stream>>>(SAp, wt_pw_ed, SAp, MMp, HW128, S128, mm128);
    k_attn_res<false><<<dim3(HW128/1024,1,nb), 256, 0, stream>>>(SAp, MMp, E2p, w_sa_ed, SBp, 128, 128, S128, mm128);
    k_down_mfma<false><<<dim3(4,8,nb), 512, 0, stream>>>(SBp, wb4d_ed, E3p, 64, 64, S128, S64);
    k_quant<<<dim3(HW128/256,1,nb), 256, 0, stream>>>(E2p, embed2, Q2p, DIFF+0, HW128, S128);
    k_quant<<<dim3(HW64/256,1,nb), 256, 0, stream>>>(E3p, embed3, Q3p, DIFF+1, HW64, S64);
    k_convT_mfma<false,false><<<dim3(4,8,nb), 512, 0, stream>>>(Q3p, wb4_dd, SAp, 128, 128, S64, S128);
    k_conv<3,8><<<dim3(4,16,nb), 256, 0, stream>>>(SAp, wt_dd3, SBp, 128, 128, S128, S128);
    k_pw<<<dim3(HW128/1024,1,nb), 256, 0, stream>>>(SBp, wt_pw_dd, SBp, MMp, HW128, S128, mm128);
    k_attn_res<false><<<dim3(HW128/1024,1,nb), 256, 0, stream>>>(SBp, MMp, SAp, w_sa_dd, SAp, 128, 128, S128, mm128);
    k_squeeze<<<dim3(HW128/1024,1,nb), 256, 0, stream>>>(SAp, Q2p, wt_squ2, SBp, HW128, S128);
    k_convT_mfma<false,false><<<dim3(8,16,nb), 512, 0, stream>>>(SBp, wb4_dm, SAp, 256, 256, S128, S256);
    k_conv_mfma<5,false,false,false><<<dim3(8,16,nb), 512, 0, stream>>>(
        SAp, wb_dm5, wb_pw_dm, nullptr, SBp, MMp, 256, 256, S256, S256, mm256);
    k_attn_res<false><<<dim3(HW256/1024,1,nb), 256, 0, stream>>>(SBp, MMp, SAp, w_sa_dm, SAp, 256, 256, S256, mm256);
    k_squeeze<<<dim3(HW256/1024,1,nb), 256, 0, stream>>>(SAp, E1p, wt_squ1, D1p, HW256, S256);
  };

  // ---- phase 3: D1 -> outputs (U1/U2 bf16 @512) ----
  auto phase3 = [&](int c0, int nz, const float* D1p, const float* XLp){
    k_convT_mfma<false,true><<<dim3(16,32,nz), 512, 0, stream>>>(D1p, wb4_dt, U1b, 512, 512, S256, S512);
    k_conv_mfma<7,false,true,true><<<dim3(16,32,nz), 512, 0, stream>>>(
        U1b, wb_dt7, wb_pw_dt, nullptr, U2b, MM, 512, 512, S512, S512, 2*HW512);
    k_attn_res<true><<<dim3(HW512/1024,1,nz), 256, 0, stream>>>(U2b, MM, U1b, w_sa_dt, U1b, 512, 512, S512, 2*HW512);
    k_final<<<dim3(HW512/1024,1,nz), 256, 0, stream>>>(U1b, w_img_out, XLp,
                                                       OUT + (size_t)c0*HW512,
                                                       OUT + 2097152 + (size_t)c0*HW512,
                                                       HW512, S512);
  };

  if (CB > 0){
    for (int c0=0;c0<8;c0+=CB)
      phase1(c0, CB, XL + (size_t)c0*HW512, E1 + (size_t)c0*S256);
    deep(8, E1, U1, U2, E2, Q2, E3, Q3, MM, E1);
    for (int c0=0;c0<8;c0+=CB)
      phase3(c0, CB, E1 + (size_t)c0*S256, XL + (size_t)c0*HW512);
  } else {
    for (int b=0;b<8;b++){
      phase1(b, 1, XL, E1);
      deep(1, E1, U1, U2, E2, Q2, E3, Q3, MM, U2);
      phase3(b, 1, U2, XL);
    }
  }

  k_diff<<<1, 1, 0, stream>>>(DIFF, OUT + 4194304);
}

// Round 15
// 1440.392 us; speedup vs baseline: 1.1516x; 1.0224x over previous
//
#include <hip/hip_runtime.h>
#include <math.h>

#define CH 24

typedef __attribute__((ext_vector_type(8))) short short8v;
typedef __attribute__((ext_vector_type(4))) float f32x4;
typedef unsigned short ushort_t;
typedef unsigned int uint_t;

__device__ inline ushort_t bf16r(float f){
  uint_t u = __float_as_uint(f);
  u += 0x7FFF + ((u>>16)&1);
  return (ushort_t)(u>>16);
}
__device__ inline float bf2f(uint_t u){ return __uint_as_float(u<<16); }

// ================= weight reorder kernels =================
__global__ void k_r_res(const float* __restrict__ w, float* __restrict__ wT, int K){
  int i = blockIdx.x*256 + threadIdx.x;
  int n = 576*K*K; if (i >= n) return;
  int co = i % 24, ci = (i/24) % 24, kk = i/576;
  int ky = kk / K, kx = kk % K;
  wT[i] = w[((co*24+ci)*K+ky)*K+kx];
}
__global__ void k_r_pw(const float* __restrict__ w, float* __restrict__ wT, int CIN){
  int i = blockIdx.x*256 + threadIdx.x;
  if (i >= CIN*24) return;
  int co = i % 24, ci = i/24;
  wT[i] = w[co*CIN+ci];
}
__global__ void k_rmfma(const float* __restrict__ w, ushort_t* __restrict__ wb, int K){
  int i = blockIdx.x*256 + threadIdx.x;
  int n = K*K*1024; if (i >= n) return;
  int j = i & 7, l = (i>>3) & 63, t = (i>>9) & 1, tap = i >> 10;
  int ci = (l>>4)*8 + j, co = t*16 + (l&15);
  int ky = tap / K, kx = tap % K;
  float v = (ci<24 && co<24) ? w[((co*24+ci)*K+ky)*K+kx] : 0.f;
  wb[i] = bf16r(v);
}
__global__ void k_rmfma4(const float* __restrict__ w, ushort_t* __restrict__ wb){
  int i = blockIdx.x*256 + threadIdx.x;
  if (i >= 16384) return;
  int j = i & 7, l = (i>>3) & 63, t = (i>>9) & 1, tap = i >> 10;
  int ci = (l>>4)*8 + j, co = t*16 + (l&15);
  int ky = tap >> 2, kx = tap & 3;
  float v = (ci<24 && co<24) ? w[((ci*24+co)*4+ky)*4+kx] : 0.f;
  wb[i] = bf16r(v);
}

// ================= compute kernels =================

__global__ void k_lap(const float* __restrict__ x, float* __restrict__ xl, int H, int W){
  int idx = blockIdx.x*256 + threadIdx.x;
  int HW = H*W;
  if (idx >= HW) return;
  const float* xb = x + (size_t)blockIdx.z*3*HW;
  float* xo = xl + (size_t)blockIdx.z*HW;
  int px = idx % W, py = idx / W;
#define MEANV(yy,xx) (((yy)>=0&&(yy)<H&&(xx)>=0&&(xx)<W) ? (xb[(yy)*W+(xx)]+xb[HW+(yy)*W+(xx)]+xb[2*HW+(yy)*W+(xx)])*(1.f/3.f) : 0.f)
  float v = 4.f*MEANV(py,px) - MEANV(py-1,px) - MEANV(py+1,px) - MEANV(py,px-1) - MEANV(py,px+1);
#undef MEANV
  xo[idx] = v;
}

// ---------- MFMA KxK conv 24->24 FUSED with 1x1 pw + mean/max. 48B records. ----------
template<int K, bool EXPAND, bool INBF, bool OUTBF>
__launch_bounds__(512)
__global__ void k_conv_mfma(const void* in, const ushort_t* __restrict__ wb,
                            const ushort_t* __restrict__ wbpw, const float* __restrict__ wexp,
                            void* out, float* __restrict__ mm,
                            int H, int W, int istrIn, int istrOut, int istrMM){
  constexpr int SW_T = 32 + K - 1;
  constexpr int SH = 16 + K - 1;
  constexpr int NPX = SH*SW_T;
  __shared__ ushort_t lds[NPX*24];
  __shared__ uint_t sc[8][16*20];
  int tid = threadIdx.x;
  const float* inb_f = (const float*)in + (size_t)blockIdx.z*istrIn;
  const ushort_t* inb_b = (const ushort_t*)in + (size_t)blockIdx.z*istrIn;
  int x0g = blockIdx.x*32 - K/2, y0g = blockIdx.y*16 - K/2;
  int HW = H*W;
  for (int i = tid; i < NPX*3; i += 512){
    int q = i / NPX;
    int pp = i - q*NPX;
    int row = pp / SW_T, col = pp - row*SW_T;
    int gy = y0g + row, gx = x0g + col;
    uint4 w4; w4.x=0u; w4.y=0u; w4.z=0u; w4.w=0u;
    if (gy >= 0 && gy < H && gx >= 0 && gx < W){
      size_t base = (size_t)gy*W + gx;
      int c0 = q*8;
      if (EXPAND){
        float val = inb_f[base];
        w4.x = (uint_t)bf16r(val*wexp[c0+0]) | ((uint_t)bf16r(val*wexp[c0+1])<<16);
        w4.y = (uint_t)bf16r(val*wexp[c0+2]) | ((uint_t)bf16r(val*wexp[c0+3])<<16);
        w4.z = (uint_t)bf16r(val*wexp[c0+4]) | ((uint_t)bf16r(val*wexp[c0+5])<<16);
        w4.w = (uint_t)bf16r(val*wexp[c0+6]) | ((uint_t)bf16r(val*wexp[c0+7])<<16);
      } else if (INBF){
        uint_t u0=inb_b[(size_t)(c0+0)*HW+base], u1=inb_b[(size_t)(c0+1)*HW+base];
        uint_t u2=inb_b[(size_t)(c0+2)*HW+base], u3=inb_b[(size_t)(c0+3)*HW+base];
        uint_t u4=inb_b[(size_t)(c0+4)*HW+base], u5=inb_b[(size_t)(c0+5)*HW+base];
        uint_t u6=inb_b[(size_t)(c0+6)*HW+base], u7=inb_b[(size_t)(c0+7)*HW+base];
        w4.x = u0 | (u1<<16); w4.y = u2 | (u3<<16); w4.z = u4 | (u5<<16); w4.w = u6 | (u7<<16);
      } else {
        w4.x = (uint_t)bf16r(inb_f[(size_t)(c0+0)*HW+base]) | ((uint_t)bf16r(inb_f[(size_t)(c0+1)*HW+base])<<16);
        w4.y = (uint_t)bf16r(inb_f[(size_t)(c0+2)*HW+base]) | ((uint_t)bf16r(inb_f[(size_t)(c0+3)*HW+base])<<16);
        w4.z = (uint_t)bf16r(inb_f[(size_t)(c0+4)*HW+base]) | ((uint_t)bf16r(inb_f[(size_t)(c0+5)*HW+base])<<16);
        w4.w = (uint_t)bf16r(inb_f[(size_t)(c0+6)*HW+base]) | ((uint_t)bf16r(inb_f[(size_t)(c0+7)*HW+base])<<16);
      }
    }
    *(uint4*)(lds + (size_t)pp*24 + q*8) = w4;
  }
  __syncthreads();
  int l = tid & 63, wid = tid >> 6;
  int kg = l >> 4, li = l & 15;
  int kgc = (kg < 3) ? kg : 2;
  f32x4 zero = {0.f,0.f,0.f,0.f};
  f32x4 acc[4][2];
  #pragma unroll
  for (int i=0;i<4;i++){ acc[i][0]=zero; acc[i][1]=zero; }

  const ushort_t* aln = lds + li*24 + kgc*8 + (size_t)wid*SW_T*24;

  #pragma unroll
  for (int ky=0; ky<K; ky++){
    #pragma unroll
    for (int kx=0; kx<K; kx++){
      int tap = ky*K + kx;
      const ushort_t* wp = wb + (size_t)tap*1024;
      short8v b0 = *(const short8v*)(wp + l*8);
      short8v b1 = *(const short8v*)(wp + 512 + l*8);
      #pragma unroll
      for (int i=0;i<4;i++){
        const ushort_t* ap = aln + (((i&1)*8 + ky)*SW_T + (i>>1)*16 + kx)*24;
        short8v a = *(const short8v*)ap;
        acc[i][0] = __builtin_amdgcn_mfma_f32_16x16x32_bf16(a, b0, acc[i][0], 0, 0, 0);
        acc[i][1] = __builtin_amdgcn_mfma_f32_16x16x32_bf16(a, b1, acc[i][1], 0, 0, 0);
      }
    }
  }
  // ---- stage 2: pw 1x1 via second MFMA, + mean/max ----
  short8v bpw0 = *(const short8v*)(wbpw + l*8);
  short8v bpw1 = *(const short8v*)(wbpw + 512 + l*8);
  uint_t* s = sc[wid];
  float* outb_f = (float*)out + (size_t)blockIdx.z*istrOut;
  ushort_t* outb_b = (ushort_t*)out + (size_t)blockIdx.z*istrOut;
  float* mmb = mm + (size_t)blockIdx.z*istrMM;
  #pragma unroll 1
  for (int i=0;i<4;i++){
    __asm__ volatile("s_waitcnt lgkmcnt(0)" ::: "memory");
    __builtin_amdgcn_sched_barrier(0);
    #pragma unroll
    for (int reg=0; reg<4; reg++){
      float v0 = acc[i][0][reg], v1 = acc[i][1][reg];
      float v0n = __shfl_xor(v0, 1, 64);
      float v1n = __shfl_xor(v1, 1, 64);
      int pxr = kg*4 + reg;
      uint_t packed; int uidx;
      if ((li & 1) == 0){
        packed = (uint_t)bf16r(v0) | ((uint_t)bf16r(v0n) << 16);
        uidx = li >> 1;
      } else {
        packed = (uint_t)bf16r(v1n) | ((uint_t)bf16r(v1) << 16);
        uidx = 8 + (li >> 1);
      }
      s[pxr*20 + uidx] = packed;
    }
    __asm__ volatile("s_waitcnt lgkmcnt(0)" ::: "memory");
    __builtin_amdgcn_sched_barrier(0);
    short8v a2 = *(const short8v*)((const ushort_t*)s + li*40 + kg*8);
    f32x4 d0 = __builtin_amdgcn_mfma_f32_16x16x32_bf16(a2, bpw0, zero, 0, 0, 0);
    f32x4 d1 = __builtin_amdgcn_mfma_f32_16x16x32_bf16(a2, bpw1, zero, 0, 0, 0);
    int gy = blockIdx.y*16 + wid + (i&1)*8;
    int gx = blockIdx.x*32 + (i>>1)*16 + kg*4;
    if (OUTBF){
      uint2 p0; p0.x = (uint_t)bf16r(d0[0]) | ((uint_t)bf16r(d0[1])<<16);
      p0.y = (uint_t)bf16r(d0[2]) | ((uint_t)bf16r(d0[3])<<16);
      *(uint2*)(outb_b + (size_t)li*HW + (size_t)gy*W + gx) = p0;
      if (li < 8){
        uint2 p1; p1.x = (uint_t)bf16r(d1[0]) | ((uint_t)bf16r(d1[1])<<16);
        p1.y = (uint_t)bf16r(d1[2]) | ((uint_t)bf16r(d1[3])<<16);
        *(uint2*)(outb_b + (size_t)(16+li)*HW + (size_t)gy*W + gx) = p1;
      }
    } else {
      *(f32x4*)(outb_f + (size_t)li*HW + (size_t)gy*W + gx) = d0;
      if (li < 8)
        *(f32x4*)(outb_f + (size_t)(16+li)*HW + (size_t)gy*W + gx) = d1;
    }
    f32x4 sm, mx;
    #pragma unroll
    for (int reg=0; reg<4; reg++){
      sm[reg] = d0[reg] + d1[reg];
      mx[reg] = fmaxf(d0[reg], (li<8) ? d1[reg] : -3.4e38f);
    }
    #pragma unroll
    for (int m=1; m<16; m<<=1){
      #pragma unroll
      for (int reg=0; reg<4; reg++){
        sm[reg] += __shfl_xor(sm[reg], m, 64);
        mx[reg] = fmaxf(mx[reg], __shfl_xor(mx[reg], m, 64));
      }
    }
    if (li == 0){
      f32x4 me; me[0]=sm[0]*(1.f/24.f); me[1]=sm[1]*(1.f/24.f); me[2]=sm[2]*(1.f/24.f); me[3]=sm[3]*(1.f/24.f);
      *(f32x4*)(mmb + (size_t)gy*W + gx) = me;
      *(f32x4*)(mmb + (size_t)HW + (size_t)gy*W + gx) = mx;
    }
  }
}

// ---------- MFMA ConvTranspose2d(k=4,s=2,p=1), 32x16 out tile ----------
template<bool INBF, bool OUTBF>
__launch_bounds__(512)
__global__ void k_convT_mfma(const void* in, const ushort_t* __restrict__ wb,
                             void* out, int Ho, int Wo, int istrIn, int istrOut){
  const int Hi = Ho>>1, Wi = Wo>>1;
  constexpr int SW_T = 18, NPX = 180;
  __shared__ ushort_t lds[NPX*24];
  int tid = threadIdx.x;
  const float* inb_f = (const float*)in + (size_t)blockIdx.z*istrIn;
  const ushort_t* inb_b = (const ushort_t*)in + (size_t)blockIdx.z*istrIn;
  int X0 = blockIdx.x*32, Y0 = blockIdx.y*16;
  int ix0 = (X0>>1) - 1, iy0 = (Y0>>1) - 1;
  int HWi = Hi*Wi;
  for (int i = tid; i < NPX*3; i += 512){
    int q = i / NPX;
    int pp = i - q*NPX;
    int row = pp / SW_T, col = pp - row*SW_T;
    int gy = iy0 + row, gx = ix0 + col;
    uint4 w4; w4.x=0u; w4.y=0u; w4.z=0u; w4.w=0u;
    if (gy>=0 && gy<Hi && gx>=0 && gx<Wi){
      size_t base = (size_t)gy*Wi + gx;
      int c0 = q*8;
      if (INBF){
        uint_t u0=inb_b[(size_t)(c0+0)*HWi+base], u1=inb_b[(size_t)(c0+1)*HWi+base];
        uint_t u2=inb_b[(size_t)(c0+2)*HWi+base], u3=inb_b[(size_t)(c0+3)*HWi+base];
        uint_t u4=inb_b[(size_t)(c0+4)*HWi+base], u5=inb_b[(size_t)(c0+5)*HWi+base];
        uint_t u6=inb_b[(size_t)(c0+6)*HWi+base], u7=inb_b[(size_t)(c0+7)*HWi+base];
        w4.x = u0 | (u1<<16); w4.y = u2 | (u3<<16); w4.z = u4 | (u5<<16); w4.w = u6 | (u7<<16);
      } else {
        w4.x = (uint_t)bf16r(inb_f[(size_t)(c0+0)*HWi+base]) | ((uint_t)bf16r(inb_f[(size_t)(c0+1)*HWi+base])<<16);
        w4.y = (uint_t)bf16r(inb_f[(size_t)(c0+2)*HWi+base]) | ((uint_t)bf16r(inb_f[(size_t)(c0+3)*HWi+base])<<16);
        w4.z = (uint_t)bf16r(inb_f[(size_t)(c0+4)*HWi+base]) | ((uint_t)bf16r(inb_f[(size_t)(c0+5)*HWi+base])<<16);
        w4.w = (uint_t)bf16r(inb_f[(size_t)(c0+6)*HWi+base]) | ((uint_t)bf16r(inb_f[(size_t)(c0+7)*HWi+base])<<16);
      }
    }
    *(uint4*)(lds + (size_t)pp*24 + q*8) = w4;
  }
  __syncthreads();
  int l = tid & 63, wid = tid >> 6;
  int kg = l >> 4, li = l & 15;
  int kgc = (kg < 3) ? kg : 2;
  f32x4 zero = {0.f,0.f,0.f,0.f};
  f32x4 acc[4][2];
  #pragma unroll
  for (int i=0;i<4;i++){ acc[i][0]=zero; acc[i][1]=zero; }

  const ushort_t* aln = lds + li*24 + kgc*8;

  #pragma unroll
  for (int i=0;i<4;i++){
    int g = wid + 8*i;
    int r = g & 15, q = g >> 4;
    int ky0 = (r+1)&1;
    #pragma unroll
    for (int t2=0;t2<2;t2++){
      int ky = ky0 + 2*t2;
      int liy = ((r+1-ky)>>1) + 1;
      #pragma unroll
      for (int u=0;u<2;u++){
        int kx = (q ? 0 : 1) + 2*u;
        int lixb = ((q+1-kx)>>1) + 1;
        int tap = ky*4 + kx;
        const ushort_t* wp = wb + (size_t)tap*1024;
        short8v b0 = *(const short8v*)(wp + l*8);
        short8v b1 = *(const short8v*)(wp + 512 + l*8);
        short8v a = *(const short8v*)(aln + (liy*SW_T + lixb)*24);
        acc[i][0] = __builtin_amdgcn_mfma_f32_16x16x32_bf16(a, b0, acc[i][0], 0, 0, 0);
        acc[i][1] = __builtin_amdgcn_mfma_f32_16x16x32_bf16(a, b1, acc[i][1], 0, 0, 0);
      }
    }
  }
  float* outb_f = (float*)out + (size_t)blockIdx.z*istrOut;
  ushort_t* outb_b = (ushort_t*)out + (size_t)blockIdx.z*istrOut;
  int HWo = Ho*Wo;
  #pragma unroll
  for (int i=0;i<4;i++){
    int g = wid + 8*i;
    int r = g & 15, q = g >> 4;
    int oy = Y0 + r;
    #pragma unroll
    for (int reg=0; reg<4; reg++){
      int ox = X0 + 2*(kg*4 + reg) + q;
      if (OUTBF){
        outb_b[(size_t)li*HWo + (size_t)oy*Wo + ox] = bf16r(acc[i][0][reg]);
        if (li < 8)
          outb_b[(size_t)(16+li)*HWo + (size_t)oy*Wo + ox] = bf16r(acc[i][1][reg]);
      } else {
        outb_f[(size_t)li*HWo + (size_t)oy*Wo + ox] = acc[i][0][reg];
        if (li < 8)
          outb_f[(size_t)(16+li)*HWo + (size_t)oy*Wo + ox] = acc[i][1][reg];
      }
    }
  }
}

// ---------- MFMA 4x4 s2 p1 downsample, 16x8 out tile ----------
template<bool INBF, bool OUTBF>
__launch_bounds__(512)
__global__ void k_down_mfma(const void* in, const ushort_t* __restrict__ wb,
                            void* out, int Ho, int Wo, int istrIn, int istrOut){
  const int Hi = Ho*2, Wi = Wo*2;
  constexpr int NPX = 18*34;
  __shared__ ushort_t lds[NPX*24];
  int tid = threadIdx.x;
  const float* inb_f = (const float*)in + (size_t)blockIdx.z*istrIn;
  const ushort_t* inb_b = (const ushort_t*)in + (size_t)blockIdx.z*istrIn;
  int X0 = blockIdx.x*16, Y0 = blockIdx.y*8;
  int ix0 = 2*X0 - 1, iy0 = 2*Y0 - 1;
  int HWi = Hi*Wi;
  for (int i = tid; i < NPX*3; i += 512){
    int q = i / NPX;
    int pp = i - q*NPX;
    int row = pp / 34;
    int rem = pp - row*34;
    int par = (rem >= 17) ? 1 : 0;
    int sub = rem - par*17;
    int gx = ix0 + 2*sub + par;
    int gy = iy0 + row;
    uint4 w4; w4.x=0u; w4.y=0u; w4.z=0u; w4.w=0u;
    if (gy>=0 && gy<Hi && gx>=0 && gx<Wi){
      size_t base = (size_t)gy*Wi + gx;
      int c0 = q*8;
      if (INBF){
        uint_t u0=inb_b[(size_t)(c0+0)*HWi+base], u1=inb_b[(size_t)(c0+1)*HWi+base];
        uint_t u2=inb_b[(size_t)(c0+2)*HWi+base], u3=inb_b[(size_t)(c0+3)*HWi+base];
        uint_t u4=inb_b[(size_t)(c0+4)*HWi+base], u5=inb_b[(size_t)(c0+5)*HWi+base];
        uint_t u6=inb_b[(size_t)(c0+6)*HWi+base], u7=inb_b[(size_t)(c0+7)*HWi+base];
        w4.x = u0 | (u1<<16); w4.y = u2 | (u3<<16); w4.z = u4 | (u5<<16); w4.w = u6 | (u7<<16);
      } else {
        w4.x = (uint_t)bf16r(inb_f[(size_t)(c0+0)*HWi+base]) | ((uint_t)bf16r(inb_f[(size_t)(c0+1)*HWi+base])<<16);
        w4.y = (uint_t)bf16r(inb_f[(size_t)(c0+2)*HWi+base]) | ((uint_t)bf16r(inb_f[(size_t)(c0+3)*HWi+base])<<16);
        w4.z = (uint_t)bf16r(inb_f[(size_t)(c0+4)*HWi+base]) | ((uint_t)bf16r(inb_f[(size_t)(c0+5)*HWi+base])<<16);
        w4.w = (uint_t)bf16r(inb_f[(size_t)(c0+6)*HWi+base]) | ((uint_t)bf16r(inb_f[(size_t)(c0+7)*HWi+base])<<16);
      }
    }
    *(uint4*)(lds + (size_t)pp*24 + q*8) = w4;
  }
  __syncthreads();
  int l = tid & 63, wid = tid >> 6;
  int kg = l >> 4, li = l & 15;
  int kgc = (kg < 3) ? kg : 2;
  f32x4 zero = {0.f,0.f,0.f,0.f};
  f32x4 acc0 = zero, acc1 = zero;
  const ushort_t* aln = lds + li*24 + kgc*8 + (size_t)(2*wid)*34*24;
  #pragma unroll
  for (int ky=0; ky<4; ky++){
    #pragma unroll
    for (int kx=0; kx<4; kx++){
      int tap = ky*4 + kx;
      const ushort_t* wp = wb + (size_t)tap*1024;
      short8v b0 = *(const short8v*)(wp + l*8);
      short8v b1 = *(const short8v*)(wp + 512 + l*8);
      short8v a = *(const short8v*)(aln + (ky*34 + (kx&1)*17 + (kx>>1))*24);
      acc0 = __builtin_amdgcn_mfma_f32_16x16x32_bf16(a, b0, acc0, 0, 0, 0);
      acc1 = __builtin_amdgcn_mfma_f32_16x16x32_bf16(a, b1, acc1, 0, 0, 0);
    }
  }
  int HWo = Ho*Wo;
  int oy = Y0 + wid, ox = X0 + kg*4;
  if (OUTBF){
    ushort_t* outb = (ushort_t*)out + (size_t)blockIdx.z*istrOut;
    uint2 p0; p0.x = (uint_t)bf16r(acc0[0]) | ((uint_t)bf16r(acc0[1])<<16);
    p0.y = (uint_t)bf16r(acc0[2]) | ((uint_t)bf16r(acc0[3])<<16);
    *(uint2*)(outb + (size_t)li*HWo + (size_t)oy*Wo + ox) = p0;
    if (li < 8){
      uint2 p1; p1.x = (uint_t)bf16r(acc1[0]) | ((uint_t)bf16r(acc1[1])<<16);
      p1.y = (uint_t)bf16r(acc1[2]) | ((uint_t)bf16r(acc1[3])<<16);
      *(uint2*)(outb + (size_t)(16+li)*HWo + (size_t)oy*Wo + ox) = p1;
    }
  } else {
    float* outb = (float*)out + (size_t)blockIdx.z*istrOut;
    *(f32x4*)(outb + (size_t)li*HWo + (size_t)oy*Wo + ox) = acc0;
    if (li < 8)
      *(f32x4*)(outb + (size_t)(16+li)*HWo + (size_t)oy*Wo + ox) = acc1;
  }
}

// KxK conv fp32 (K=3 @128). wT=[ky][kx][ci][co]. Tile 32 x TH.
template<int K, int TH>
__launch_bounds__(256)
__global__ void k_conv(const float* __restrict__ in, const float* __restrict__ wT,
                       float* __restrict__ out, int H, int W, int istrIn, int istrOut){
  constexpr int TW = 32;
  constexpr int PX = (TW*TH)/256;
  constexpr int XT = TW/PX;
  constexpr int SW = TW + K - 1;
  constexpr int SWP = SW | 1;
  constexpr int SH = TH + K - 1;
  constexpr int CC = 8;
  __shared__ float tile[CC*SH*SWP];
  int tx = threadIdx.x % XT, ty = threadIdx.x / XT;
  int x0 = blockIdx.x*TW - K/2, y0 = blockIdx.y*TH - K/2;
  const float* inb = in + (size_t)blockIdx.z*istrIn;
  float acc[CH][PX];
  #pragma unroll
  for (int co=0;co<CH;co++)
    #pragma unroll
    for (int px=0;px<PX;px++) acc[co][px] = 0.f;

  #pragma unroll 1
  for (int c0=0;c0<CH;c0+=CC){
    __syncthreads();
    for (int i=threadIdx.x; i<CC*SH*SW; i+=256){
      int col = i % SW; int rr = i / SW; int row = rr % SH; int c = rr / SH;
      int gy = y0+row, gx = x0+col;
      tile[(c*SH+row)*SWP+col] = (gy>=0 && gy<H && gx>=0 && gx<W)
          ? inb[(size_t)(c0+c)*H*W + (size_t)gy*W + gx] : 0.f;
    }
    __syncthreads();
    #pragma unroll 1
    for (int ci=0;ci<CC;ci++){
      #pragma unroll 1
      for (int ky=0;ky<K;ky++){
        const float* trow = &tile[(ci*SH + ty+ky)*SWP + tx*PX];
        #pragma unroll
        for (int kx=0;kx<K;kx++){
          float v[PX];
          #pragma unroll
          for (int px=0;px<PX;px++) v[px] = trow[kx+px];
          const float* wp = wT + ((ky*K+kx)*24 + c0+ci)*24;
          #pragma unroll
          for (int co=0;co<CH;co++){
            float wv = wp[co];
            #pragma unroll
            for (int px=0;px<PX;px++) acc[co][px] = fmaf(v[px], wv, acc[co][px]);
          }
        }
      }
    }
  }
  int oy = blockIdx.y*TH+ty, ox = blockIdx.x*TW+tx*PX;
  float* ob = out + (size_t)blockIdx.z*istrOut + (size_t)oy*W + ox;
  #pragma unroll
  for (int co=0;co<CH;co++){
    if (PX == 2){
      float2 o; o.x=acc[co][0]; o.y=acc[co][1];
      *(float2*)(ob + (size_t)co*H*W) = o;
    } else {
      ob[(size_t)co*H*W] = acc[co][0];
    }
  }
}

__global__ void k_pw(const float* in, const float* __restrict__ wT,
                     float* out, float* __restrict__ mm, int HW, int istr, int istrMM){
  int p = (blockIdx.x*256 + threadIdx.x)*4;
  if (p >= HW) return;
  const float* ib = in + (size_t)blockIdx.z*istr;
  float acc[CH][4];
  #pragma unroll
  for (int co=0;co<CH;co++){ acc[co][0]=0;acc[co][1]=0;acc[co][2]=0;acc[co][3]=0; }
  #pragma unroll 1
  for (int ci=0;ci<CH;ci++){
    float4 v = *(const float4*)(ib + (size_t)ci*HW + p);
    const float* wp = wT + ci*24;
    #pragma unroll
    for (int co=0;co<CH;co++){
      float wv = wp[co];
      acc[co][0] = fmaf(v.x, wv, acc[co][0]);
      acc[co][1] = fmaf(v.y, wv, acc[co][1]);
      acc[co][2] = fmaf(v.z, wv, acc[co][2]);
      acc[co][3] = fmaf(v.w, wv, acc[co][3]);
    }
  }
  float mean[4]={0,0,0,0}, mx[4]={-3.4e38f,-3.4e38f,-3.4e38f,-3.4e38f};
  #pragma unroll
  for (int co=0;co<CH;co++)
    #pragma unroll
    for (int j=0;j<4;j++){ mean[j]+=acc[co][j]; mx[j]=fmaxf(mx[j],acc[co][j]); }
  float* ob = out + (size_t)blockIdx.z*istr;
  #pragma unroll
  for (int co=0;co<CH;co++){
    float4 o; o.x=acc[co][0]; o.y=acc[co][1]; o.z=acc[co][2]; o.w=acc[co][3];
    *(float4*)(ob + (size_t)co*HW + p) = o;
  }
  float* mb = mm + (size_t)blockIdx.z*istrMM;
  float4 me; me.x=mean[0]*(1.f/24.f); me.y=mean[1]*(1.f/24.f); me.z=mean[2]*(1.f/24.f); me.w=mean[3]*(1.f/24.f);
  float4 mxo; mxo.x=mx[0]; mxo.y=mx[1]; mxo.z=mx[2]; mxo.w=mx[3];
  *(float4*)(mb + p) = me;
  *(float4*)(mb + HW + p) = mxo;
}

// spatial attn + sigmoid + relu + residual add; BF: R/X/out are bf16 planes
template<bool BF>
__global__ void k_attn_res(const void* R_, const float* __restrict__ M,
                           const void* X_, const float* __restrict__ wsa,
                           void* out_, int H, int W, int istr, int istrMM){
  int p = (blockIdx.x*256 + threadIdx.x)*4;
  int HW = H*W;
  if (p >= HW) return;
  int py = p / W, px0 = p % W;
  const float* Mb = M + (size_t)blockIdx.z*istrMM;
  float s[4]={0,0,0,0};
  #pragma unroll
  for (int cc=0;cc<2;cc++){
    const float* Mc = Mb + (size_t)cc*HW;
    #pragma unroll 1
    for (int ky=0;ky<7;ky++){
      int gy = py+ky-3;
      if (gy<0||gy>=H) continue;
      const float* mr = Mc + (size_t)gy*W;
      float mv[10];
      #pragma unroll
      for (int j=0;j<10;j++){
        int gx = px0-3+j;
        mv[j] = (gx>=0 && gx<W) ? mr[gx] : 0.f;
      }
      const float* wr = wsa + (cc*7+ky)*7;
      #pragma unroll
      for (int kx=0;kx<7;kx++){
        float wv = wr[kx];
        #pragma unroll
        for (int px=0;px<4;px++) s[px] = fmaf(mv[kx+px], wv, s[px]);
      }
    }
  }
  float g[4];
  #pragma unroll
  for (int px=0;px<4;px++) g[px] = 1.f/(1.f+expf(-s[px]));
  #pragma unroll
  for (int c=0;c<CH;c++){
    float r0,r1,r2,r3, x0v,x1v,x2v,x3v;
    if (BF){
      const ushort_t* Rb = (const ushort_t*)R_ + (size_t)blockIdx.z*istr + (size_t)c*HW + p;
      const ushort_t* Xb = (const ushort_t*)X_ + (size_t)blockIdx.z*istr + (size_t)c*HW + p;
      uint2 rv = *(const uint2*)Rb;
      uint2 xv = *(const uint2*)Xb;
      r0=bf2f(rv.x&0xffffu); r1=bf2f(rv.x>>16); r2=bf2f(rv.y&0xffffu); r3=bf2f(rv.y>>16);
      x0v=bf2f(xv.x&0xffffu); x1v=bf2f(xv.x>>16); x2v=bf2f(xv.y&0xffffu); x3v=bf2f(xv.y>>16);
    } else {
      const float* Rb = (const float*)R_ + (size_t)blockIdx.z*istr + (size_t)c*HW + p;
      const float* Xb = (const float*)X_ + (size_t)blockIdx.z*istr + (size_t)c*HW + p;
      float4 rv = *(const float4*)Rb;
      float4 xv = *(const float4*)Xb;
      r0=rv.x; r1=rv.y; r2=rv.z; r3=rv.w;
      x0v=xv.x; x1v=xv.y; x2v=xv.z; x3v=xv.w;
    }
    float o0 = x0v + fmaxf(r0*g[0], 0.f);
    float o1 = x1v + fmaxf(r1*g[1], 0.f);
    float o2 = x2v + fmaxf(r2*g[2], 0.f);
    float o3 = x3v + fmaxf(r3*g[3], 0.f);
    if (BF){
      ushort_t* Ob = (ushort_t*)out_ + (size_t)blockIdx.z*istr + (size_t)c*HW + p;
      uint2 ov;
      ov.x = (uint_t)bf16r(o0) | ((uint_t)bf16r(o1)<<16);
      ov.y = (uint_t)bf16r(o2) | ((uint_t)bf16r(o3)<<16);
      *(uint2*)Ob = ov;
    } else {
      float* Ob = (float*)out_ + (size_t)blockIdx.z*istr + (size_t)c*HW + p;
      float4 ov; ov.x=o0; ov.y=o1; ov.z=o2; ov.w=o3;
      *(float4*)Ob = ov;
    }
  }
}

// variant: residual computed from XL*wexp; BF: R/out bf16
template<bool BF>
__global__ void k_attn_res_x(const void* R_, const float* __restrict__ M,
                             const float* __restrict__ XL, const float* __restrict__ wsa,
                             const float* __restrict__ wexp,
                             void* out_, int H, int W, int istr, int istrMM){
  int p = (blockIdx.x*256 + threadIdx.x)*4;
  int HW = H*W;
  if (p >= HW) return;
  int py = p / W, px0 = p % W;
  const float* Mb = M + (size_t)blockIdx.z*istrMM;
  float s[4]={0,0,0,0};
  #pragma unroll
  for (int cc=0;cc<2;cc++){
    const float* Mc = Mb + (size_t)cc*HW;
    #pragma unroll 1
    for (int ky=0;ky<7;ky++){
      int gy = py+ky-3;
      if (gy<0||gy>=H) continue;
      const float* mr = Mc + (size_t)gy*W;
      float mv[10];
      #pragma unroll
      for (int j=0;j<10;j++){
        int gx = px0-3+j;
        mv[j] = (gx>=0 && gx<W) ? mr[gx] : 0.f;
      }
      const float* wr = wsa + (cc*7+ky)*7;
      #pragma unroll
      for (int kx=0;kx<7;kx++){
        float wv = wr[kx];
        #pragma unroll
        for (int px=0;px<4;px++) s[px] = fmaf(mv[kx+px], wv, s[px]);
      }
    }
  }
  float g[4];
  #pragma unroll
  for (int px=0;px<4;px++) g[px] = 1.f/(1.f+expf(-s[px]));
  float4 xl4 = *(const float4*)(XL + (size_t)blockIdx.z*HW + p);
  #pragma unroll
  for (int c=0;c<CH;c++){
    float wc = wexp[c];
    float r0,r1,r2,r3;
    if (BF){
      const ushort_t* Rb = (const ushort_t*)R_ + (size_t)blockIdx.z*istr + (size_t)c*HW + p;
      uint2 rv = *(const uint2*)Rb;
      r0=bf2f(rv.x&0xffffu); r1=bf2f(rv.x>>16); r2=bf2f(rv.y&0xffffu); r3=bf2f(rv.y>>16);
    } else {
      const float* Rb = (const float*)R_ + (size_t)blockIdx.z*istr + (size_t)c*HW + p;
      float4 rv = *(const float4*)Rb;
      r0=rv.x; r1=rv.y; r2=rv.z; r3=rv.w;
    }
    float o0 = xl4.x*wc + fmaxf(r0*g[0], 0.f);
    float o1 = xl4.y*wc + fmaxf(r1*g[1], 0.f);
    float o2 = xl4.z*wc + fmaxf(r2*g[2], 0.f);
    float o3 = xl4.w*wc + fmaxf(r3*g[3], 0.f);
    if (BF){
      ushort_t* Ob = (ushort_t*)out_ + (size_t)blockIdx.z*istr + (size_t)c*HW + p;
      uint2 ov;
      ov.x = (uint_t)bf16r(o0) | ((uint_t)bf16r(o1)<<16);
      ov.y = (uint_t)bf16r(o2) | ((uint_t)bf16r(o3)<<16);
      *(uint2*)Ob = ov;
    } else {
      float* Ob = (float*)out_ + (size_t)blockIdx.z*istr + (size_t)c*HW + p;
      float4 ov; ov.x=o0; ov.y=o1; ov.z=o2; ov.w=o3;
      *(float4*)Ob = ov;
    }
  }
}

// 1x1 conv 48->24 over concat(A,B); BF: all planes bf16
template<bool BF>
__global__ void k_squeeze(const void* inA_, const void* inB_,
                          const float* __restrict__ wT, void* out_, int HW, int istr){
  int p = (blockIdx.x*256 + threadIdx.x)*4;
  if (p >= HW) return;
  float acc[CH][4];
  #pragma unroll
  for (int co=0;co<CH;co++){ acc[co][0]=0;acc[co][1]=0;acc[co][2]=0;acc[co][3]=0; }
  #pragma unroll 1
  for (int ci=0;ci<48;ci++){
    float v0,v1,v2,v3;
    if (BF){
      const ushort_t* src = (ci<24)
        ? ((const ushort_t*)inA_ + (size_t)blockIdx.z*istr + (size_t)ci*HW + p)
        : ((const ushort_t*)inB_ + (size_t)blockIdx.z*istr + (size_t)(ci-24)*HW + p);
      uint2 rv = *(const uint2*)src;
      v0=bf2f(rv.x&0xffffu); v1=bf2f(rv.x>>16); v2=bf2f(rv.y&0xffffu); v3=bf2f(rv.y>>16);
    } else {
      const float* src = (ci<24)
        ? ((const float*)inA_ + (size_t)blockIdx.z*istr + (size_t)ci*HW + p)
        : ((const float*)inB_ + (size_t)blockIdx.z*istr + (size_t)(ci-24)*HW + p);
      float4 rv = *(const float4*)src;
      v0=rv.x; v1=rv.y; v2=rv.z; v3=rv.w;
    }
    const float* wp = wT + ci*24;
    #pragma unroll
    for (int co=0;co<CH;co++){
      float wv = wp[co];
      acc[co][0] = fmaf(v0, wv, acc[co][0]);
      acc[co][1] = fmaf(v1, wv, acc[co][1]);
      acc[co][2] = fmaf(v2, wv, acc[co][2]);
      acc[co][3] = fmaf(v3, wv, acc[co][3]);
    }
  }
  #pragma unroll
  for (int co=0;co<CH;co++){
    if (BF){
      ushort_t* ob = (ushort_t*)out_ + (size_t)blockIdx.z*istr + (size_t)co*HW + p;
      uint2 ov;
      ov.x = (uint_t)bf16r(acc[co][0]) | ((uint_t)bf16r(acc[co][1])<<16);
      ov.y = (uint_t)bf16r(acc[co][2]) | ((uint_t)bf16r(acc[co][3])<<16);
      *(uint2*)ob = ov;
    } else {
      float* ob = (float*)out_ + (size_t)blockIdx.z*istr + (size_t)co*HW + p;
      float4 o; o.x=acc[co][0]; o.y=acc[co][1]; o.z=acc[co][2]; o.w=acc[co][3];
      *(float4*)ob = o;
    }
  }
}

__global__ void k_quant(const float* __restrict__ enc, const float* __restrict__ embed,
                        float* __restrict__ qt, float* __restrict__ diffAcc, int HW, int istr){
  __shared__ float em[256*28];
  __shared__ float red[4];
  {
    int j = threadIdx.x;
    float s = 0.f;
    #pragma unroll
    for (int c=0;c<CH;c++){
      float e = embed[c*256+j];
      em[j*28+c] = -2.0f*e;
      s = fmaf(e,e,s);
    }
    em[j*28+24] = s; em[j*28+25]=0.f; em[j*28+26]=0.f; em[j*28+27]=0.f;
  }
  __syncthreads();
  int p = blockIdx.x*256 + threadIdx.x;
  const float* eb = enc + (size_t)blockIdx.z*istr;
  float f[CH];
  #pragma unroll
  for (int c=0;c<CH;c++) f[c] = eb[(size_t)c*HW + p];
  float best = 3.4e38f; int bj = 0;
  #pragma unroll 1
  for (int j=0;j<256;j++){
    const float4* row = (const float4*)&em[j*28];
    float s = em[j*28+24];
    #pragma unroll
    for (int q4=0;q4<6;q4++){
      float4 r = row[q4];
      s = fmaf(f[q4*4+0], r.x, s);
      s = fmaf(f[q4*4+1], r.y, s);
      s = fmaf(f[q4*4+2], r.z, s);
      s = fmaf(f[q4*4+3], r.w, s);
    }
    if (s < best){ best = s; bj = j; }
  }
  float* qb = qt + (size_t)blockIdx.z*istr;
  float d = 0.f;
  #pragma unroll
  for (int c=0;c<CH;c++){
    float q = embed[c*256+bj];
    qb[(size_t)c*HW + p] = q;
    float e = q - f[c];
    d = fmaf(e,e,d);
  }
  #pragma unroll
  for (int off=32; off>0; off>>=1) d += __shfl_down(d, off, 64);
  int lane = threadIdx.x & 63, wv = threadIdx.x >> 6;
  if (lane==0) red[wv] = d;
  __syncthreads();
  if (threadIdx.x==0) atomicAdd(diffAcc, red[0]+red[1]+red[2]+red[3]);
}

// final: dec1 is bf16 planes; mask = 1x1(24->1), clean = xl - mask
__global__ void k_final(const ushort_t* __restrict__ dec1, const float* __restrict__ w,
                        const float* __restrict__ xl, float* __restrict__ outMask,
                        float* __restrict__ outClean, int HW, int dstr){
  int p = (blockIdx.x*256 + threadIdx.x)*4;
  if (p >= HW) return;
  const ushort_t* db = dec1 + (size_t)blockIdx.z*dstr;
  float m[4]={0,0,0,0};
  #pragma unroll
  for (int c=0;c<CH;c++){
    uint2 dv = *(const uint2*)(db + (size_t)c*HW + p);
    float wc = w[c];
    m[0]=fmaf(bf2f(dv.x&0xffffu),wc,m[0]);
    m[1]=fmaf(bf2f(dv.x>>16),wc,m[1]);
    m[2]=fmaf(bf2f(dv.y&0xffffu),wc,m[2]);
    m[3]=fmaf(bf2f(dv.y>>16),wc,m[3]);
  }
  float4 xv = *(const float4*)(xl + (size_t)blockIdx.z*HW + p);
  float4 mo; mo.x=m[0]; mo.y=m[1]; mo.z=m[2]; mo.w=m[3];
  float4 co; co.x=xv.x-m[0]; co.y=xv.y-m[1]; co.z=xv.z-m[2]; co.w=xv.w-m[3];
  *(float4*)(outMask + (size_t)blockIdx.z*HW + p) = mo;
  *(float4*)(outClean + (size_t)blockIdx.z*HW + p) = co;
}

__global__ void k_diff(const float* __restrict__ acc, float* __restrict__ out){
  out[0] = acc[0]*(1.f/3145728.f) + acc[1]*(1.f/786432.f);
}

// =======================================================================
extern "C" void kernel_launch(void* const* d_in, const int* in_sizes, int n_in,
                              void* d_out, int out_size, void* d_ws, size_t ws_size,
                              hipStream_t stream) {
  const float* x        = (const float*)d_in[0];
  const float* embed2   = (const float*)d_in[1];
  const float* embed3   = (const float*)d_in[2];
  const float* w_img_in = (const float*)d_in[3];
  const float* w_img_out= (const float*)d_in[4];
  const float* w_out_dd = (const float*)d_in[5];
  const float* w_out_dm = (const float*)d_in[6];
  const float* w_out_dt = (const float*)d_in[7];
  const float* w_out_ed = (const float*)d_in[8];
  const float* w_out_em = (const float*)d_in[9];
  const float* w_out_et = (const float*)d_in[10];
  const float* w_pw_dd  = (const float*)d_in[11];
  const float* w_pw_dm  = (const float*)d_in[12];
  const float* w_pw_dt  = (const float*)d_in[13];
  const float* w_pw_ed  = (const float*)d_in[14];
  const float* w_pw_em  = (const float*)d_in[15];
  const float* w_pw_et  = (const float*)d_in[16];
  const float* w_res_dd = (const float*)d_in[17];
  const float* w_res_dm = (const float*)d_in[18];
  const float* w_res_dt = (const float*)d_in[19];
  const float* w_res_ed = (const float*)d_in[20];
  const float* w_res_em = (const float*)d_in[21];
  const float* w_res_et = (const float*)d_in[22];
  const float* w_sa_dd  = (const float*)d_in[23];
  const float* w_sa_dm  = (const float*)d_in[24];
  const float* w_sa_dt  = (const float*)d_in[25];
  const float* w_sa_ed  = (const float*)d_in[26];
  const float* w_sa_em  = (const float*)d_in[27];
  const float* w_sa_et  = (const float*)d_in[28];
  const float* w_squ1   = (const float*)d_in[29];
  const float* w_squ2   = (const float*)d_in[30];
  (void)in_sizes; (void)n_in; (void)out_size;

  const int HW512 = 512*512, HW256 = 256*256, HW128 = 128*128, HW64 = 64*64;
  const int S512 = 24*HW512, S256 = 24*HW256, S128 = 24*HW128, S64 = 24*HW64;

  float* ws = (float*)d_ws;
  float* OUT = (float*)d_out;
  size_t F = ws_size / sizeof(float);

  // fp32-reordered weights
  float* WT      = ws;
  float* wt_ed3  = WT + 85248;
  float* wt_dd3  = WT + 90432;
  float* wt_pw_ed= WT + 152064;
  float* wt_pw_dd= WT + 152640;
  float* wt_squ1 = WT + 154368;
  float* wt_squ2 = WT + 155520;

  // MFMA bf16 B-frag weights
  ushort_t* WB = (ushort_t*)(ws + 160000);
  ushort_t* wb_et7   = WB;
  ushort_t* wb_dt7   = WB + 50176;
  ushort_t* wb_em5   = WB + 100352;
  ushort_t* wb_dm5   = WB + 125952;
  ushort_t* wb_pw_et = WB + 151552;
  ushort_t* wb_pw_em = WB + 152576;
  ushort_t* wb_pw_dm = WB + 153600;
  ushort_t* wb_pw_dt = WB + 154624;
  ushort_t* wb4_dd   = WB + 155648;
  ushort_t* wb4_dm   = WB + 172032;
  ushort_t* wb4_dt   = WB + 188416;
  ushort_t* wb4d_et  = WB + 204800;
  ushort_t* wb4d_em  = WB + 221184;
  ushort_t* wb4d_ed  = WB + 237568;

  const size_t ABASE = 290000;

  auto needBatched = [&](size_t CB)->size_t{
    // U1/U2 union (floats): bf16 @512 CB*S512/2; bf16 @256 8*S256/2=4*S256; fp32 @128 8*S128
    size_t u_f = (CB*(size_t)S512 + 1)/2;
    if ((size_t)4*S256 > u_f) u_f = (size_t)4*S256;
    if ((size_t)8*S128 > u_f) u_f = (size_t)8*S128;
    // E1 bf16: 8*S256 ushorts = 4*S256 floats
    return ABASE + 2097152 + (size_t)4*S256 + 3145728 + 786432 + CB*524288 + 2*u_f + 2;
  };
  int CB = 0;
  if (F >= needBatched(8)) CB = 8;
  else if (F >= needBatched(4)) CB = 4;
  else if (F >= needBatched(2)) CB = 2;
  const size_t NEED_B = ABASE + 15925250;
  if (CB == 0 && F < NEED_B) return;

  float *XL, *E2, *Q2, *E3, *Q3, *MM, *DIFF, *U1, *U2;
  ushort_t* E1b;
  if (CB > 0){
    size_t off = ABASE;
    size_t u_f = (CB*(size_t)S512 + 1)/2;
    if ((size_t)4*S256 > u_f) u_f = (size_t)4*S256;
    if ((size_t)8*S128 > u_f) u_f = (size_t)8*S128;
    XL = ws + off; off += 2097152;
    E1b = (ushort_t*)(ws + off); off += (size_t)4*S256;
    Q2 = ws + off; off += 3145728;
    Q3 = ws + off; off += 786432;
    MM = ws + off; off += CB*524288;
    U1 = ws + off; off += u_f;
    U2 = ws + off; off += u_f;
    DIFF = ws + off;
    E2 = OUT;
    E3 = OUT + 3145728;
  } else {
    size_t off = ABASE;
    XL = ws + off; off += 262144;
    U1 = ws + off; off += 6291456;
    U2 = ws + off; off += 6291456;
    E1b = (ushort_t*)(ws + off); off += 1572864;
    E2 = ws + off; off += 393216;
    Q2 = ws + off; off += 393216;
    E3 = ws + off; off += 98304;
    Q3 = ws + off; off += 98304;
    MM = ws + off; off += 524288;
    DIFF = ws + off;
  }
  ushort_t* U1b = (ushort_t*)U1;
  ushort_t* U2b = (ushort_t*)U2;

  // ---- weight reorders ----
  k_rmfma<<<dim3(196), 256, 0, stream>>>(w_res_et, wb_et7, 7);
  k_rmfma<<<dim3(196), 256, 0, stream>>>(w_res_dt, wb_dt7, 7);
  k_rmfma<<<dim3(100), 256, 0, stream>>>(w_res_em, wb_em5, 5);
  k_rmfma<<<dim3(100), 256, 0, stream>>>(w_res_dm, wb_dm5, 5);
  k_rmfma<<<dim3(4), 256, 0, stream>>>(w_pw_et, wb_pw_et, 1);
  k_rmfma<<<dim3(4), 256, 0, stream>>>(w_pw_em, wb_pw_em, 1);
  k_rmfma<<<dim3(4), 256, 0, stream>>>(w_pw_dm, wb_pw_dm, 1);
  k_rmfma<<<dim3(4), 256, 0, stream>>>(w_pw_dt, wb_pw_dt, 1);
  k_rmfma4<<<dim3(64), 256, 0, stream>>>(w_out_dd, wb4_dd);
  k_rmfma4<<<dim3(64), 256, 0, stream>>>(w_out_dm, wb4_dm);
  k_rmfma4<<<dim3(64), 256, 0, stream>>>(w_out_dt, wb4_dt);
  k_rmfma<<<dim3(64), 256, 0, stream>>>(w_out_et, wb4d_et, 4);
  k_rmfma<<<dim3(64), 256, 0, stream>>>(w_out_em, wb4d_em, 4);
  k_rmfma<<<dim3(64), 256, 0, stream>>>(w_out_ed, wb4d_ed, 4);
  k_r_res<<<dim3((576*9+255)/256), 256, 0, stream>>>(w_res_ed, wt_ed3, 3);
  k_r_res<<<dim3((576*9+255)/256), 256, 0, stream>>>(w_res_dd, wt_dd3, 3);
  k_r_pw<<<dim3(3), 256, 0, stream>>>(w_pw_ed, wt_pw_ed, 24);
  k_r_pw<<<dim3(3), 256, 0, stream>>>(w_pw_dd, wt_pw_dd, 24);
  k_r_pw<<<dim3(5), 256, 0, stream>>>(w_squ1, wt_squ1, 48);
  k_r_pw<<<dim3(5), 256, 0, stream>>>(w_squ2, wt_squ2, 48);

  hipMemsetAsync(DIFF, 0, 2*sizeof(float), stream);

  // ---- phase 1: input -> enc1 (E1 bf16) ----
  auto phase1 = [&](int c0, int nz, float* XLp, ushort_t* E1p){
    k_lap<<<dim3(HW512/256,1,nz), 256, 0, stream>>>(x + (size_t)c0*3*HW512, XLp, 512, 512);
    k_conv_mfma<7,true,false,true><<<dim3(16,32,nz), 512, 0, stream>>>(
        XLp, wb_et7, wb_pw_et, w_img_in, U2b, MM, 512, 512, HW512, S512, 2*HW512);
    k_attn_res_x<true><<<dim3(HW512/1024,1,nz), 256, 0, stream>>>(
        U2b, MM, XLp, w_sa_et, w_img_in, U1b, 512, 512, S512, 2*HW512);
    k_down_mfma<true,true><<<dim3(16,32,nz), 512, 0, stream>>>(U1b, wb4d_et, E1p, 256, 256, S512, S256);
  };

  // ---- deep: enc1 -> squ1 output (bf16 @256, fp32 @128) ----
  auto deep = [&](int nb, ushort_t* E1p, float* SAp, float* SBp, float* E2p, float* Q2p,
                  float* E3p, float* Q3p, float* MMp, ushort_t* D1p){
    ushort_t* SAb = (ushort_t*)SAp;
    ushort_t* SBb = (ushort_t*)SBp;
    int mm256 = 2*HW256, mm128 = 2*HW128;
    k_conv_mfma<5,false,true,true><<<dim3(8,16,nb), 512, 0, stream>>>(
        E1p, wb_em5, wb_pw_em, nullptr, SAb, MMp, 256, 256, S256, S256, mm256);
    k_attn_res<true><<<dim3(HW256/1024,1,nb), 256, 0, stream>>>(SAb, MMp, E1p, w_sa_em, SBb, 256, 256, S256, mm256);
    k_down_mfma<true,false><<<dim3(8,16,nb), 512, 0, stream>>>(SBb, wb4d_em, E2p, 128, 128, S256, S128);
    k_conv<3,8><<<dim3(4,16,nb), 256, 0, stream>>>(E2p, wt_ed3, SAp, 128, 128, S128, S128);
    k_pw<<<dim3(HW128/1024,1,nb), 256, 0, stream>>>(SAp, wt_pw_ed, SAp, MMp, HW128, S128, mm128);
    k_attn_res<false><<<dim3(HW128/1024,1,nb), 256, 0, stream>>>(SAp, MMp, E2p, w_sa_ed, SBp, 128, 128, S128, mm128);
    k_down_mfma<false,false><<<dim3(4,8,nb), 512, 0, stream>>>(SBp, wb4d_ed, E3p, 64, 64, S128, S64);
    k_quant<<<dim3(HW128/256,1,nb), 256, 0, stream>>>(E2p, embed2, Q2p, DIFF+0, HW128, S128);
    k_quant<<<dim3(HW64/256,1,nb), 256, 0, stream>>>(E3p, embed3, Q3p, DIFF+1, HW64, S64);
    k_convT_mfma<false,false><<<dim3(4,8,nb), 512, 0, stream>>>(Q3p, wb4_dd, SAp, 128, 128, S64, S128);
    k_conv<3,8><<<dim3(4,16,nb), 256, 0, stream>>>(SAp, wt_dd3, SBp, 128, 128, S128, S128);
    k_pw<<<dim3(HW128/1024,1,nb), 256, 0, stream>>>(SBp, wt_pw_dd, SBp, MMp, HW128, S128, mm128);
    k_attn_res<false><<<dim3(HW128/1024,1,nb), 256, 0, stream>>>(SBp, MMp, SAp, w_sa_dd, SAp, 128, 128, S128, mm128);
    k_squeeze<false><<<dim3(HW128/1024,1,nb), 256, 0, stream>>>(SAp, Q2p, wt_squ2, SBp, HW128, S128);
    k_convT_mfma<false,true><<<dim3(8,16,nb), 512, 0, stream>>>(SBp, wb4_dm, SAb, 256, 256, S128, S256);
    k_conv_mfma<5,false,true,true><<<dim3(8,16,nb), 512, 0, stream>>>(
        SAb, wb_dm5, wb_pw_dm, nullptr, SBb, MMp, 256, 256, S256, S256, mm256);
    k_attn_res<true><<<dim3(HW256/1024,1,nb), 256, 0, stream>>>(SBb, MMp, SAb, w_sa_dm, SAb, 256, 256, S256, mm256);
    k_squeeze<true><<<dim3(HW256/1024,1,nb), 256, 0, stream>>>(SAb, E1p, wt_squ1, D1p, HW256, S256);
  };

  // ---- phase 3: D1 (bf16) -> outputs ----
  auto phase3 = [&](int c0, int nz, const ushort_t* D1p, const float* XLp){
    k_convT_mfma<true,true><<<dim3(16,32,nz), 512, 0, stream>>>(D1p, wb4_dt, U1b, 512, 512, S256, S512);
    k_conv_mfma<7,false,true,true><<<dim3(16,32,nz), 512, 0, stream>>>(
        U1b, wb_dt7, wb_pw_dt, nullptr, U2b, MM, 512, 512, S512, S512, 2*HW512);
    k_attn_res<true><<<dim3(HW512/1024,1,nz), 256, 0, stream>>>(U2b, MM, U1b, w_sa_dt, U1b, 512, 512, S512, 2*HW512);
    k_final<<<dim3(HW512/1024,1,nz), 256, 0, stream>>>(U1b, w_img_out, XLp,
                                                       OUT + (size_t)c0*HW512,
                                                       OUT + 2097152 + (size_t)c0*HW512,
                                                       HW512, S512);
  };

  if (CB > 0){
    for (int c0=0;c0<8;c0+=CB)
      phase1(c0, CB, XL + (size_t)c0*HW512, E1b + (size_t)c0*S256);
    deep(8, E1b, U1, U2, E2, Q2, E3, Q3, MM, E1b);
    for (int c0=0;c0<8;c0+=CB)
      phase3(c0, CB, E1b + (size_t)c0*S256, XL + (size_t)c0*HW512);
  } else {
    for (int b=0;b<8;b++){
      phase1(b, 1, XL, E1b);
      deep(1, E1b, U1, U2, E2, Q2, E3, Q3, MM, (ushort_t*)U2);
      phase3(b, 1, (ushort_t*)U2, XL);
    }
  }

  k_diff<<<1, 1, 0, stream>>>(DIFF, OUT + 4194304);
}

// Round 16
// 1311.087 us; speedup vs baseline: 1.2652x; 1.0986x over previous
//
#include <hip/hip_runtime.h>
#include <math.h>

#define CH 24

typedef __attribute__((ext_vector_type(8))) short short8v;
typedef __attribute__((ext_vector_type(4))) float f32x4;
typedef unsigned short ushort_t;
typedef unsigned int uint_t;

__device__ inline ushort_t bf16r(float f){
  uint_t u = __float_as_uint(f);
  u += 0x7FFF + ((u>>16)&1);
  return (ushort_t)(u>>16);
}
__device__ inline float bf2f(uint_t u){ return __uint_as_float(u<<16); }

// ================= weight reorder kernels =================
__global__ void k_r_pw(const float* __restrict__ w, float* __restrict__ wT, int CIN){
  int i = blockIdx.x*256 + threadIdx.x;
  if (i >= CIN*24) return;
  int co = i % 24, ci = i/24;
  wT[i] = w[co*CIN+ci];
}
__global__ void k_rmfma(const float* __restrict__ w, ushort_t* __restrict__ wb, int K){
  int i = blockIdx.x*256 + threadIdx.x;
  int n = K*K*1024; if (i >= n) return;
  int j = i & 7, l = (i>>3) & 63, t = (i>>9) & 1, tap = i >> 10;
  int ci = (l>>4)*8 + j, co = t*16 + (l&15);
  int ky = tap / K, kx = tap % K;
  float v = (ci<24 && co<24) ? w[((co*24+ci)*K+ky)*K+kx] : 0.f;
  wb[i] = bf16r(v);
}
__global__ void k_rmfma4(const float* __restrict__ w, ushort_t* __restrict__ wb){
  int i = blockIdx.x*256 + threadIdx.x;
  if (i >= 16384) return;
  int j = i & 7, l = (i>>3) & 63, t = (i>>9) & 1, tap = i >> 10;
  int ci = (l>>4)*8 + j, co = t*16 + (l&15);
  int ky = tap >> 2, kx = tap & 3;
  float v = (ci<24 && co<24) ? w[((ci*24+co)*4+ky)*4+kx] : 0.f;
  wb[i] = bf16r(v);
}

// ================= compute kernels =================

__global__ void k_lap(const float* __restrict__ x, float* __restrict__ xl, int H, int W){
  int idx = blockIdx.x*256 + threadIdx.x;
  int HW = H*W;
  if (idx >= HW) return;
  const float* xb = x + (size_t)blockIdx.z*3*HW;
  float* xo = xl + (size_t)blockIdx.z*HW;
  int px = idx % W, py = idx / W;
#define MEANV(yy,xx) (((yy)>=0&&(yy)<H&&(xx)>=0&&(xx)<W) ? (xb[(yy)*W+(xx)]+xb[HW+(yy)*W+(xx)]+xb[2*HW+(yy)*W+(xx)])*(1.f/3.f) : 0.f)
  float v = 4.f*MEANV(py,px) - MEANV(py-1,px) - MEANV(py+1,px) - MEANV(py,px-1) - MEANV(py,px+1);
#undef MEANV
  xo[idx] = v;
}

// ---------- MFMA KxK conv 24->24 FUSED with 1x1 pw + mean/max. 48B records. ----------
template<int K, bool EXPAND, bool INBF, bool OUTBF>
__launch_bounds__(512)
__global__ void k_conv_mfma(const void* in, const ushort_t* __restrict__ wb,
                            const ushort_t* __restrict__ wbpw, const float* __restrict__ wexp,
                            void* out, float* __restrict__ mm,
                            int H, int W, int istrIn, int istrOut, int istrMM){
  constexpr int SW_T = 32 + K - 1;
  constexpr int SH = 16 + K - 1;
  constexpr int NPX = SH*SW_T;
  __shared__ ushort_t lds[NPX*24];
  __shared__ uint_t sc[8][16*20];
  int tid = threadIdx.x;
  const float* inb_f = (const float*)in + (size_t)blockIdx.z*istrIn;
  const ushort_t* inb_b = (const ushort_t*)in + (size_t)blockIdx.z*istrIn;
  int x0g = blockIdx.x*32 - K/2, y0g = blockIdx.y*16 - K/2;
  int HW = H*W;
  for (int i = tid; i < NPX*3; i += 512){
    int q = i / NPX;
    int pp = i - q*NPX;
    int row = pp / SW_T, col = pp - row*SW_T;
    int gy = y0g + row, gx = x0g + col;
    uint4 w4; w4.x=0u; w4.y=0u; w4.z=0u; w4.w=0u;
    if (gy >= 0 && gy < H && gx >= 0 && gx < W){
      size_t base = (size_t)gy*W + gx;
      int c0 = q*8;
      if (EXPAND){
        float val = inb_f[base];
        w4.x = (uint_t)bf16r(val*wexp[c0+0]) | ((uint_t)bf16r(val*wexp[c0+1])<<16);
        w4.y = (uint_t)bf16r(val*wexp[c0+2]) | ((uint_t)bf16r(val*wexp[c0+3])<<16);
        w4.z = (uint_t)bf16r(val*wexp[c0+4]) | ((uint_t)bf16r(val*wexp[c0+5])<<16);
        w4.w = (uint_t)bf16r(val*wexp[c0+6]) | ((uint_t)bf16r(val*wexp[c0+7])<<16);
      } else if (INBF){
        uint_t u0=inb_b[(size_t)(c0+0)*HW+base], u1=inb_b[(size_t)(c0+1)*HW+base];
        uint_t u2=inb_b[(size_t)(c0+2)*HW+base], u3=inb_b[(size_t)(c0+3)*HW+base];
        uint_t u4=inb_b[(size_t)(c0+4)*HW+base], u5=inb_b[(size_t)(c0+5)*HW+base];
        uint_t u6=inb_b[(size_t)(c0+6)*HW+base], u7=inb_b[(size_t)(c0+7)*HW+base];
        w4.x = u0 | (u1<<16); w4.y = u2 | (u3<<16); w4.z = u4 | (u5<<16); w4.w = u6 | (u7<<16);
      } else {
        w4.x = (uint_t)bf16r(inb_f[(size_t)(c0+0)*HW+base]) | ((uint_t)bf16r(inb_f[(size_t)(c0+1)*HW+base])<<16);
        w4.y = (uint_t)bf16r(inb_f[(size_t)(c0+2)*HW+base]) | ((uint_t)bf16r(inb_f[(size_t)(c0+3)*HW+base])<<16);
        w4.z = (uint_t)bf16r(inb_f[(size_t)(c0+4)*HW+base]) | ((uint_t)bf16r(inb_f[(size_t)(c0+5)*HW+base])<<16);
        w4.w = (uint_t)bf16r(inb_f[(size_t)(c0+6)*HW+base]) | ((uint_t)bf16r(inb_f[(size_t)(c0+7)*HW+base])<<16);
      }
    }
    *(uint4*)(lds + (size_t)pp*24 + q*8) = w4;
  }
  __syncthreads();
  int l = tid & 63, wid = tid >> 6;
  int kg = l >> 4, li = l & 15;
  int kgc = (kg < 3) ? kg : 2;
  f32x4 zero = {0.f,0.f,0.f,0.f};
  f32x4 acc[4][2];
  #pragma unroll
  for (int i=0;i<4;i++){ acc[i][0]=zero; acc[i][1]=zero; }

  const ushort_t* aln = lds + li*24 + kgc*8 + (size_t)wid*SW_T*24;

  #pragma unroll
  for (int ky=0; ky<K; ky++){
    #pragma unroll
    for (int kx=0; kx<K; kx++){
      int tap = ky*K + kx;
      const ushort_t* wp = wb + (size_t)tap*1024;
      short8v b0 = *(const short8v*)(wp + l*8);
      short8v b1 = *(const short8v*)(wp + 512 + l*8);
      #pragma unroll
      for (int i=0;i<4;i++){
        const ushort_t* ap = aln + (((i&1)*8 + ky)*SW_T + (i>>1)*16 + kx)*24;
        short8v a = *(const short8v*)ap;
        acc[i][0] = __builtin_amdgcn_mfma_f32_16x16x32_bf16(a, b0, acc[i][0], 0, 0, 0);
        acc[i][1] = __builtin_amdgcn_mfma_f32_16x16x32_bf16(a, b1, acc[i][1], 0, 0, 0);
      }
    }
  }
  // ---- stage 2: pw 1x1 via second MFMA, + mean/max ----
  short8v bpw0 = *(const short8v*)(wbpw + l*8);
  short8v bpw1 = *(const short8v*)(wbpw + 512 + l*8);
  uint_t* s = sc[wid];
  float* outb_f = (float*)out + (size_t)blockIdx.z*istrOut;
  ushort_t* outb_b = (ushort_t*)out + (size_t)blockIdx.z*istrOut;
  float* mmb = mm + (size_t)blockIdx.z*istrMM;
  #pragma unroll 1
  for (int i=0;i<4;i++){
    __asm__ volatile("s_waitcnt lgkmcnt(0)" ::: "memory");
    __builtin_amdgcn_sched_barrier(0);
    #pragma unroll
    for (int reg=0; reg<4; reg++){
      float v0 = acc[i][0][reg], v1 = acc[i][1][reg];
      float v0n = __shfl_xor(v0, 1, 64);
      float v1n = __shfl_xor(v1, 1, 64);
      int pxr = kg*4 + reg;
      uint_t packed; int uidx;
      if ((li & 1) == 0){
        packed = (uint_t)bf16r(v0) | ((uint_t)bf16r(v0n) << 16);
        uidx = li >> 1;
      } else {
        packed = (uint_t)bf16r(v1n) | ((uint_t)bf16r(v1) << 16);
        uidx = 8 + (li >> 1);
      }
      s[pxr*20 + uidx] = packed;
    }
    __asm__ volatile("s_waitcnt lgkmcnt(0)" ::: "memory");
    __builtin_amdgcn_sched_barrier(0);
    short8v a2 = *(const short8v*)((const ushort_t*)s + li*40 + kg*8);
    f32x4 d0 = __builtin_amdgcn_mfma_f32_16x16x32_bf16(a2, bpw0, zero, 0, 0, 0);
    f32x4 d1 = __builtin_amdgcn_mfma_f32_16x16x32_bf16(a2, bpw1, zero, 0, 0, 0);
    int gy = blockIdx.y*16 + wid + (i&1)*8;
    int gx = blockIdx.x*32 + (i>>1)*16 + kg*4;
    if (OUTBF){
      uint2 p0; p0.x = (uint_t)bf16r(d0[0]) | ((uint_t)bf16r(d0[1])<<16);
      p0.y = (uint_t)bf16r(d0[2]) | ((uint_t)bf16r(d0[3])<<16);
      *(uint2*)(outb_b + (size_t)li*HW + (size_t)gy*W + gx) = p0;
      if (li < 8){
        uint2 p1; p1.x = (uint_t)bf16r(d1[0]) | ((uint_t)bf16r(d1[1])<<16);
        p1.y = (uint_t)bf16r(d1[2]) | ((uint_t)bf16r(d1[3])<<16);
        *(uint2*)(outb_b + (size_t)(16+li)*HW + (size_t)gy*W + gx) = p1;
      }
    } else {
      *(f32x4*)(outb_f + (size_t)li*HW + (size_t)gy*W + gx) = d0;
      if (li < 8)
        *(f32x4*)(outb_f + (size_t)(16+li)*HW + (size_t)gy*W + gx) = d1;
    }
    f32x4 sm, mx;
    #pragma unroll
    for (int reg=0; reg<4; reg++){
      sm[reg] = d0[reg] + d1[reg];
      mx[reg] = fmaxf(d0[reg], (li<8) ? d1[reg] : -3.4e38f);
    }
    #pragma unroll
    for (int m=1; m<16; m<<=1){
      #pragma unroll
      for (int reg=0; reg<4; reg++){
        sm[reg] += __shfl_xor(sm[reg], m, 64);
        mx[reg] = fmaxf(mx[reg], __shfl_xor(mx[reg], m, 64));
      }
    }
    if (li == 0){
      f32x4 me; me[0]=sm[0]*(1.f/24.f); me[1]=sm[1]*(1.f/24.f); me[2]=sm[2]*(1.f/24.f); me[3]=sm[3]*(1.f/24.f);
      *(f32x4*)(mmb + (size_t)gy*W + gx) = me;
      *(f32x4*)(mmb + (size_t)HW + (size_t)gy*W + gx) = mx;
    }
  }
}

// ---------- MFMA ConvTranspose2d(k=4,s=2,p=1), 32x16 out tile ----------
template<bool INBF, bool OUTBF>
__launch_bounds__(512)
__global__ void k_convT_mfma(const void* in, const ushort_t* __restrict__ wb,
                             void* out, int Ho, int Wo, int istrIn, int istrOut){
  const int Hi = Ho>>1, Wi = Wo>>1;
  constexpr int SW_T = 18, NPX = 180;
  __shared__ ushort_t lds[NPX*24];
  int tid = threadIdx.x;
  const float* inb_f = (const float*)in + (size_t)blockIdx.z*istrIn;
  const ushort_t* inb_b = (const ushort_t*)in + (size_t)blockIdx.z*istrIn;
  int X0 = blockIdx.x*32, Y0 = blockIdx.y*16;
  int ix0 = (X0>>1) - 1, iy0 = (Y0>>1) - 1;
  int HWi = Hi*Wi;
  for (int i = tid; i < NPX*3; i += 512){
    int q = i / NPX;
    int pp = i - q*NPX;
    int row = pp / SW_T, col = pp - row*SW_T;
    int gy = iy0 + row, gx = ix0 + col;
    uint4 w4; w4.x=0u; w4.y=0u; w4.z=0u; w4.w=0u;
    if (gy>=0 && gy<Hi && gx>=0 && gx<Wi){
      size_t base = (size_t)gy*Wi + gx;
      int c0 = q*8;
      if (INBF){
        uint_t u0=inb_b[(size_t)(c0+0)*HWi+base], u1=inb_b[(size_t)(c0+1)*HWi+base];
        uint_t u2=inb_b[(size_t)(c0+2)*HWi+base], u3=inb_b[(size_t)(c0+3)*HWi+base];
        uint_t u4=inb_b[(size_t)(c0+4)*HWi+base], u5=inb_b[(size_t)(c0+5)*HWi+base];
        uint_t u6=inb_b[(size_t)(c0+6)*HWi+base], u7=inb_b[(size_t)(c0+7)*HWi+base];
        w4.x = u0 | (u1<<16); w4.y = u2 | (u3<<16); w4.z = u4 | (u5<<16); w4.w = u6 | (u7<<16);
      } else {
        w4.x = (uint_t)bf16r(inb_f[(size_t)(c0+0)*HWi+base]) | ((uint_t)bf16r(inb_f[(size_t)(c0+1)*HWi+base])<<16);
        w4.y = (uint_t)bf16r(inb_f[(size_t)(c0+2)*HWi+base]) | ((uint_t)bf16r(inb_f[(size_t)(c0+3)*HWi+base])<<16);
        w4.z = (uint_t)bf16r(inb_f[(size_t)(c0+4)*HWi+base]) | ((uint_t)bf16r(inb_f[(size_t)(c0+5)*HWi+base])<<16);
        w4.w = (uint_t)bf16r(inb_f[(size_t)(c0+6)*HWi+base]) | ((uint_t)bf16r(inb_f[(size_t)(c0+7)*HWi+base])<<16);
      }
    }
    *(uint4*)(lds + (size_t)pp*24 + q*8) = w4;
  }
  __syncthreads();
  int l = tid & 63, wid = tid >> 6;
  int kg = l >> 4, li = l & 15;
  int kgc = (kg < 3) ? kg : 2;
  f32x4 zero = {0.f,0.f,0.f,0.f};
  f32x4 acc[4][2];
  #pragma unroll
  for (int i=0;i<4;i++){ acc[i][0]=zero; acc[i][1]=zero; }

  const ushort_t* aln = lds + li*24 + kgc*8;

  #pragma unroll
  for (int i=0;i<4;i++){
    int g = wid + 8*i;
    int r = g & 15, q = g >> 4;
    int ky0 = (r+1)&1;
    #pragma unroll
    for (int t2=0;t2<2;t2++){
      int ky = ky0 + 2*t2;
      int liy = ((r+1-ky)>>1) + 1;
      #pragma unroll
      for (int u=0;u<2;u++){
        int kx = (q ? 0 : 1) + 2*u;
        int lixb = ((q+1-kx)>>1) + 1;
        int tap = ky*4 + kx;
        const ushort_t* wp = wb + (size_t)tap*1024;
        short8v b0 = *(const short8v*)(wp + l*8);
        short8v b1 = *(const short8v*)(wp + 512 + l*8);
        short8v a = *(const short8v*)(aln + (liy*SW_T + lixb)*24);
        acc[i][0] = __builtin_amdgcn_mfma_f32_16x16x32_bf16(a, b0, acc[i][0], 0, 0, 0);
        acc[i][1] = __builtin_amdgcn_mfma_f32_16x16x32_bf16(a, b1, acc[i][1], 0, 0, 0);
      }
    }
  }
  float* outb_f = (float*)out + (size_t)blockIdx.z*istrOut;
  ushort_t* outb_b = (ushort_t*)out + (size_t)blockIdx.z*istrOut;
  int HWo = Ho*Wo;
  #pragma unroll
  for (int i=0;i<4;i++){
    int g = wid + 8*i;
    int r = g & 15, q = g >> 4;
    int oy = Y0 + r;
    #pragma unroll
    for (int reg=0; reg<4; reg++){
      int ox = X0 + 2*(kg*4 + reg) + q;
      if (OUTBF){
        outb_b[(size_t)li*HWo + (size_t)oy*Wo + ox] = bf16r(acc[i][0][reg]);
        if (li < 8)
          outb_b[(size_t)(16+li)*HWo + (size_t)oy*Wo + ox] = bf16r(acc[i][1][reg]);
      } else {
        outb_f[(size_t)li*HWo + (size_t)oy*Wo + ox] = acc[i][0][reg];
        if (li < 8)
          outb_f[(size_t)(16+li)*HWo + (size_t)oy*Wo + ox] = acc[i][1][reg];
      }
    }
  }
}

// ---------- MFMA 4x4 s2 p1 downsample, 16x8 out tile ----------
template<bool INBF, bool OUTBF>
__launch_bounds__(512)
__global__ void k_down_mfma(const void* in, const ushort_t* __restrict__ wb,
                            void* out, int Ho, int Wo, int istrIn, int istrOut){
  const int Hi = Ho*2, Wi = Wo*2;
  constexpr int NPX = 18*34;
  __shared__ ushort_t lds[NPX*24];
  int tid = threadIdx.x;
  const float* inb_f = (const float*)in + (size_t)blockIdx.z*istrIn;
  const ushort_t* inb_b = (const ushort_t*)in + (size_t)blockIdx.z*istrIn;
  int X0 = blockIdx.x*16, Y0 = blockIdx.y*8;
  int ix0 = 2*X0 - 1, iy0 = 2*Y0 - 1;
  int HWi = Hi*Wi;
  for (int i = tid; i < NPX*3; i += 512){
    int q = i / NPX;
    int pp = i - q*NPX;
    int row = pp / 34;
    int rem = pp - row*34;
    int par = (rem >= 17) ? 1 : 0;
    int sub = rem - par*17;
    int gx = ix0 + 2*sub + par;
    int gy = iy0 + row;
    uint4 w4; w4.x=0u; w4.y=0u; w4.z=0u; w4.w=0u;
    if (gy>=0 && gy<Hi && gx>=0 && gx<Wi){
      size_t base = (size_t)gy*Wi + gx;
      int c0 = q*8;
      if (INBF){
        uint_t u0=inb_b[(size_t)(c0+0)*HWi+base], u1=inb_b[(size_t)(c0+1)*HWi+base];
        uint_t u2=inb_b[(size_t)(c0+2)*HWi+base], u3=inb_b[(size_t)(c0+3)*HWi+base];
        uint_t u4=inb_b[(size_t)(c0+4)*HWi+base], u5=inb_b[(size_t)(c0+5)*HWi+base];
        uint_t u6=inb_b[(size_t)(c0+6)*HWi+base], u7=inb_b[(size_t)(c0+7)*HWi+base];
        w4.x = u0 | (u1<<16); w4.y = u2 | (u3<<16); w4.z = u4 | (u5<<16); w4.w = u6 | (u7<<16);
      } else {
        w4.x = (uint_t)bf16r(inb_f[(size_t)(c0+0)*HWi+base]) | ((uint_t)bf16r(inb_f[(size_t)(c0+1)*HWi+base])<<16);
        w4.y = (uint_t)bf16r(inb_f[(size_t)(c0+2)*HWi+base]) | ((uint_t)bf16r(inb_f[(size_t)(c0+3)*HWi+base])<<16);
        w4.z = (uint_t)bf16r(inb_f[(size_t)(c0+4)*HWi+base]) | ((uint_t)bf16r(inb_f[(size_t)(c0+5)*HWi+base])<<16);
        w4.w = (uint_t)bf16r(inb_f[(size_t)(c0+6)*HWi+base]) | ((uint_t)bf16r(inb_f[(size_t)(c0+7)*HWi+base])<<16);
      }
    }
    *(uint4*)(lds + (size_t)pp*24 + q*8) = w4;
  }
  __syncthreads();
  int l = tid & 63, wid = tid >> 6;
  int kg = l >> 4, li = l & 15;
  int kgc = (kg < 3) ? kg : 2;
  f32x4 zero = {0.f,0.f,0.f,0.f};
  f32x4 acc0 = zero, acc1 = zero;
  const ushort_t* aln = lds + li*24 + kgc*8 + (size_t)(2*wid)*34*24;
  #pragma unroll
  for (int ky=0; ky<4; ky++){
    #pragma unroll
    for (int kx=0; kx<4; kx++){
      int tap = ky*4 + kx;
      const ushort_t* wp = wb + (size_t)tap*1024;
      short8v b0 = *(const short8v*)(wp + l*8);
      short8v b1 = *(const short8v*)(wp + 512 + l*8);
      short8v a = *(const short8v*)(aln + (ky*34 + (kx&1)*17 + (kx>>1))*24);
      acc0 = __builtin_amdgcn_mfma_f32_16x16x32_bf16(a, b0, acc0, 0, 0, 0);
      acc1 = __builtin_amdgcn_mfma_f32_16x16x32_bf16(a, b1, acc1, 0, 0, 0);
    }
  }
  int HWo = Ho*Wo;
  int oy = Y0 + wid, ox = X0 + kg*4;
  if (OUTBF){
    ushort_t* outb = (ushort_t*)out + (size_t)blockIdx.z*istrOut;
    uint2 p0; p0.x = (uint_t)bf16r(acc0[0]) | ((uint_t)bf16r(acc0[1])<<16);
    p0.y = (uint_t)bf16r(acc0[2]) | ((uint_t)bf16r(acc0[3])<<16);
    *(uint2*)(outb + (size_t)li*HWo + (size_t)oy*Wo + ox) = p0;
    if (li < 8){
      uint2 p1; p1.x = (uint_t)bf16r(acc1[0]) | ((uint_t)bf16r(acc1[1])<<16);
      p1.y = (uint_t)bf16r(acc1[2]) | ((uint_t)bf16r(acc1[3])<<16);
      *(uint2*)(outb + (size_t)(16+li)*HWo + (size_t)oy*Wo + ox) = p1;
    }
  } else {
    float* outb = (float*)out + (size_t)blockIdx.z*istrOut;
    *(f32x4*)(outb + (size_t)li*HWo + (size_t)oy*Wo + ox) = acc0;
    if (li < 8)
      *(f32x4*)(outb + (size_t)(16+li)*HWo + (size_t)oy*Wo + ox) = acc1;
  }
}

// spatial attn + sigmoid + relu + residual add; BF: R/X/out are bf16 planes
template<bool BF>
__global__ void k_attn_res(const void* R_, const float* __restrict__ M,
                           const void* X_, const float* __restrict__ wsa,
                           void* out_, int H, int W, int istr, int istrMM){
  int p = (blockIdx.x*256 + threadIdx.x)*4;
  int HW = H*W;
  if (p >= HW) return;
  int py = p / W, px0 = p % W;
  const float* Mb = M + (size_t)blockIdx.z*istrMM;
  float s[4]={0,0,0,0};
  #pragma unroll
  for (int cc=0;cc<2;cc++){
    const float* Mc = Mb + (size_t)cc*HW;
    #pragma unroll 1
    for (int ky=0;ky<7;ky++){
      int gy = py+ky-3;
      if (gy<0||gy>=H) continue;
      const float* mr = Mc + (size_t)gy*W;
      float mv[10];
      #pragma unroll
      for (int j=0;j<10;j++){
        int gx = px0-3+j;
        mv[j] = (gx>=0 && gx<W) ? mr[gx] : 0.f;
      }
      const float* wr = wsa + (cc*7+ky)*7;
      #pragma unroll
      for (int kx=0;kx<7;kx++){
        float wv = wr[kx];
        #pragma unroll
        for (int px=0;px<4;px++) s[px] = fmaf(mv[kx+px], wv, s[px]);
      }
    }
  }
  float g[4];
  #pragma unroll
  for (int px=0;px<4;px++) g[px] = 1.f/(1.f+expf(-s[px]));
  #pragma unroll
  for (int c=0;c<CH;c++){
    float r0,r1,r2,r3, x0v,x1v,x2v,x3v;
    if (BF){
      const ushort_t* Rb = (const ushort_t*)R_ + (size_t)blockIdx.z*istr + (size_t)c*HW + p;
      const ushort_t* Xb = (const ushort_t*)X_ + (size_t)blockIdx.z*istr + (size_t)c*HW + p;
      uint2 rv = *(const uint2*)Rb;
      uint2 xv = *(const uint2*)Xb;
      r0=bf2f(rv.x&0xffffu); r1=bf2f(rv.x>>16); r2=bf2f(rv.y&0xffffu); r3=bf2f(rv.y>>16);
      x0v=bf2f(xv.x&0xffffu); x1v=bf2f(xv.x>>16); x2v=bf2f(xv.y&0xffffu); x3v=bf2f(xv.y>>16);
    } else {
      const float* Rb = (const float*)R_ + (size_t)blockIdx.z*istr + (size_t)c*HW + p;
      const float* Xb = (const float*)X_ + (size_t)blockIdx.z*istr + (size_t)c*HW + p;
      float4 rv = *(const float4*)Rb;
      float4 xv = *(const float4*)Xb;
      r0=rv.x; r1=rv.y; r2=rv.z; r3=rv.w;
      x0v=xv.x; x1v=xv.y; x2v=xv.z; x3v=xv.w;
    }
    float o0 = x0v + fmaxf(r0*g[0], 0.f);
    float o1 = x1v + fmaxf(r1*g[1], 0.f);
    float o2 = x2v + fmaxf(r2*g[2], 0.f);
    float o3 = x3v + fmaxf(r3*g[3], 0.f);
    if (BF){
      ushort_t* Ob = (ushort_t*)out_ + (size_t)blockIdx.z*istr + (size_t)c*HW + p;
      uint2 ov;
      ov.x = (uint_t)bf16r(o0) | ((uint_t)bf16r(o1)<<16);
      ov.y = (uint_t)bf16r(o2) | ((uint_t)bf16r(o3)<<16);
      *(uint2*)Ob = ov;
    } else {
      float* Ob = (float*)out_ + (size_t)blockIdx.z*istr + (size_t)c*HW + p;
      float4 ov; ov.x=o0; ov.y=o1; ov.z=o2; ov.w=o3;
      *(float4*)Ob = ov;
    }
  }
}

// variant: residual computed from XL*wexp; BF: R/out bf16
template<bool BF>
__global__ void k_attn_res_x(const void* R_, const float* __restrict__ M,
                             const float* __restrict__ XL, const float* __restrict__ wsa,
                             const float* __restrict__ wexp,
                             void* out_, int H, int W, int istr, int istrMM){
  int p = (blockIdx.x*256 + threadIdx.x)*4;
  int HW = H*W;
  if (p >= HW) return;
  int py = p / W, px0 = p % W;
  const float* Mb = M + (size_t)blockIdx.z*istrMM;
  float s[4]={0,0,0,0};
  #pragma unroll
  for (int cc=0;cc<2;cc++){
    const float* Mc = Mb + (size_t)cc*HW;
    #pragma unroll 1
    for (int ky=0;ky<7;ky++){
      int gy = py+ky-3;
      if (gy<0||gy>=H) continue;
      const float* mr = Mc + (size_t)gy*W;
      float mv[10];
      #pragma unroll
      for (int j=0;j<10;j++){
        int gx = px0-3+j;
        mv[j] = (gx>=0 && gx<W) ? mr[gx] : 0.f;
      }
      const float* wr = wsa + (cc*7+ky)*7;
      #pragma unroll
      for (int kx=0;kx<7;kx++){
        float wv = wr[kx];
        #pragma unroll
        for (int px=0;px<4;px++) s[px] = fmaf(mv[kx+px], wv, s[px]);
      }
    }
  }
  float g[4];
  #pragma unroll
  for (int px=0;px<4;px++) g[px] = 1.f/(1.f+expf(-s[px]));
  float4 xl4 = *(const float4*)(XL + (size_t)blockIdx.z*HW + p);
  #pragma unroll
  for (int c=0;c<CH;c++){
    float wc = wexp[c];
    float r0,r1,r2,r3;
    if (BF){
      const ushort_t* Rb = (const ushort_t*)R_ + (size_t)blockIdx.z*istr + (size_t)c*HW + p;
      uint2 rv = *(const uint2*)Rb;
      r0=bf2f(rv.x&0xffffu); r1=bf2f(rv.x>>16); r2=bf2f(rv.y&0xffffu); r3=bf2f(rv.y>>16);
    } else {
      const float* Rb = (const float*)R_ + (size_t)blockIdx.z*istr + (size_t)c*HW + p;
      float4 rv = *(const float4*)Rb;
      r0=rv.x; r1=rv.y; r2=rv.z; r3=rv.w;
    }
    float o0 = xl4.x*wc + fmaxf(r0*g[0], 0.f);
    float o1 = xl4.y*wc + fmaxf(r1*g[1], 0.f);
    float o2 = xl4.z*wc + fmaxf(r2*g[2], 0.f);
    float o3 = xl4.w*wc + fmaxf(r3*g[3], 0.f);
    if (BF){
      ushort_t* Ob = (ushort_t*)out_ + (size_t)blockIdx.z*istr + (size_t)c*HW + p;
      uint2 ov;
      ov.x = (uint_t)bf16r(o0) | ((uint_t)bf16r(o1)<<16);
      ov.y = (uint_t)bf16r(o2) | ((uint_t)bf16r(o3)<<16);
      *(uint2*)Ob = ov;
    } else {
      float* Ob = (float*)out_ + (size_t)blockIdx.z*istr + (size_t)c*HW + p;
      float4 ov; ov.x=o0; ov.y=o1; ov.z=o2; ov.w=o3;
      *(float4*)Ob = ov;
    }
  }
}

// FUSED attn_res(dt) + final: mask = sum_c wout[c]*(x_c + relu(r_c*g)); clean = xl - mask
__global__ void k_attn_final(const ushort_t* __restrict__ R, const float* __restrict__ M,
                             const ushort_t* __restrict__ X, const float* __restrict__ wsa,
                             const float* __restrict__ wout, const float* __restrict__ xl,
                             float* __restrict__ outMask, float* __restrict__ outClean,
                             int H, int W, int istr, int istrMM){
  int p = (blockIdx.x*256 + threadIdx.x)*4;
  int HW = H*W;
  if (p >= HW) return;
  int py = p / W, px0 = p % W;
  const float* Mb = M + (size_t)blockIdx.z*istrMM;
  float s[4]={0,0,0,0};
  #pragma unroll
  for (int cc=0;cc<2;cc++){
    const float* Mc = Mb + (size_t)cc*HW;
    #pragma unroll 1
    for (int ky=0;ky<7;ky++){
      int gy = py+ky-3;
      if (gy<0||gy>=H) continue;
      const float* mr = Mc + (size_t)gy*W;
      float mv[10];
      #pragma unroll
      for (int j=0;j<10;j++){
        int gx = px0-3+j;
        mv[j] = (gx>=0 && gx<W) ? mr[gx] : 0.f;
      }
      const float* wr = wsa + (cc*7+ky)*7;
      #pragma unroll
      for (int kx=0;kx<7;kx++){
        float wv = wr[kx];
        #pragma unroll
        for (int px=0;px<4;px++) s[px] = fmaf(mv[kx+px], wv, s[px]);
      }
    }
  }
  float g[4];
  #pragma unroll
  for (int px=0;px<4;px++) g[px] = 1.f/(1.f+expf(-s[px]));
  float m0=0.f,m1=0.f,m2=0.f,m3=0.f;
  #pragma unroll
  for (int c=0;c<CH;c++){
    const ushort_t* Rb = R + (size_t)blockIdx.z*istr + (size_t)c*HW + p;
    const ushort_t* Xb = X + (size_t)blockIdx.z*istr + (size_t)c*HW + p;
    uint2 rv = *(const uint2*)Rb;
    uint2 xv = *(const uint2*)Xb;
    float wc = wout[c];
    float o0 = bf2f(xv.x&0xffffu) + fmaxf(bf2f(rv.x&0xffffu)*g[0], 0.f);
    float o1 = bf2f(xv.x>>16)     + fmaxf(bf2f(rv.x>>16)*g[1], 0.f);
    float o2 = bf2f(xv.y&0xffffu) + fmaxf(bf2f(rv.y&0xffffu)*g[2], 0.f);
    float o3 = bf2f(xv.y>>16)     + fmaxf(bf2f(rv.y>>16)*g[3], 0.f);
    m0 = fmaf(o0,wc,m0); m1 = fmaf(o1,wc,m1); m2 = fmaf(o2,wc,m2); m3 = fmaf(o3,wc,m3);
  }
  float4 xlv = *(const float4*)(xl + (size_t)blockIdx.z*HW + p);
  float4 mo; mo.x=m0; mo.y=m1; mo.z=m2; mo.w=m3;
  float4 co; co.x=xlv.x-m0; co.y=xlv.y-m1; co.z=xlv.z-m2; co.w=xlv.w-m3;
  *(float4*)(outMask + (size_t)blockIdx.z*HW + p) = mo;
  *(float4*)(outClean + (size_t)blockIdx.z*HW + p) = co;
}

// 1x1 conv 48->24 over concat(A,B); BF: all planes bf16
template<bool BF>
__global__ void k_squeeze(const void* inA_, const void* inB_,
                          const float* __restrict__ wT, void* out_, int HW, int istr){
  int p = (blockIdx.x*256 + threadIdx.x)*4;
  if (p >= HW) return;
  float acc[CH][4];
  #pragma unroll
  for (int co=0;co<CH;co++){ acc[co][0]=0;acc[co][1]=0;acc[co][2]=0;acc[co][3]=0; }
  #pragma unroll 1
  for (int ci=0;ci<48;ci++){
    float v0,v1,v2,v3;
    if (BF){
      const ushort_t* src = (ci<24)
        ? ((const ushort_t*)inA_ + (size_t)blockIdx.z*istr + (size_t)ci*HW + p)
        : ((const ushort_t*)inB_ + (size_t)blockIdx.z*istr + (size_t)(ci-24)*HW + p);
      uint2 rv = *(const uint2*)src;
      v0=bf2f(rv.x&0xffffu); v1=bf2f(rv.x>>16); v2=bf2f(rv.y&0xffffu); v3=bf2f(rv.y>>16);
    } else {
      const float* src = (ci<24)
        ? ((const float*)inA_ + (size_t)blockIdx.z*istr + (size_t)ci*HW + p)
        : ((const float*)inB_ + (size_t)blockIdx.z*istr + (size_t)(ci-24)*HW + p);
      float4 rv = *(const float4*)src;
      v0=rv.x; v1=rv.y; v2=rv.z; v3=rv.w;
    }
    const float* wp = wT + ci*24;
    #pragma unroll
    for (int co=0;co<CH;co++){
      float wv = wp[co];
      acc[co][0] = fmaf(v0, wv, acc[co][0]);
      acc[co][1] = fmaf(v1, wv, acc[co][1]);
      acc[co][2] = fmaf(v2, wv, acc[co][2]);
      acc[co][3] = fmaf(v3, wv, acc[co][3]);
    }
  }
  #pragma unroll
  for (int co=0;co<CH;co++){
    if (BF){
      ushort_t* ob = (ushort_t*)out_ + (size_t)blockIdx.z*istr + (size_t)co*HW + p;
      uint2 ov;
      ov.x = (uint_t)bf16r(acc[co][0]) | ((uint_t)bf16r(acc[co][1])<<16);
      ov.y = (uint_t)bf16r(acc[co][2]) | ((uint_t)bf16r(acc[co][3])<<16);
      *(uint2*)ob = ov;
    } else {
      float* ob = (float*)out_ + (size_t)blockIdx.z*istr + (size_t)co*HW + p;
      float4 o; o.x=acc[co][0]; o.y=acc[co][1]; o.z=acc[co][2]; o.w=acc[co][3];
      *(float4*)ob = o;
    }
  }
}

__global__ void k_quant(const float* __restrict__ enc, const float* __restrict__ embed,
                        float* __restrict__ qt, float* __restrict__ diffAcc, int HW, int istr){
  __shared__ float em[256*28];
  __shared__ float red[4];
  {
    int j = threadIdx.x;
    float s = 0.f;
    #pragma unroll
    for (int c=0;c<CH;c++){
      float e = embed[c*256+j];
      em[j*28+c] = -2.0f*e;
      s = fmaf(e,e,s);
    }
    em[j*28+24] = s; em[j*28+25]=0.f; em[j*28+26]=0.f; em[j*28+27]=0.f;
  }
  __syncthreads();
  int p = blockIdx.x*256 + threadIdx.x;
  const float* eb = enc + (size_t)blockIdx.z*istr;
  float f[CH];
  #pragma unroll
  for (int c=0;c<CH;c++) f[c] = eb[(size_t)c*HW + p];
  float best = 3.4e38f; int bj = 0;
  #pragma unroll 1
  for (int j=0;j<256;j++){
    const float4* row = (const float4*)&em[j*28];
    float s = em[j*28+24];
    #pragma unroll
    for (int q4=0;q4<6;q4++){
      float4 r = row[q4];
      s = fmaf(f[q4*4+0], r.x, s);
      s = fmaf(f[q4*4+1], r.y, s);
      s = fmaf(f[q4*4+2], r.z, s);
      s = fmaf(f[q4*4+3], r.w, s);
    }
    if (s < best){ best = s; bj = j; }
  }
  float* qb = qt + (size_t)blockIdx.z*istr;
  float d = 0.f;
  #pragma unroll
  for (int c=0;c<CH;c++){
    float q = embed[c*256+bj];
    qb[(size_t)c*HW + p] = q;
    float e = q - f[c];
    d = fmaf(e,e,d);
  }
  #pragma unroll
  for (int off=32; off>0; off>>=1) d += __shfl_down(d, off, 64);
  int lane = threadIdx.x & 63, wv = threadIdx.x >> 6;
  if (lane==0) red[wv] = d;
  __syncthreads();
  if (threadIdx.x==0) atomicAdd(diffAcc, red[0]+red[1]+red[2]+red[3]);
}

__global__ void k_diff(const float* __restrict__ acc, float* __restrict__ out){
  out[0] = acc[0]*(1.f/3145728.f) + acc[1]*(1.f/786432.f);
}

// =======================================================================
extern "C" void kernel_launch(void* const* d_in, const int* in_sizes, int n_in,
                              void* d_out, int out_size, void* d_ws, size_t ws_size,
                              hipStream_t stream) {
  const float* x        = (const float*)d_in[0];
  const float* embed2   = (const float*)d_in[1];
  const float* embed3   = (const float*)d_in[2];
  const float* w_img_in = (const float*)d_in[3];
  const float* w_img_out= (const float*)d_in[4];
  const float* w_out_dd = (const float*)d_in[5];
  const float* w_out_dm = (const float*)d_in[6];
  const float* w_out_dt = (const float*)d_in[7];
  const float* w_out_ed = (const float*)d_in[8];
  const float* w_out_em = (const float*)d_in[9];
  const float* w_out_et = (const float*)d_in[10];
  const float* w_pw_dd  = (const float*)d_in[11];
  const float* w_pw_dm  = (const float*)d_in[12];
  const float* w_pw_dt  = (const float*)d_in[13];
  const float* w_pw_ed  = (const float*)d_in[14];
  const float* w_pw_em  = (const float*)d_in[15];
  const float* w_pw_et  = (const float*)d_in[16];
  const float* w_res_dd = (const float*)d_in[17];
  const float* w_res_dm = (const float*)d_in[18];
  const float* w_res_dt = (const float*)d_in[19];
  const float* w_res_ed = (const float*)d_in[20];
  const float* w_res_em = (const float*)d_in[21];
  const float* w_res_et = (const float*)d_in[22];
  const float* w_sa_dd  = (const float*)d_in[23];
  const float* w_sa_dm  = (const float*)d_in[24];
  const float* w_sa_dt  = (const float*)d_in[25];
  const float* w_sa_ed  = (const float*)d_in[26];
  const float* w_sa_em  = (const float*)d_in[27];
  const float* w_sa_et  = (const float*)d_in[28];
  const float* w_squ1   = (const float*)d_in[29];
  const float* w_squ2   = (const float*)d_in[30];
  (void)in_sizes; (void)n_in; (void)out_size;

  const int HW512 = 512*512, HW256 = 256*256, HW128 = 128*128, HW64 = 64*64;
  const int S512 = 24*HW512, S256 = 24*HW256, S128 = 24*HW128, S64 = 24*HW64;

  float* ws = (float*)d_ws;
  float* OUT = (float*)d_out;
  size_t F = ws_size / sizeof(float);

  // fp32-reordered weights (squeeze only)
  float* WT      = ws;
  float* wt_squ1 = WT + 154368;
  float* wt_squ2 = WT + 155520;

  // MFMA bf16 B-frag weights
  ushort_t* WB = (ushort_t*)(ws + 160000);
  ushort_t* wb_et7   = WB;
  ushort_t* wb_dt7   = WB + 50176;
  ushort_t* wb_em5   = WB + 100352;
  ushort_t* wb_dm5   = WB + 125952;
  ushort_t* wb_pw_et = WB + 151552;
  ushort_t* wb_pw_em = WB + 152576;
  ushort_t* wb_pw_dm = WB + 153600;
  ushort_t* wb_pw_dt = WB + 154624;
  ushort_t* wb4_dd   = WB + 155648;
  ushort_t* wb4_dm   = WB + 172032;
  ushort_t* wb4_dt   = WB + 188416;
  ushort_t* wb4d_et  = WB + 204800;
  ushort_t* wb4d_em  = WB + 221184;
  ushort_t* wb4d_ed  = WB + 237568;
  ushort_t* wb_ed3   = WB + 253952;
  ushort_t* wb_dd3   = WB + 263168;
  ushort_t* wb_pw_ed = WB + 272384;
  ushort_t* wb_pw_dd = WB + 273408;   // end 274432 ushorts = 137216 floats

  const size_t ABASE = 300000;

  auto needBatched = [&](size_t CB)->size_t{
    size_t u_f = (CB*(size_t)S512 + 1)/2;
    if ((size_t)4*S256 > u_f) u_f = (size_t)4*S256;
    if ((size_t)8*S128 > u_f) u_f = (size_t)8*S128;
    return ABASE + 2097152 + (size_t)4*S256 + 3145728 + 786432 + CB*524288 + 2*u_f + 2;
  };
  int CB = 0;
  if (F >= needBatched(8)) CB = 8;
  else if (F >= needBatched(4)) CB = 4;
  else if (F >= needBatched(2)) CB = 2;
  const size_t NEED_B = ABASE + 15925250;
  if (CB == 0 && F < NEED_B) return;

  float *XL, *E2, *Q2, *E3, *Q3, *MM, *DIFF, *U1, *U2;
  ushort_t* E1b;
  if (CB > 0){
    size_t off = ABASE;
    size_t u_f = (CB*(size_t)S512 + 1)/2;
    if ((size_t)4*S256 > u_f) u_f = (size_t)4*S256;
    if ((size_t)8*S128 > u_f) u_f = (size_t)8*S128;
    XL = ws + off; off += 2097152;
    E1b = (ushort_t*)(ws + off); off += (size_t)4*S256;
    Q2 = ws + off; off += 3145728;
    Q3 = ws + off; off += 786432;
    MM = ws + off; off += CB*524288;
    U1 = ws + off; off += u_f;
    U2 = ws + off; off += u_f;
    DIFF = ws + off;
    E2 = OUT;
    E3 = OUT + 3145728;
  } else {
    size_t off = ABASE;
    XL = ws + off; off += 262144;
    U1 = ws + off; off += 6291456;
    U2 = ws + off; off += 6291456;
    E1b = (ushort_t*)(ws + off); off += 1572864;
    E2 = ws + off; off += 393216;
    Q2 = ws + off; off += 393216;
    E3 = ws + off; off += 98304;
    Q3 = ws + off; off += 98304;
    MM = ws + off; off += 524288;
    DIFF = ws + off;
  }
  ushort_t* U1b = (ushort_t*)U1;
  ushort_t* U2b = (ushort_t*)U2;

  // ---- weight reorders ----
  k_rmfma<<<dim3(196), 256, 0, stream>>>(w_res_et, wb_et7, 7);
  k_rmfma<<<dim3(196), 256, 0, stream>>>(w_res_dt, wb_dt7, 7);
  k_rmfma<<<dim3(100), 256, 0, stream>>>(w_res_em, wb_em5, 5);
  k_rmfma<<<dim3(100), 256, 0, stream>>>(w_res_dm, wb_dm5, 5);
  k_rmfma<<<dim3(36), 256, 0, stream>>>(w_res_ed, wb_ed3, 3);
  k_rmfma<<<dim3(36), 256, 0, stream>>>(w_res_dd, wb_dd3, 3);
  k_rmfma<<<dim3(4), 256, 0, stream>>>(w_pw_et, wb_pw_et, 1);
  k_rmfma<<<dim3(4), 256, 0, stream>>>(w_pw_em, wb_pw_em, 1);
  k_rmfma<<<dim3(4), 256, 0, stream>>>(w_pw_dm, wb_pw_dm, 1);
  k_rmfma<<<dim3(4), 256, 0, stream>>>(w_pw_dt, wb_pw_dt, 1);
  k_rmfma<<<dim3(4), 256, 0, stream>>>(w_pw_ed, wb_pw_ed, 1);
  k_rmfma<<<dim3(4), 256, 0, stream>>>(w_pw_dd, wb_pw_dd, 1);
  k_rmfma4<<<dim3(64), 256, 0, stream>>>(w_out_dd, wb4_dd);
  k_rmfma4<<<dim3(64), 256, 0, stream>>>(w_out_dm, wb4_dm);
  k_rmfma4<<<dim3(64), 256, 0, stream>>>(w_out_dt, wb4_dt);
  k_rmfma<<<dim3(64), 256, 0, stream>>>(w_out_et, wb4d_et, 4);
  k_rmfma<<<dim3(64), 256, 0, stream>>>(w_out_em, wb4d_em, 4);
  k_rmfma<<<dim3(64), 256, 0, stream>>>(w_out_ed, wb4d_ed, 4);
  k_r_pw<<<dim3(5), 256, 0, stream>>>(w_squ1, wt_squ1, 48);
  k_r_pw<<<dim3(5), 256, 0, stream>>>(w_squ2, wt_squ2, 48);

  hipMemsetAsync(DIFF, 0, 2*sizeof(float), stream);

  // ---- phase 1: input -> enc1 (E1 bf16) ----
  auto phase1 = [&](int c0, int nz, float* XLp, ushort_t* E1p){
    k_lap<<<dim3(HW512/256,1,nz), 256, 0, stream>>>(x + (size_t)c0*3*HW512, XLp, 512, 512);
    k_conv_mfma<7,true,false,true><<<dim3(16,32,nz), 512, 0, stream>>>(
        XLp, wb_et7, wb_pw_et, w_img_in, U2b, MM, 512, 512, HW512, S512, 2*HW512);
    k_attn_res_x<true><<<dim3(HW512/1024,1,nz), 256, 0, stream>>>(
        U2b, MM, XLp, w_sa_et, w_img_in, U1b, 512, 512, S512, 2*HW512);
    k_down_mfma<true,true><<<dim3(16,32,nz), 512, 0, stream>>>(U1b, wb4d_et, E1p, 256, 256, S512, S256);
  };

  // ---- deep: enc1 -> squ1 output (bf16 @256, fp32 @128 via MFMA conv3) ----
  auto deep = [&](int nb, ushort_t* E1p, float* SAp, float* SBp, float* E2p, float* Q2p,
                  float* E3p, float* Q3p, float* MMp, ushort_t* D1p){
    ushort_t* SAb = (ushort_t*)SAp;
    ushort_t* SBb = (ushort_t*)SBp;
    int mm256 = 2*HW256, mm128 = 2*HW128;
    k_conv_mfma<5,false,true,true><<<dim3(8,16,nb), 512, 0, stream>>>(
        E1p, wb_em5, wb_pw_em, nullptr, SAb, MMp, 256, 256, S256, S256, mm256);
    k_attn_res<true><<<dim3(HW256/1024,1,nb), 256, 0, stream>>>(SAb, MMp, E1p, w_sa_em, SBb, 256, 256, S256, mm256);
    k_down_mfma<true,false><<<dim3(8,16,nb), 512, 0, stream>>>(SBb, wb4d_em, E2p, 128, 128, S256, S128);
    k_conv_mfma<3,false,false,false><<<dim3(4,8,nb), 512, 0, stream>>>(
        E2p, wb_ed3, wb_pw_ed, nullptr, SAp, MMp, 128, 128, S128, S128, mm128);
    k_attn_res<false><<<dim3(HW128/1024,1,nb), 256, 0, stream>>>(SAp, MMp, E2p, w_sa_ed, SBp, 128, 128, S128, mm128);
    k_down_mfma<false,false><<<dim3(4,8,nb), 512, 0, stream>>>(SBp, wb4d_ed, E3p, 64, 64, S128, S64);
    k_quant<<<dim3(HW128/256,1,nb), 256, 0, stream>>>(E2p, embed2, Q2p, DIFF+0, HW128, S128);
    k_quant<<<dim3(HW64/256,1,nb), 256, 0, stream>>>(E3p, embed3, Q3p, DIFF+1, HW64, S64);
    k_convT_mfma<false,false><<<dim3(4,8,nb), 512, 0, stream>>>(Q3p, wb4_dd, SAp, 128, 128, S64, S128);
    k_conv_mfma<3,false,false,false><<<dim3(4,8,nb), 512, 0, stream>>>(
        SAp, wb_dd3, wb_pw_dd, nullptr, SBp, MMp, 128, 128, S128, S128, mm128);
    k_attn_res<false><<<dim3(HW128/1024,1,nb), 256, 0, stream>>>(SBp, MMp, SAp, w_sa_dd, SAp, 128, 128, S128, mm128);
    k_squeeze<false><<<dim3(HW128/1024,1,nb), 256, 0, stream>>>(SAp, Q2p, wt_squ2, SBp, HW128, S128);
    k_convT_mfma<false,true><<<dim3(8,16,nb), 512, 0, stream>>>(SBp, wb4_dm, SAb, 256, 256, S128, S256);
    k_conv_mfma<5,false,true,true><<<dim3(8,16,nb), 512, 0, stream>>>(
        SAb, wb_dm5, wb_pw_dm, nullptr, SBb, MMp, 256, 256, S256, S256, mm256);
    k_attn_res<true><<<dim3(HW256/1024,1,nb), 256, 0, stream>>>(SBb, MMp, SAb, w_sa_dm, SAb, 256, 256, S256, mm256);
    k_squeeze<true><<<dim3(HW256/1024,1,nb), 256, 0, stream>>>(SAb, E1p, wt_squ1, D1p, HW256, S256);
  };

  // ---- phase 3: D1 (bf16) -> outputs (attn+final fused) ----
  auto phase3 = [&](int c0, int nz, const ushort_t* D1p, const float* XLp){
    k_convT_mfma<true,true><<<dim3(16,32,nz), 512, 0, stream>>>(D1p, wb4_dt, U1b, 512, 512, S256, S512);
    k_conv_mfma<7,false,true,true><<<dim3(16,32,nz), 512, 0, stream>>>(
        U1b, wb_dt7, wb_pw_dt, nullptr, U2b, MM, 512, 512, S512, S512, 2*HW512);
    k_attn_final<<<dim3(HW512/1024,1,nz), 256, 0, stream>>>(
        U2b, MM, U1b, w_sa_dt, w_img_out, XLp,
        OUT + (size_t)c0*HW512, OUT + 2097152 + (size_t)c0*HW512,
        512, 512, S512, 2*HW512);
  };

  if (CB > 0){
    for (int c0=0;c0<8;c0+=CB)
      phase1(c0, CB, XL + (size_t)c0*HW512, E1b + (size_t)c0*S256);
    deep(8, E1b, U1, U2, E2, Q2, E3, Q3, MM, E1b);
    for (int c0=0;c0<8;c0+=CB)
      phase3(c0, CB, E1b + (size_t)c0*S256, XL + (size_t)c0*HW512);
  } else {
    for (int b=0;b<8;b++){
      phase1(b, 1, XL, E1b);
      deep(1, E1b, U1, U2, E2, Q2, E3, Q3, MM, (ushort_t*)U2);
      phase3(b, 1, (ushort_t*)U2, XL);
    }
  }

  k_diff<<<1, 1, 0, stream>>>(DIFF, OUT + 4194304);
}

// Round 17
// 1269.328 us; speedup vs baseline: 1.3068x; 1.0329x over previous
//
#include <hip/hip_runtime.h>
#include <math.h>

#define CH 24

typedef __attribute__((ext_vector_type(8))) short short8v;
typedef __attribute__((ext_vector_type(4))) float f32x4;
typedef unsigned short ushort_t;
typedef unsigned int uint_t;

__device__ inline ushort_t bf16r(float f){
  uint_t u = __float_as_uint(f);
  u += 0x7FFF + ((u>>16)&1);
  return (ushort_t)(u>>16);
}
__device__ inline float bf2f(uint_t u){ return __uint_as_float(u<<16); }

// ================= merged weight reorder =================
struct WPtrs {
  const float *res_et, *res_dt, *res_em, *res_dm, *res_ed, *res_dd;
  const float *pw_et, *pw_em, *pw_dm, *pw_dt, *pw_ed, *pw_dd;
  const float *out_dd, *out_dm, *out_dt;   // convT (torch IOHW)
  const float *out_et, *out_em, *out_ed;   // down (OIHW)
  const float *squ1, *squ2;
};

__device__ inline void do_rmfma(const float* w, ushort_t* wb, int K, int i){
  int n = K*K*1024; if (i >= n) return;
  int j = i & 7, l = (i>>3) & 63, t = (i>>9) & 1, tap = i >> 10;
  int ci = (l>>4)*8 + j, co = t*16 + (l&15);
  int ky = tap / K, kx = tap % K;
  float v = (ci<24 && co<24) ? w[((co*24+ci)*K+ky)*K+kx] : 0.f;
  wb[i] = bf16r(v);
}
// pw (K=1) with mean column at co=24: B[k][24] = sum_co w[co][k]/24
__device__ inline void do_rmfma_pw(const float* w, ushort_t* wb, int i){
  if (i >= 1024) return;
  int j = i & 7, l = (i>>3) & 63, t = (i>>9) & 1;
  int ci = (l>>4)*8 + j, co = t*16 + (l&15);
  float v = 0.f;
  if (ci < 24){
    if (co < 24) v = w[co*24+ci];
    else if (co == 24){
      float s = 0.f;
      for (int c2=0;c2<24;c2++) s += w[c2*24+ci];
      v = s*(1.f/24.f);
    }
  }
  wb[i] = bf16r(v);
}
__device__ inline void do_rmfma4(const float* w, ushort_t* wb, int i){
  if (i >= 16384) return;
  int j = i & 7, l = (i>>3) & 63, t = (i>>9) & 1, tap = i >> 10;
  int ci = (l>>4)*8 + j, co = t*16 + (l&15);
  int ky = tap >> 2, kx = tap & 3;
  float v = (ci<24 && co<24) ? w[((ci*24+co)*4+ky)*4+kx] : 0.f;
  wb[i] = bf16r(v);
}
__device__ inline void do_rpw48(const float* w, float* wT, int i){
  if (i >= 1152) return;
  int co = i % 24, ci = i/24;
  wT[i] = w[co*48+ci];
}

__global__ void k_reorder(WPtrs P, ushort_t* __restrict__ WB,
                          float* __restrict__ wt_squ1, float* __restrict__ wt_squ2){
  int b = blockIdx.x, t = threadIdx.x;
  if      (b < 196)  do_rmfma(P.res_et, WB+0,      7, b*256+t);
  else if (b < 392)  do_rmfma(P.res_dt, WB+50176,  7, (b-196)*256+t);
  else if (b < 492)  do_rmfma(P.res_em, WB+100352, 5, (b-392)*256+t);
  else if (b < 592)  do_rmfma(P.res_dm, WB+125952, 5, (b-492)*256+t);
  else if (b < 628)  do_rmfma(P.res_ed, WB+253952, 3, (b-592)*256+t);
  else if (b < 664)  do_rmfma(P.res_dd, WB+263168, 3, (b-628)*256+t);
  else if (b < 668)  do_rmfma_pw(P.pw_et, WB+151552, (b-664)*256+t);
  else if (b < 672)  do_rmfma_pw(P.pw_em, WB+152576, (b-668)*256+t);
  else if (b < 676)  do_rmfma_pw(P.pw_dm, WB+153600, (b-672)*256+t);
  else if (b < 680)  do_rmfma_pw(P.pw_dt, WB+154624, (b-676)*256+t);
  else if (b < 684)  do_rmfma_pw(P.pw_ed, WB+272384, (b-680)*256+t);
  else if (b < 688)  do_rmfma_pw(P.pw_dd, WB+273408, (b-684)*256+t);
  else if (b < 752)  do_rmfma4(P.out_dd, WB+155648, (b-688)*256+t);
  else if (b < 816)  do_rmfma4(P.out_dm, WB+172032, (b-752)*256+t);
  else if (b < 880)  do_rmfma4(P.out_dt, WB+188416, (b-816)*256+t);
  else if (b < 944)  do_rmfma(P.out_et, WB+204800, 4, (b-880)*256+t);
  else if (b < 1008) do_rmfma(P.out_em, WB+221184, 4, (b-944)*256+t);
  else if (b < 1072) do_rmfma(P.out_ed, WB+237568, 4, (b-1008)*256+t);
  else if (b < 1077) do_rpw48(P.squ1, wt_squ1, (b-1072)*256+t);
  else if (b < 1082) do_rpw48(P.squ2, wt_squ2, (b-1077)*256+t);
}

// ================= compute kernels =================

__global__ void k_lap(const float* __restrict__ x, float* __restrict__ xl, int H, int W){
  int idx = blockIdx.x*256 + threadIdx.x;
  int HW = H*W;
  if (idx >= HW) return;
  const float* xb = x + (size_t)blockIdx.z*3*HW;
  float* xo = xl + (size_t)blockIdx.z*HW;
  int px = idx % W, py = idx / W;
#define MEANV(yy,xx) (((yy)>=0&&(yy)<H&&(xx)>=0&&(xx)<W) ? (xb[(yy)*W+(xx)]+xb[HW+(yy)*W+(xx)]+xb[2*HW+(yy)*W+(xx)])*(1.f/3.f) : 0.f)
  float v = 4.f*MEANV(py,px) - MEANV(py-1,px) - MEANV(py+1,px) - MEANV(py,px-1) - MEANV(py,px+1);
#undef MEANV
  xo[idx] = v;
}

// ---------- MFMA KxK conv 24->24 FUSED with 1x1 pw + mean/max. 48B records. ----------
// Stage-2 scratch aliases the A-tile LDS (extra barrier after MFMA loop).
// Mean map comes free via pw B column 24 (rowsum/24); only max needs the shfl tree.
template<int K, bool EXPAND, bool INBF, bool OUTBF>
__launch_bounds__(512)
__global__ void k_conv_mfma(const void* in, const ushort_t* __restrict__ wb,
                            const ushort_t* __restrict__ wbpw, const float* __restrict__ wexp,
                            void* out, float* __restrict__ mm,
                            int H, int W, int istrIn, int istrOut, int istrMM){
  constexpr int SW_T = 32 + K - 1;
  constexpr int SH = 16 + K - 1;
  constexpr int NPX = SH*SW_T;
  __shared__ __align__(16) ushort_t lds[NPX*24];
  int tid = threadIdx.x;
  const float* inb_f = (const float*)in + (size_t)blockIdx.z*istrIn;
  const ushort_t* inb_b = (const ushort_t*)in + (size_t)blockIdx.z*istrIn;
  int x0g = blockIdx.x*32 - K/2, y0g = blockIdx.y*16 - K/2;
  int HW = H*W;
  for (int i = tid; i < NPX*3; i += 512){
    int q = i / NPX;
    int pp = i - q*NPX;
    int row = pp / SW_T, col = pp - row*SW_T;
    int gy = y0g + row, gx = x0g + col;
    uint4 w4; w4.x=0u; w4.y=0u; w4.z=0u; w4.w=0u;
    if (gy >= 0 && gy < H && gx >= 0 && gx < W){
      size_t base = (size_t)gy*W + gx;
      int c0 = q*8;
      if (EXPAND){
        float val = inb_f[base];
        w4.x = (uint_t)bf16r(val*wexp[c0+0]) | ((uint_t)bf16r(val*wexp[c0+1])<<16);
        w4.y = (uint_t)bf16r(val*wexp[c0+2]) | ((uint_t)bf16r(val*wexp[c0+3])<<16);
        w4.z = (uint_t)bf16r(val*wexp[c0+4]) | ((uint_t)bf16r(val*wexp[c0+5])<<16);
        w4.w = (uint_t)bf16r(val*wexp[c0+6]) | ((uint_t)bf16r(val*wexp[c0+7])<<16);
      } else if (INBF){
        uint_t u0=inb_b[(size_t)(c0+0)*HW+base], u1=inb_b[(size_t)(c0+1)*HW+base];
        uint_t u2=inb_b[(size_t)(c0+2)*HW+base], u3=inb_b[(size_t)(c0+3)*HW+base];
        uint_t u4=inb_b[(size_t)(c0+4)*HW+base], u5=inb_b[(size_t)(c0+5)*HW+base];
        uint_t u6=inb_b[(size_t)(c0+6)*HW+base], u7=inb_b[(size_t)(c0+7)*HW+base];
        w4.x = u0 | (u1<<16); w4.y = u2 | (u3<<16); w4.z = u4 | (u5<<16); w4.w = u6 | (u7<<16);
      } else {
        w4.x = (uint_t)bf16r(inb_f[(size_t)(c0+0)*HW+base]) | ((uint_t)bf16r(inb_f[(size_t)(c0+1)*HW+base])<<16);
        w4.y = (uint_t)bf16r(inb_f[(size_t)(c0+2)*HW+base]) | ((uint_t)bf16r(inb_f[(size_t)(c0+3)*HW+base])<<16);
        w4.z = (uint_t)bf16r(inb_f[(size_t)(c0+4)*HW+base]) | ((uint_t)bf16r(inb_f[(size_t)(c0+5)*HW+base])<<16);
        w4.w = (uint_t)bf16r(inb_f[(size_t)(c0+6)*HW+base]) | ((uint_t)bf16r(inb_f[(size_t)(c0+7)*HW+base])<<16);
      }
    }
    *(uint4*)(lds + (size_t)pp*24 + q*8) = w4;
  }
  __syncthreads();
  int l = tid & 63, wid = tid >> 6;
  int kg = l >> 4, li = l & 15;
  int kgc = (kg < 3) ? kg : 2;
  f32x4 zero = {0.f,0.f,0.f,0.f};
  f32x4 acc[4][2];
  #pragma unroll
  for (int i=0;i<4;i++){ acc[i][0]=zero; acc[i][1]=zero; }

  const ushort_t* aln = lds + li*24 + kgc*8 + (size_t)wid*SW_T*24;

  #pragma unroll
  for (int ky=0; ky<K; ky++){
    #pragma unroll
    for (int kx=0; kx<K; kx++){
      int tap = ky*K + kx;
      const ushort_t* wp = wb + (size_t)tap*1024;
      short8v b0 = *(const short8v*)(wp + l*8);
      short8v b1 = *(const short8v*)(wp + 512 + l*8);
      #pragma unroll
      for (int i=0;i<4;i++){
        const ushort_t* ap = aln + (((i&1)*8 + ky)*SW_T + (i>>1)*16 + kx)*24;
        short8v a = *(const short8v*)ap;
        acc[i][0] = __builtin_amdgcn_mfma_f32_16x16x32_bf16(a, b0, acc[i][0], 0, 0, 0);
        acc[i][1] = __builtin_amdgcn_mfma_f32_16x16x32_bf16(a, b1, acc[i][1], 0, 0, 0);
      }
    }
  }
  // ---- stage 2: pw 1x1 via second MFMA, + mean/max (scratch aliases lds) ----
  __syncthreads();   // all waves done reading A-tile before scratch overwrites it
  short8v bpw0 = *(const short8v*)(wbpw + l*8);
  short8v bpw1 = *(const short8v*)(wbpw + 512 + l*8);
  uint_t* s = (uint_t*)lds + wid*320;
  float* outb_f = (float*)out + (size_t)blockIdx.z*istrOut;
  ushort_t* outb_b = (ushort_t*)out + (size_t)blockIdx.z*istrOut;
  float* mmb = mm + (size_t)blockIdx.z*istrMM;
  #pragma unroll 1
  for (int i=0;i<4;i++){
    __asm__ volatile("s_waitcnt lgkmcnt(0)" ::: "memory");
    __builtin_amdgcn_sched_barrier(0);
    #pragma unroll
    for (int reg=0; reg<4; reg++){
      float v0 = acc[i][0][reg], v1 = acc[i][1][reg];
      float v0n = __shfl_xor(v0, 1, 64);
      float v1n = __shfl_xor(v1, 1, 64);
      int pxr = kg*4 + reg;
      uint_t packed; int uidx;
      if ((li & 1) == 0){
        packed = (uint_t)bf16r(v0) | ((uint_t)bf16r(v0n) << 16);
        uidx = li >> 1;
      } else {
        packed = (uint_t)bf16r(v1n) | ((uint_t)bf16r(v1) << 16);
        uidx = 8 + (li >> 1);
      }
      s[pxr*20 + uidx] = packed;
    }
    __asm__ volatile("s_waitcnt lgkmcnt(0)" ::: "memory");
    __builtin_amdgcn_sched_barrier(0);
    short8v a2 = *(const short8v*)((const ushort_t*)s + li*40 + kg*8);
    f32x4 d0 = __builtin_amdgcn_mfma_f32_16x16x32_bf16(a2, bpw0, zero, 0, 0, 0);
    f32x4 d1 = __builtin_amdgcn_mfma_f32_16x16x32_bf16(a2, bpw1, zero, 0, 0, 0);
    int gy = blockIdx.y*16 + wid + (i&1)*8;
    int gx = blockIdx.x*32 + (i>>1)*16 + kg*4;
    if (OUTBF){
      uint2 p0; p0.x = (uint_t)bf16r(d0[0]) | ((uint_t)bf16r(d0[1])<<16);
      p0.y = (uint_t)bf16r(d0[2]) | ((uint_t)bf16r(d0[3])<<16);
      *(uint2*)(outb_b + (size_t)li*HW + (size_t)gy*W + gx) = p0;
      if (li < 8){
        uint2 p1; p1.x = (uint_t)bf16r(d1[0]) | ((uint_t)bf16r(d1[1])<<16);
        p1.y = (uint_t)bf16r(d1[2]) | ((uint_t)bf16r(d1[3])<<16);
        *(uint2*)(outb_b + (size_t)(16+li)*HW + (size_t)gy*W + gx) = p1;
      }
    } else {
      *(f32x4*)(outb_f + (size_t)li*HW + (size_t)gy*W + gx) = d0;
      if (li < 8)
        *(f32x4*)(outb_f + (size_t)(16+li)*HW + (size_t)gy*W + gx) = d1;
    }
    f32x4 mx;
    #pragma unroll
    for (int reg=0; reg<4; reg++)
      mx[reg] = fmaxf(d0[reg], (li<8) ? d1[reg] : -3.4e38f);
    #pragma unroll
    for (int m=1; m<16; m<<=1){
      #pragma unroll
      for (int reg=0; reg<4; reg++)
        mx[reg] = fmaxf(mx[reg], __shfl_xor(mx[reg], m, 64));
    }
    if (li == 8)
      *(f32x4*)(mmb + (size_t)gy*W + gx) = d1;           // col 24 = mean (pre-scaled)
    if (li == 0)
      *(f32x4*)(mmb + (size_t)HW + (size_t)gy*W + gx) = mx;
  }
}

// ---------- MFMA ConvTranspose2d(k=4,s=2,p=1), 32x16 out tile ----------
template<bool INBF, bool OUTBF>
__launch_bounds__(512)
__global__ void k_convT_mfma(const void* in, const ushort_t* __restrict__ wb,
                             void* out, int Ho, int Wo, int istrIn, int istrOut){
  const int Hi = Ho>>1, Wi = Wo>>1;
  constexpr int SW_T = 18, NPX = 180;
  __shared__ __align__(16) ushort_t lds[NPX*24];
  int tid = threadIdx.x;
  const float* inb_f = (const float*)in + (size_t)blockIdx.z*istrIn;
  const ushort_t* inb_b = (const ushort_t*)in + (size_t)blockIdx.z*istrIn;
  int X0 = blockIdx.x*32, Y0 = blockIdx.y*16;
  int ix0 = (X0>>1) - 1, iy0 = (Y0>>1) - 1;
  int HWi = Hi*Wi;
  for (int i = tid; i < NPX*3; i += 512){
    int q = i / NPX;
    int pp = i - q*NPX;
    int row = pp / SW_T, col = pp - row*SW_T;
    int gy = iy0 + row, gx = ix0 + col;
    uint4 w4; w4.x=0u; w4.y=0u; w4.z=0u; w4.w=0u;
    if (gy>=0 && gy<Hi && gx>=0 && gx<Wi){
      size_t base = (size_t)gy*Wi + gx;
      int c0 = q*8;
      if (INBF){
        uint_t u0=inb_b[(size_t)(c0+0)*HWi+base], u1=inb_b[(size_t)(c0+1)*HWi+base];
        uint_t u2=inb_b[(size_t)(c0+2)*HWi+base], u3=inb_b[(size_t)(c0+3)*HWi+base];
        uint_t u4=inb_b[(size_t)(c0+4)*HWi+base], u5=inb_b[(size_t)(c0+5)*HWi+base];
        uint_t u6=inb_b[(size_t)(c0+6)*HWi+base], u7=inb_b[(size_t)(c0+7)*HWi+base];
        w4.x = u0 | (u1<<16); w4.y = u2 | (u3<<16); w4.z = u4 | (u5<<16); w4.w = u6 | (u7<<16);
      } else {
        w4.x = (uint_t)bf16r(inb_f[(size_t)(c0+0)*HWi+base]) | ((uint_t)bf16r(inb_f[(size_t)(c0+1)*HWi+base])<<16);
        w4.y = (uint_t)bf16r(inb_f[(size_t)(c0+2)*HWi+base]) | ((uint_t)bf16r(inb_f[(size_t)(c0+3)*HWi+base])<<16);
        w4.z = (uint_t)bf16r(inb_f[(size_t)(c0+4)*HWi+base]) | ((uint_t)bf16r(inb_f[(size_t)(c0+5)*HWi+base])<<16);
        w4.w = (uint_t)bf16r(inb_f[(size_t)(c0+6)*HWi+base]) | ((uint_t)bf16r(inb_f[(size_t)(c0+7)*HWi+base])<<16);
      }
    }
    *(uint4*)(lds + (size_t)pp*24 + q*8) = w4;
  }
  __syncthreads();
  int l = tid & 63, wid = tid >> 6;
  int kg = l >> 4, li = l & 15;
  int kgc = (kg < 3) ? kg : 2;
  f32x4 zero = {0.f,0.f,0.f,0.f};
  f32x4 acc[4][2];
  #pragma unroll
  for (int i=0;i<4;i++){ acc[i][0]=zero; acc[i][1]=zero; }

  const ushort_t* aln = lds + li*24 + kgc*8;

  #pragma unroll
  for (int i=0;i<4;i++){
    int g = wid + 8*i;
    int r = g & 15, q = g >> 4;
    int ky0 = (r+1)&1;
    #pragma unroll
    for (int t2=0;t2<2;t2++){
      int ky = ky0 + 2*t2;
      int liy = ((r+1-ky)>>1) + 1;
      #pragma unroll
      for (int u=0;u<2;u++){
        int kx = (q ? 0 : 1) + 2*u;
        int lixb = ((q+1-kx)>>1) + 1;
        int tap = ky*4 + kx;
        const ushort_t* wp = wb + (size_t)tap*1024;
        short8v b0 = *(const short8v*)(wp + l*8);
        short8v b1 = *(const short8v*)(wp + 512 + l*8);
        short8v a = *(const short8v*)(aln + (liy*SW_T + lixb)*24);
        acc[i][0] = __builtin_amdgcn_mfma_f32_16x16x32_bf16(a, b0, acc[i][0], 0, 0, 0);
        acc[i][1] = __builtin_amdgcn_mfma_f32_16x16x32_bf16(a, b1, acc[i][1], 0, 0, 0);
      }
    }
  }
  float* outb_f = (float*)out + (size_t)blockIdx.z*istrOut;
  ushort_t* outb_b = (ushort_t*)out + (size_t)blockIdx.z*istrOut;
  int HWo = Ho*Wo;
  #pragma unroll
  for (int i=0;i<4;i++){
    int g = wid + 8*i;
    int r = g & 15, q = g >> 4;
    int oy = Y0 + r;
    #pragma unroll
    for (int reg=0; reg<4; reg++){
      int ox = X0 + 2*(kg*4 + reg) + q;
      if (OUTBF){
        outb_b[(size_t)li*HWo + (size_t)oy*Wo + ox] = bf16r(acc[i][0][reg]);
        if (li < 8)
          outb_b[(size_t)(16+li)*HWo + (size_t)oy*Wo + ox] = bf16r(acc[i][1][reg]);
      } else {
        outb_f[(size_t)li*HWo + (size_t)oy*Wo + ox] = acc[i][0][reg];
        if (li < 8)
          outb_f[(size_t)(16+li)*HWo + (size_t)oy*Wo + ox] = acc[i][1][reg];
      }
    }
  }
}

// ---------- MFMA 4x4 s2 p1 downsample, 16x8 out tile ----------
template<bool INBF, bool OUTBF>
__launch_bounds__(512)
__global__ void k_down_mfma(const void* in, const ushort_t* __restrict__ wb,
                            void* out, int Ho, int Wo, int istrIn, int istrOut){
  const int Hi = Ho*2, Wi = Wo*2;
  constexpr int NPX = 18*34;
  __shared__ __align__(16) ushort_t lds[NPX*24];
  int tid = threadIdx.x;
  const float* inb_f = (const float*)in + (size_t)blockIdx.z*istrIn;
  const ushort_t* inb_b = (const ushort_t*)in + (size_t)blockIdx.z*istrIn;
  int X0 = blockIdx.x*16, Y0 = blockIdx.y*8;
  int ix0 = 2*X0 - 1, iy0 = 2*Y0 - 1;
  int HWi = Hi*Wi;
  for (int i = tid; i < NPX*3; i += 512){
    int q = i / NPX;
    int pp = i - q*NPX;
    int row = pp / 34;
    int rem = pp - row*34;
    int par = (rem >= 17) ? 1 : 0;
    int sub = rem - par*17;
    int gx = ix0 + 2*sub + par;
    int gy = iy0 + row;
    uint4 w4; w4.x=0u; w4.y=0u; w4.z=0u; w4.w=0u;
    if (gy>=0 && gy<Hi && gx>=0 && gx<Wi){
      size_t base = (size_t)gy*Wi + gx;
      int c0 = q*8;
      if (INBF){
        uint_t u0=inb_b[(size_t)(c0+0)*HWi+base], u1=inb_b[(size_t)(c0+1)*HWi+base];
        uint_t u2=inb_b[(size_t)(c0+2)*HWi+base], u3=inb_b[(size_t)(c0+3)*HWi+base];
        uint_t u4=inb_b[(size_t)(c0+4)*HWi+base], u5=inb_b[(size_t)(c0+5)*HWi+base];
        uint_t u6=inb_b[(size_t)(c0+6)*HWi+base], u7=inb_b[(size_t)(c0+7)*HWi+base];
        w4.x = u0 | (u1<<16); w4.y = u2 | (u3<<16); w4.z = u4 | (u5<<16); w4.w = u6 | (u7<<16);
      } else {
        w4.x = (uint_t)bf16r(inb_f[(size_t)(c0+0)*HWi+base]) | ((uint_t)bf16r(inb_f[(size_t)(c0+1)*HWi+base])<<16);
        w4.y = (uint_t)bf16r(inb_f[(size_t)(c0+2)*HWi+base]) | ((uint_t)bf16r(inb_f[(size_t)(c0+3)*HWi+base])<<16);
        w4.z = (uint_t)bf16r(inb_f[(size_t)(c0+4)*HWi+base]) | ((uint_t)bf16r(inb_f[(size_t)(c0+5)*HWi+base])<<16);
        w4.w = (uint_t)bf16r(inb_f[(size_t)(c0+6)*HWi+base]) | ((uint_t)bf16r(inb_f[(size_t)(c0+7)*HWi+base])<<16);
      }
    }
    *(uint4*)(lds + (size_t)pp*24 + q*8) = w4;
  }
  __syncthreads();
  int l = tid & 63, wid = tid >> 6;
  int kg = l >> 4, li = l & 15;
  int kgc = (kg < 3) ? kg : 2;
  f32x4 zero = {0.f,0.f,0.f,0.f};
  f32x4 acc0 = zero, acc1 = zero;
  const ushort_t* aln = lds + li*24 + kgc*8 + (size_t)(2*wid)*34*24;
  #pragma unroll
  for (int ky=0; ky<4; ky++){
    #pragma unroll
    for (int kx=0; kx<4; kx++){
      int tap = ky*4 + kx;
      const ushort_t* wp = wb + (size_t)tap*1024;
      short8v b0 = *(const short8v*)(wp + l*8);
      short8v b1 = *(const short8v*)(wp + 512 + l*8);
      short8v a = *(const short8v*)(aln + (ky*34 + (kx&1)*17 + (kx>>1))*24);
      acc0 = __builtin_amdgcn_mfma_f32_16x16x32_bf16(a, b0, acc0, 0, 0, 0);
      acc1 = __builtin_amdgcn_mfma_f32_16x16x32_bf16(a, b1, acc1, 0, 0, 0);
    }
  }
  int HWo = Ho*Wo;
  int oy = Y0 + wid, ox = X0 + kg*4;
  if (OUTBF){
    ushort_t* outb = (ushort_t*)out + (size_t)blockIdx.z*istrOut;
    uint2 p0; p0.x = (uint_t)bf16r(acc0[0]) | ((uint_t)bf16r(acc0[1])<<16);
    p0.y = (uint_t)bf16r(acc0[2]) | ((uint_t)bf16r(acc0[3])<<16);
    *(uint2*)(outb + (size_t)li*HWo + (size_t)oy*Wo + ox) = p0;
    if (li < 8){
      uint2 p1; p1.x = (uint_t)bf16r(acc1[0]) | ((uint_t)bf16r(acc1[1])<<16);
      p1.y = (uint_t)bf16r(acc1[2]) | ((uint_t)bf16r(acc1[3])<<16);
      *(uint2*)(outb + (size_t)(16+li)*HWo + (size_t)oy*Wo + ox) = p1;
    }
  } else {
    float* outb = (float*)out + (size_t)blockIdx.z*istrOut;
    *(f32x4*)(outb + (size_t)li*HWo + (size_t)oy*Wo + ox) = acc0;
    if (li < 8)
      *(f32x4*)(outb + (size_t)(16+li)*HWo + (size_t)oy*Wo + ox) = acc1;
  }
}

// spatial attn + sigmoid + relu + residual add; BF: R/X/out are bf16 planes
template<bool BF>
__global__ void k_attn_res(const void* R_, const float* __restrict__ M,
                           const void* X_, const float* __restrict__ wsa,
                           void* out_, int H, int W, int istr, int istrMM){
  int p = (blockIdx.x*256 + threadIdx.x)*4;
  int HW = H*W;
  if (p >= HW) return;
  int py = p / W, px0 = p % W;
  const float* Mb = M + (size_t)blockIdx.z*istrMM;
  float s[4]={0,0,0,0};
  #pragma unroll
  for (int cc=0;cc<2;cc++){
    const float* Mc = Mb + (size_t)cc*HW;
    #pragma unroll 1
    for (int ky=0;ky<7;ky++){
      int gy = py+ky-3;
      if (gy<0||gy>=H) continue;
      const float* mr = Mc + (size_t)gy*W;
      float mv[10];
      #pragma unroll
      for (int j=0;j<10;j++){
        int gx = px0-3+j;
        mv[j] = (gx>=0 && gx<W) ? mr[gx] : 0.f;
      }
      const float* wr = wsa + (cc*7+ky)*7;
      #pragma unroll
      for (int kx=0;kx<7;kx++){
        float wv = wr[kx];
        #pragma unroll
        for (int px=0;px<4;px++) s[px] = fmaf(mv[kx+px], wv, s[px]);
      }
    }
  }
  float g[4];
  #pragma unroll
  for (int px=0;px<4;px++) g[px] = 1.f/(1.f+expf(-s[px]));
  #pragma unroll
  for (int c=0;c<CH;c++){
    float r0,r1,r2,r3, x0v,x1v,x2v,x3v;
    if (BF){
      const ushort_t* Rb = (const ushort_t*)R_ + (size_t)blockIdx.z*istr + (size_t)c*HW + p;
      const ushort_t* Xb = (const ushort_t*)X_ + (size_t)blockIdx.z*istr + (size_t)c*HW + p;
      uint2 rv = *(const uint2*)Rb;
      uint2 xv = *(const uint2*)Xb;
      r0=bf2f(rv.x&0xffffu); r1=bf2f(rv.x>>16); r2=bf2f(rv.y&0xffffu); r3=bf2f(rv.y>>16);
      x0v=bf2f(xv.x&0xffffu); x1v=bf2f(xv.x>>16); x2v=bf2f(xv.y&0xffffu); x3v=bf2f(xv.y>>16);
    } else {
      const float* Rb = (const float*)R_ + (size_t)blockIdx.z*istr + (size_t)c*HW + p;
      const float* Xb = (const float*)X_ + (size_t)blockIdx.z*istr + (size_t)c*HW + p;
      float4 rv = *(const float4*)Rb;
      float4 xv = *(const float4*)Xb;
      r0=rv.x; r1=rv.y; r2=rv.z; r3=rv.w;
      x0v=xv.x; x1v=xv.y; x2v=xv.z; x3v=xv.w;
    }
    float o0 = x0v + fmaxf(r0*g[0], 0.f);
    float o1 = x1v + fmaxf(r1*g[1], 0.f);
    float o2 = x2v + fmaxf(r2*g[2], 0.f);
    float o3 = x3v + fmaxf(r3*g[3], 0.f);
    if (BF){
      ushort_t* Ob = (ushort_t*)out_ + (size_t)blockIdx.z*istr + (size_t)c*HW + p;
      uint2 ov;
      ov.x = (uint_t)bf16r(o0) | ((uint_t)bf16r(o1)<<16);
      ov.y = (uint_t)bf16r(o2) | ((uint_t)bf16r(o3)<<16);
      *(uint2*)Ob = ov;
    } else {
      float* Ob = (float*)out_ + (size_t)blockIdx.z*istr + (size_t)c*HW + p;
      float4 ov; ov.x=o0; ov.y=o1; ov.z=o2; ov.w=o3;
      *(float4*)Ob = ov;
    }
  }
}

// variant: residual computed from XL*wexp; BF: R/out bf16
template<bool BF>
__global__ void k_attn_res_x(const void* R_, const float* __restrict__ M,
                             const float* __restrict__ XL, const float* __restrict__ wsa,
                             const float* __restrict__ wexp,
                             void* out_, int H, int W, int istr, int istrMM){
  int p = (blockIdx.x*256 + threadIdx.x)*4;
  int HW = H*W;
  if (p >= HW) return;
  int py = p / W, px0 = p % W;
  const float* Mb = M + (size_t)blockIdx.z*istrMM;
  float s[4]={0,0,0,0};
  #pragma unroll
  for (int cc=0;cc<2;cc++){
    const float* Mc = Mb + (size_t)cc*HW;
    #pragma unroll 1
    for (int ky=0;ky<7;ky++){
      int gy = py+ky-3;
      if (gy<0||gy>=H) continue;
      const float* mr = Mc + (size_t)gy*W;
      float mv[10];
      #pragma unroll
      for (int j=0;j<10;j++){
        int gx = px0-3+j;
        mv[j] = (gx>=0 && gx<W) ? mr[gx] : 0.f;
      }
      const float* wr = wsa + (cc*7+ky)*7;
      #pragma unroll
      for (int kx=0;kx<7;kx++){
        float wv = wr[kx];
        #pragma unroll
        for (int px=0;px<4;px++) s[px] = fmaf(mv[kx+px], wv, s[px]);
      }
    }
  }
  float g[4];
  #pragma unroll
  for (int px=0;px<4;px++) g[px] = 1.f/(1.f+expf(-s[px]));
  float4 xl4 = *(const float4*)(XL + (size_t)blockIdx.z*HW + p);
  #pragma unroll
  for (int c=0;c<CH;c++){
    float wc = wexp[c];
    float r0,r1,r2,r3;
    if (BF){
      const ushort_t* Rb = (const ushort_t*)R_ + (size_t)blockIdx.z*istr + (size_t)c*HW + p;
      uint2 rv = *(const uint2*)Rb;
      r0=bf2f(rv.x&0xffffu); r1=bf2f(rv.x>>16); r2=bf2f(rv.y&0xffffu); r3=bf2f(rv.y>>16);
    } else {
      const float* Rb = (const float*)R_ + (size_t)blockIdx.z*istr + (size_t)c*HW + p;
      float4 rv = *(const float4*)Rb;
      r0=rv.x; r1=rv.y; r2=rv.z; r3=rv.w;
    }
    float o0 = xl4.x*wc + fmaxf(r0*g[0], 0.f);
    float o1 = xl4.y*wc + fmaxf(r1*g[1], 0.f);
    float o2 = xl4.z*wc + fmaxf(r2*g[2], 0.f);
    float o3 = xl4.w*wc + fmaxf(r3*g[3], 0.f);
    if (BF){
      ushort_t* Ob = (ushort_t*)out_ + (size_t)blockIdx.z*istr + (size_t)c*HW + p;
      uint2 ov;
      ov.x = (uint_t)bf16r(o0) | ((uint_t)bf16r(o1)<<16);
      ov.y = (uint_t)bf16r(o2) | ((uint_t)bf16r(o3)<<16);
      *(uint2*)Ob = ov;
    } else {
      float* Ob = (float*)out_ + (size_t)blockIdx.z*istr + (size_t)c*HW + p;
      float4 ov; ov.x=o0; ov.y=o1; ov.z=o2; ov.w=o3;
      *(float4*)Ob = ov;
    }
  }
}

// FUSED attn_res(dt) + final
__global__ void k_attn_final(const ushort_t* __restrict__ R, const float* __restrict__ M,
                             const ushort_t* __restrict__ X, const float* __restrict__ wsa,
                             const float* __restrict__ wout, const float* __restrict__ xl,
                             float* __restrict__ outMask, float* __restrict__ outClean,
                             int H, int W, int istr, int istrMM){
  int p = (blockIdx.x*256 + threadIdx.x)*4;
  int HW = H*W;
  if (p >= HW) return;
  int py = p / W, px0 = p % W;
  const float* Mb = M + (size_t)blockIdx.z*istrMM;
  float s[4]={0,0,0,0};
  #pragma unroll
  for (int cc=0;cc<2;cc++){
    const float* Mc = Mb + (size_t)cc*HW;
    #pragma unroll 1
    for (int ky=0;ky<7;ky++){
      int gy = py+ky-3;
      if (gy<0||gy>=H) continue;
      const float* mr = Mc + (size_t)gy*W;
      float mv[10];
      #pragma unroll
      for (int j=0;j<10;j++){
        int gx = px0-3+j;
        mv[j] = (gx>=0 && gx<W) ? mr[gx] : 0.f;
      }
      const float* wr = wsa + (cc*7+ky)*7;
      #pragma unroll
      for (int kx=0;kx<7;kx++){
        float wv = wr[kx];
        #pragma unroll
        for (int px=0;px<4;px++) s[px] = fmaf(mv[kx+px], wv, s[px]);
      }
    }
  }
  float g[4];
  #pragma unroll
  for (int px=0;px<4;px++) g[px] = 1.f/(1.f+expf(-s[px]));
  float m0=0.f,m1=0.f,m2=0.f,m3=0.f;
  #pragma unroll
  for (int c=0;c<CH;c++){
    const ushort_t* Rb = R + (size_t)blockIdx.z*istr + (size_t)c*HW + p;
    const ushort_t* Xb = X + (size_t)blockIdx.z*istr + (size_t)c*HW + p;
    uint2 rv = *(const uint2*)Rb;
    uint2 xv = *(const uint2*)Xb;
    float wc = wout[c];
    float o0 = bf2f(xv.x&0xffffu) + fmaxf(bf2f(rv.x&0xffffu)*g[0], 0.f);
    float o1 = bf2f(xv.x>>16)     + fmaxf(bf2f(rv.x>>16)*g[1], 0.f);
    float o2 = bf2f(xv.y&0xffffu) + fmaxf(bf2f(rv.y&0xffffu)*g[2], 0.f);
    float o3 = bf2f(xv.y>>16)     + fmaxf(bf2f(rv.y>>16)*g[3], 0.f);
    m0 = fmaf(o0,wc,m0); m1 = fmaf(o1,wc,m1); m2 = fmaf(o2,wc,m2); m3 = fmaf(o3,wc,m3);
  }
  float4 xlv = *(const float4*)(xl + (size_t)blockIdx.z*HW + p);
  float4 mo; mo.x=m0; mo.y=m1; mo.z=m2; mo.w=m3;
  float4 co; co.x=xlv.x-m0; co.y=xlv.y-m1; co.z=xlv.z-m2; co.w=xlv.w-m3;
  *(float4*)(outMask + (size_t)blockIdx.z*HW + p) = mo;
  *(float4*)(outClean + (size_t)blockIdx.z*HW + p) = co;
}

// 1x1 conv 48->24 over concat(A,B); BF: all planes bf16
template<bool BF>
__global__ void k_squeeze(const void* inA_, const void* inB_,
                          const float* __restrict__ wT, void* out_, int HW, int istr){
  int p = (blockIdx.x*256 + threadIdx.x)*4;
  if (p >= HW) return;
  float acc[CH][4];
  #pragma unroll
  for (int co=0;co<CH;co++){ acc[co][0]=0;acc[co][1]=0;acc[co][2]=0;acc[co][3]=0; }
  #pragma unroll 1
  for (int ci=0;ci<48;ci++){
    float v0,v1,v2,v3;
    if (BF){
      const ushort_t* src = (ci<24)
        ? ((const ushort_t*)inA_ + (size_t)blockIdx.z*istr + (size_t)ci*HW + p)
        : ((const ushort_t*)inB_ + (size_t)blockIdx.z*istr + (size_t)(ci-24)*HW + p);
      uint2 rv = *(const uint2*)src;
      v0=bf2f(rv.x&0xffffu); v1=bf2f(rv.x>>16); v2=bf2f(rv.y&0xffffu); v3=bf2f(rv.y>>16);
    } else {
      const float* src = (ci<24)
        ? ((const float*)inA_ + (size_t)blockIdx.z*istr + (size_t)ci*HW + p)
        : ((const float*)inB_ + (size_t)blockIdx.z*istr + (size_t)(ci-24)*HW + p);
      float4 rv = *(const float4*)src;
      v0=rv.x; v1=rv.y; v2=rv.z; v3=rv.w;
    }
    const float* wp = wT + ci*24;
    #pragma unroll
    for (int co=0;co<CH;co++){
      float wv = wp[co];
      acc[co][0] = fmaf(v0, wv, acc[co][0]);
      acc[co][1] = fmaf(v1, wv, acc[co][1]);
      acc[co][2] = fmaf(v2, wv, acc[co][2]);
      acc[co][3] = fmaf(v3, wv, acc[co][3]);
    }
  }
  #pragma unroll
  for (int co=0;co<CH;co++){
    if (BF){
      ushort_t* ob = (ushort_t*)out_ + (size_t)blockIdx.z*istr + (size_t)co*HW + p;
      uint2 ov;
      ov.x = (uint_t)bf16r(acc[co][0]) | ((uint_t)bf16r(acc[co][1])<<16);
      ov.y = (uint_t)bf16r(acc[co][2]) | ((uint_t)bf16r(acc[co][3])<<16);
      *(uint2*)ob = ov;
    } else {
      float* ob = (float*)out_ + (size_t)blockIdx.z*istr + (size_t)co*HW + p;
      float4 o; o.x=acc[co][0]; o.y=acc[co][1]; o.z=acc[co][2]; o.w=acc[co][3];
      *(float4*)ob = o;
    }
  }
}

__global__ void k_quant(const float* __restrict__ enc, const float* __restrict__ embed,
                        float* __restrict__ qt, float* __restrict__ diffAcc, int HW, int istr){
  __shared__ float em[256*28];
  __shared__ float red[4];
  {
    int j = threadIdx.x;
    float s = 0.f;
    #pragma unroll
    for (int c=0;c<CH;c++){
      float e = embed[c*256+j];
      em[j*28+c] = -2.0f*e;
      s = fmaf(e,e,s);
    }
    em[j*28+24] = s; em[j*28+25]=0.f; em[j*28+26]=0.f; em[j*28+27]=0.f;
  }
  __syncthreads();
  int p = blockIdx.x*256 + threadIdx.x;
  const float* eb = enc + (size_t)blockIdx.z*istr;
  float f[CH];
  #pragma unroll
  for (int c=0;c<CH;c++) f[c] = eb[(size_t)c*HW + p];
  float best = 3.4e38f; int bj = 0;
  #pragma unroll 1
  for (int j=0;j<256;j++){
    const float4* row = (const float4*)&em[j*28];
    float s = em[j*28+24];
    #pragma unroll
    for (int q4=0;q4<6;q4++){
      float4 r = row[q4];
      s = fmaf(f[q4*4+0], r.x, s);
      s = fmaf(f[q4*4+1], r.y, s);
      s = fmaf(f[q4*4+2], r.z, s);
      s = fmaf(f[q4*4+3], r.w, s);
    }
    if (s < best){ best = s; bj = j; }
  }
  float* qb = qt + (size_t)blockIdx.z*istr;
  float d = 0.f;
  #pragma unroll
  for (int c=0;c<CH;c++){
    float q = embed[c*256+bj];
    qb[(size_t)c*HW + p] = q;
    float e = q - f[c];
    d = fmaf(e,e,d);
  }
  #pragma unroll
  for (int off=32; off>0; off>>=1) d += __shfl_down(d, off, 64);
  int lane = threadIdx.x & 63, wv = threadIdx.x >> 6;
  if (lane==0) red[wv] = d;
  __syncthreads();
  if (threadIdx.x==0) atomicAdd(diffAcc, red[0]+red[1]+red[2]+red[3]);
}

__global__ void k_diff(const float* __restrict__ acc, float* __restrict__ out){
  out[0] = acc[0]*(1.f/3145728.f) + acc[1]*(1.f/786432.f);
}

// =======================================================================
extern "C" void kernel_launch(void* const* d_in, const int* in_sizes, int n_in,
                              void* d_out, int out_size, void* d_ws, size_t ws_size,
                              hipStream_t stream) {
  const float* x        = (const float*)d_in[0];
  const float* embed2   = (const float*)d_in[1];
  const float* embed3   = (const float*)d_in[2];
  const float* w_img_in = (const float*)d_in[3];
  const float* w_img_out= (const float*)d_in[4];
  const float* w_out_dd = (const float*)d_in[5];
  const float* w_out_dm = (const float*)d_in[6];
  const float* w_out_dt = (const float*)d_in[7];
  const float* w_out_ed = (const float*)d_in[8];
  const float* w_out_em = (const float*)d_in[9];
  const float* w_out_et = (const float*)d_in[10];
  const float* w_pw_dd  = (const float*)d_in[11];
  const float* w_pw_dm  = (const float*)d_in[12];
  const float* w_pw_dt  = (const float*)d_in[13];
  const float* w_pw_ed  = (const float*)d_in[14];
  const float* w_pw_em  = (const float*)d_in[15];
  const float* w_pw_et  = (const float*)d_in[16];
  const float* w_res_dd = (const float*)d_in[17];
  const float* w_res_dm = (const float*)d_in[18];
  const float* w_res_dt = (const float*)d_in[19];
  const float* w_res_ed = (const float*)d_in[20];
  const float* w_res_em = (const float*)d_in[21];
  const float* w_res_et = (const float*)d_in[22];
  const float* w_sa_dd  = (const float*)d_in[23];
  const float* w_sa_dm  = (const float*)d_in[24];
  const float* w_sa_dt  = (const float*)d_in[25];
  const float* w_sa_ed  = (const float*)d_in[26];
  const float* w_sa_em  = (const float*)d_in[27];
  const float* w_sa_et  = (const float*)d_in[28];
  const float* w_squ1   = (const float*)d_in[29];
  const float* w_squ2   = (const float*)d_in[30];
  (void)in_sizes; (void)n_in; (void)out_size;

  const int HW512 = 512*512, HW256 = 256*256, HW128 = 128*128, HW64 = 64*64;
  const int S512 = 24*HW512, S256 = 24*HW256, S128 = 24*HW128, S64 = 24*HW64;

  float* ws = (float*)d_ws;
  float* OUT = (float*)d_out;
  size_t F = ws_size / sizeof(float);

  float* WT      = ws;
  float* wt_squ1 = WT + 154368;
  float* wt_squ2 = WT + 155520;

  ushort_t* WB = (ushort_t*)(ws + 160000);
  ushort_t* wb_et7   = WB;
  ushort_t* wb_dt7   = WB + 50176;
  ushort_t* wb_em5   = WB + 100352;
  ushort_t* wb_dm5   = WB + 125952;
  ushort_t* wb_pw_et = WB + 151552;
  ushort_t* wb_pw_em = WB + 152576;
  ushort_t* wb_pw_dm = WB + 153600;
  ushort_t* wb_pw_dt = WB + 154624;
  ushort_t* wb4_dd   = WB + 155648;
  ushort_t* wb4_dm   = WB + 172032;
  ushort_t* wb4_dt   = WB + 188416;
  ushort_t* wb4d_et  = WB + 204800;
  ushort_t* wb4d_em  = WB + 221184;
  ushort_t* wb4d_ed  = WB + 237568;
  ushort_t* wb_ed3   = WB + 253952;
  ushort_t* wb_dd3   = WB + 263168;
  ushort_t* wb_pw_ed = WB + 272384;
  ushort_t* wb_pw_dd = WB + 273408;

  const size_t ABASE = 300000;

  auto needBatched = [&](size_t CB)->size_t{
    size_t u_f = (CB*(size_t)S512 + 1)/2;
    if ((size_t)4*S256 > u_f) u_f = (size_t)4*S256;
    if ((size_t)8*S128 > u_f) u_f = (size_t)8*S128;
    return ABASE + 2097152 + (size_t)4*S256 + 3145728 + 786432 + CB*524288 + 2*u_f + 2;
  };
  int CB = 0;
  if (F >= needBatched(8)) CB = 8;
  else if (F >= needBatched(4)) CB = 4;
  else if (F >= needBatched(2)) CB = 2;
  const size_t NEED_B = ABASE + 15925250;
  if (CB == 0 && F < NEED_B) return;

  float *XL, *E2, *Q2, *E3, *Q3, *MM, *DIFF, *U1, *U2;
  ushort_t* E1b;
  if (CB > 0){
    size_t off = ABASE;
    size_t u_f = (CB*(size_t)S512 + 1)/2;
    if ((size_t)4*S256 > u_f) u_f = (size_t)4*S256;
    if ((size_t)8*S128 > u_f) u_f = (size_t)8*S128;
    XL = ws + off; off += 2097152;
    E1b = (ushort_t*)(ws + off); off += (size_t)4*S256;
    Q2 = ws + off; off += 3145728;
    Q3 = ws + off; off += 786432;
    MM = ws + off; off += CB*524288;
    U1 = ws + off; off += u_f;
    U2 = ws + off; off += u_f;
    DIFF = ws + off;
    E2 = OUT;
    E3 = OUT + 3145728;
  } else {
    size_t off = ABASE;
    XL = ws + off; off += 262144;
    U1 = ws + off; off += 6291456;
    U2 = ws + off; off += 6291456;
    E1b = (ushort_t*)(ws + off); off += 1572864;
    E2 = ws + off; off += 393216;
    Q2 = ws + off; off += 393216;
    E3 = ws + off; off += 98304;
    Q3 = ws + off; off += 98304;
    MM = ws + off; off += 524288;
    DIFF = ws + off;
  }
  ushort_t* U1b = (ushort_t*)U1;
  ushort_t* U2b = (ushort_t*)U2;

  // ---- merged weight reorder (single launch) ----
  WPtrs P;
  P.res_et=w_res_et; P.res_dt=w_res_dt; P.res_em=w_res_em; P.res_dm=w_res_dm;
  P.res_ed=w_res_ed; P.res_dd=w_res_dd;
  P.pw_et=w_pw_et; P.pw_em=w_pw_em; P.pw_dm=w_pw_dm; P.pw_dt=w_pw_dt;
  P.pw_ed=w_pw_ed; P.pw_dd=w_pw_dd;
  P.out_dd=w_out_dd; P.out_dm=w_out_dm; P.out_dt=w_out_dt;
  P.out_et=w_out_et; P.out_em=w_out_em; P.out_ed=w_out_ed;
  P.squ1=w_squ1; P.squ2=w_squ2;
  k_reorder<<<dim3(1082), 256, 0, stream>>>(P, WB, wt_squ1, wt_squ2);

  hipMemsetAsync(DIFF, 0, 2*sizeof(float), stream);

  // ---- phase 1: input -> enc1 (E1 bf16) ----
  auto phase1 = [&](int c0, int nz, float* XLp, ushort_t* E1p){
    k_lap<<<dim3(HW512/256,1,nz), 256, 0, stream>>>(x + (size_t)c0*3*HW512, XLp, 512, 512);
    k_conv_mfma<7,true,false,true><<<dim3(16,32,nz), 512, 0, stream>>>(
        XLp, wb_et7, wb_pw_et, w_img_in, U2b, MM, 512, 512, HW512, S512, 2*HW512);
    k_attn_res_x<true><<<dim3(HW512/1024,1,nz), 256, 0, stream>>>(
        U2b, MM, XLp, w_sa_et, w_img_in, U1b, 512, 512, S512, 2*HW512);
    k_down_mfma<true,true><<<dim3(16,32,nz), 512, 0, stream>>>(U1b, wb4d_et, E1p, 256, 256, S512, S256);
  };

  // ---- deep: enc1 -> squ1 output ----
  auto deep = [&](int nb, ushort_t* E1p, float* SAp, float* SBp, float* E2p, float* Q2p,
                  float* E3p, float* Q3p, float* MMp, ushort_t* D1p){
    ushort_t* SAb = (ushort_t*)SAp;
    ushort_t* SBb = (ushort_t*)SBp;
    int mm256 = 2*HW256, mm128 = 2*HW128;
    k_conv_mfma<5,false,true,true><<<dim3(8,16,nb), 512, 0, stream>>>(
        E1p, wb_em5, wb_pw_em, nullptr, SAb, MMp, 256, 256, S256, S256, mm256);
    k_attn_res<true><<<dim3(HW256/1024,1,nb), 256, 0, stream>>>(SAb, MMp, E1p, w_sa_em, SBb, 256, 256, S256, mm256);
    k_down_mfma<true,false><<<dim3(8,16,nb), 512, 0, stream>>>(SBb, wb4d_em, E2p, 128, 128, S256, S128);
    k_conv_mfma<3,false,false,false><<<dim3(4,8,nb), 512, 0, stream>>>(
        E2p, wb_ed3, wb_pw_ed, nullptr, SAp, MMp, 128, 128, S128, S128, mm128);
    k_attn_res<false><<<dim3(HW128/1024,1,nb), 256, 0, stream>>>(SAp, MMp, E2p, w_sa_ed, SBp, 128, 128, S128, mm128);
    k_down_mfma<false,false><<<dim3(4,8,nb), 512, 0, stream>>>(SBp, wb4d_ed, E3p, 64, 64, S128, S64);
    k_quant<<<dim3(HW128/256,1,nb), 256, 0, stream>>>(E2p, embed2, Q2p, DIFF+0, HW128, S128);
    k_quant<<<dim3(HW64/256,1,nb), 256, 0, stream>>>(E3p, embed3, Q3p, DIFF+1, HW64, S64);
    k_convT_mfma<false,false><<<dim3(4,8,nb), 512, 0, stream>>>(Q3p, wb4_dd, SAp, 128, 128, S64, S128);
    k_conv_mfma<3,false,false,false><<<dim3(4,8,nb), 512, 0, stream>>>(
        SAp, wb_dd3, wb_pw_dd, nullptr, SBp, MMp, 128, 128, S128, S128, mm128);
    k_attn_res<false><<<dim3(HW128/1024,1,nb), 256, 0, stream>>>(SBp, MMp, SAp, w_sa_dd, SAp, 128, 128, S128, mm128);
    k_squeeze<false><<<dim3(HW128/1024,1,nb), 256, 0, stream>>>(SAp, Q2p, wt_squ2, SBp, HW128, S128);
    k_convT_mfma<false,true><<<dim3(8,16,nb), 512, 0, stream>>>(SBp, wb4_dm, SAb, 256, 256, S128, S256);
    k_conv_mfma<5,false,true,true><<<dim3(8,16,nb), 512, 0, stream>>>(
        SAb, wb_dm5, wb_pw_dm, nullptr, SBb, MMp, 256, 256, S256, S256, mm256);
    k_attn_res<true><<<dim3(HW256/1024,1,nb), 256, 0, stream>>>(SBb, MMp, SAb, w_sa_dm, SAb, 256, 256, S256, mm256);
    k_squeeze<true><<<dim3(HW256/1024,1,nb), 256, 0, stream>>>(SAb, E1p, wt_squ1, D1p, HW256, S256);
  };

  // ---- phase 3: D1 (bf16) -> outputs ----
  auto phase3 = [&](int c0, int nz, const ushort_t* D1p, const float* XLp){
    k_convT_mfma<true,true><<<dim3(16,32,nz), 512, 0, stream>>>(D1p, wb4_dt, U1b, 512, 512, S256, S512);
    k_conv_mfma<7,false,true,true><<<dim3(16,32,nz), 512, 0, stream>>>(
        U1b, wb_dt7, wb_pw_dt, nullptr, U2b, MM, 512, 512, S512, S512, 2*HW512);
    k_attn_final<<<dim3(HW512/1024,1,nz), 256, 0, stream>>>(
        U2b, MM, U1b, w_sa_dt, w_img_out, XLp,
        OUT + (size_t)c0*HW512, OUT + 2097152 + (size_t)c0*HW512,
        512, 512, S512, 2*HW512);
  };

  if (CB > 0){
    for (int c0=0;c0<8;c0+=CB)
      phase1(c0, CB, XL + (size_t)c0*HW512, E1b + (size_t)c0*S256);
    deep(8, E1b, U1, U2, E2, Q2, E3, Q3, MM, E1b);
    for (int c0=0;c0<8;c0+=CB)
      phase3(c0, CB, E1b + (size_t)c0*S256, XL + (size_t)c0*HW512);
  } else {
    for (int b=0;b<8;b++){
      phase1(b, 1, XL, E1b);
      deep(1, E1b, U1, U2, E2, Q2, E3, Q3, MM, (ushort_t*)U2);
      phase3(b, 1, (ushort_t*)U2, XL);
    }
  }

  k_diff<<<1, 1, 0, stream>>>(DIFF, OUT + 4194304);
}

// Round 18
// 1257.091 us; speedup vs baseline: 1.3195x; 1.0097x over previous
//
#include <hip/hip_runtime.h>
#include <math.h>

#define CH 24

typedef __attribute__((ext_vector_type(8))) short short8v;
typedef __attribute__((ext_vector_type(4))) float f32x4;
typedef unsigned short ushort_t;
typedef unsigned int uint_t;

__device__ inline ushort_t bf16r(float f){
  uint_t u = __float_as_uint(f);
  u += 0x7FFF + ((u>>16)&1);
  return (ushort_t)(u>>16);
}
__device__ inline float bf2f(uint_t u){ return __uint_as_float(u<<16); }

// ================= merged weight reorder =================
struct WPtrs {
  const float *res_et, *res_dt, *res_em, *res_dm, *res_ed, *res_dd;
  const float *pw_et, *pw_em, *pw_dm, *pw_dt, *pw_ed, *pw_dd;
  const float *out_dd, *out_dm, *out_dt;   // convT (torch IOHW)
  const float *out_et, *out_em, *out_ed;   // down (OIHW)
  const float *squ1, *squ2;
};

__device__ inline void do_rmfma(const float* w, ushort_t* wb, int K, int i){
  int n = K*K*1024; if (i >= n) return;
  int j = i & 7, l = (i>>3) & 63, t = (i>>9) & 1, tap = i >> 10;
  int ci = (l>>4)*8 + j, co = t*16 + (l&15);
  int ky = tap / K, kx = tap % K;
  float v = (ci<24 && co<24) ? w[((co*24+ci)*K+ky)*K+kx] : 0.f;
  wb[i] = bf16r(v);
}
// pw (K=1) with mean column at co=24: B[k][24] = sum_co w[co][k]/24
__device__ inline void do_rmfma_pw(const float* w, ushort_t* wb, int i){
  if (i >= 1024) return;
  int j = i & 7, l = (i>>3) & 63, t = (i>>9) & 1;
  int ci = (l>>4)*8 + j, co = t*16 + (l&15);
  float v = 0.f;
  if (ci < 24){
    if (co < 24) v = w[co*24+ci];
    else if (co == 24){
      float s = 0.f;
      for (int c2=0;c2<24;c2++) s += w[c2*24+ci];
      v = s*(1.f/24.f);
    }
  }
  wb[i] = bf16r(v);
}
__device__ inline void do_rmfma4(const float* w, ushort_t* wb, int i){
  if (i >= 16384) return;
  int j = i & 7, l = (i>>3) & 63, t = (i>>9) & 1, tap = i >> 10;
  int ci = (l>>4)*8 + j, co = t*16 + (l&15);
  int ky = tap >> 2, kx = tap & 3;
  float v = (ci<24 && co<24) ? w[((ci*24+co)*4+ky)*4+kx] : 0.f;
  wb[i] = bf16r(v);
}
__device__ inline void do_rpw48(const float* w, float* wT, int i){
  if (i >= 1152) return;
  int co = i % 24, ci = i/24;
  wT[i] = w[co*48+ci];
}

__global__ void k_reorder(WPtrs P, ushort_t* __restrict__ WB,
                          float* __restrict__ wt_squ1, float* __restrict__ wt_squ2){
  int b = blockIdx.x, t = threadIdx.x;
  if      (b < 196)  do_rmfma(P.res_et, WB+0,      7, b*256+t);
  else if (b < 392)  do_rmfma(P.res_dt, WB+50176,  7, (b-196)*256+t);
  else if (b < 492)  do_rmfma(P.res_em, WB+100352, 5, (b-392)*256+t);
  else if (b < 592)  do_rmfma(P.res_dm, WB+125952, 5, (b-492)*256+t);
  else if (b < 628)  do_rmfma(P.res_ed, WB+253952, 3, (b-592)*256+t);
  else if (b < 664)  do_rmfma(P.res_dd, WB+263168, 3, (b-628)*256+t);
  else if (b < 668)  do_rmfma_pw(P.pw_et, WB+151552, (b-664)*256+t);
  else if (b < 672)  do_rmfma_pw(P.pw_em, WB+152576, (b-668)*256+t);
  else if (b < 676)  do_rmfma_pw(P.pw_dm, WB+153600, (b-672)*256+t);
  else if (b < 680)  do_rmfma_pw(P.pw_dt, WB+154624, (b-676)*256+t);
  else if (b < 684)  do_rmfma_pw(P.pw_ed, WB+272384, (b-680)*256+t);
  else if (b < 688)  do_rmfma_pw(P.pw_dd, WB+273408, (b-684)*256+t);
  else if (b < 752)  do_rmfma4(P.out_dd, WB+155648, (b-688)*256+t);
  else if (b < 816)  do_rmfma4(P.out_dm, WB+172032, (b-752)*256+t);
  else if (b < 880)  do_rmfma4(P.out_dt, WB+188416, (b-816)*256+t);
  else if (b < 944)  do_rmfma(P.out_et, WB+204800, 4, (b-880)*256+t);
  else if (b < 1008) do_rmfma(P.out_em, WB+221184, 4, (b-944)*256+t);
  else if (b < 1072) do_rmfma(P.out_ed, WB+237568, 4, (b-1008)*256+t);
  else if (b < 1077) do_rpw48(P.squ1, wt_squ1, (b-1072)*256+t);
  else if (b < 1082) do_rpw48(P.squ2, wt_squ2, (b-1077)*256+t);
}

// ================= compute kernels =================

__global__ void k_lap(const float* __restrict__ x, float* __restrict__ xl, int H, int W){
  int idx = blockIdx.x*256 + threadIdx.x;
  int HW = H*W;
  if (idx >= HW) return;
  const float* xb = x + (size_t)blockIdx.z*3*HW;
  float* xo = xl + (size_t)blockIdx.z*HW;
  int px = idx % W, py = idx / W;
#define MEANV(yy,xx) (((yy)>=0&&(yy)<H&&(xx)>=0&&(xx)<W) ? (xb[(yy)*W+(xx)]+xb[HW+(yy)*W+(xx)]+xb[2*HW+(yy)*W+(xx)])*(1.f/3.f) : 0.f)
  float v = 4.f*MEANV(py,px) - MEANV(py-1,px) - MEANV(py+1,px) - MEANV(py,px-1) - MEANV(py,px+1);
#undef MEANV
  xo[idx] = v;
}

// ---------- MFMA KxK conv 24->24 FUSED with 1x1 pw + mean/max. 48B records. ----------
// Separate sc scratch (no post-MFMA barrier). Mean map free via pw B column 24.
template<int K, bool EXPAND, bool INBF, bool OUTBF>
__launch_bounds__(512)
__global__ void k_conv_mfma(const void* in, const ushort_t* __restrict__ wb,
                            const ushort_t* __restrict__ wbpw, const float* __restrict__ wexp,
                            void* out, float* __restrict__ mm,
                            int H, int W, int istrIn, int istrOut, int istrMM){
  constexpr int SW_T = 32 + K - 1;
  constexpr int SH = 16 + K - 1;
  constexpr int NPX = SH*SW_T;
  __shared__ __align__(16) ushort_t lds[NPX*24];
  __shared__ uint_t sc[8][16*20];
  int tid = threadIdx.x;
  const float* inb_f = (const float*)in + (size_t)blockIdx.z*istrIn;
  const ushort_t* inb_b = (const ushort_t*)in + (size_t)blockIdx.z*istrIn;
  int x0g = blockIdx.x*32 - K/2, y0g = blockIdx.y*16 - K/2;
  int HW = H*W;
  for (int i = tid; i < NPX*3; i += 512){
    int q = i / NPX;
    int pp = i - q*NPX;
    int row = pp / SW_T, col = pp - row*SW_T;
    int gy = y0g + row, gx = x0g + col;
    uint4 w4; w4.x=0u; w4.y=0u; w4.z=0u; w4.w=0u;
    if (gy >= 0 && gy < H && gx >= 0 && gx < W){
      size_t base = (size_t)gy*W + gx;
      int c0 = q*8;
      if (EXPAND){
        float val = inb_f[base];
        w4.x = (uint_t)bf16r(val*wexp[c0+0]) | ((uint_t)bf16r(val*wexp[c0+1])<<16);
        w4.y = (uint_t)bf16r(val*wexp[c0+2]) | ((uint_t)bf16r(val*wexp[c0+3])<<16);
        w4.z = (uint_t)bf16r(val*wexp[c0+4]) | ((uint_t)bf16r(val*wexp[c0+5])<<16);
        w4.w = (uint_t)bf16r(val*wexp[c0+6]) | ((uint_t)bf16r(val*wexp[c0+7])<<16);
      } else if (INBF){
        uint_t u0=inb_b[(size_t)(c0+0)*HW+base], u1=inb_b[(size_t)(c0+1)*HW+base];
        uint_t u2=inb_b[(size_t)(c0+2)*HW+base], u3=inb_b[(size_t)(c0+3)*HW+base];
        uint_t u4=inb_b[(size_t)(c0+4)*HW+base], u5=inb_b[(size_t)(c0+5)*HW+base];
        uint_t u6=inb_b[(size_t)(c0+6)*HW+base], u7=inb_b[(size_t)(c0+7)*HW+base];
        w4.x = u0 | (u1<<16); w4.y = u2 | (u3<<16); w4.z = u4 | (u5<<16); w4.w = u6 | (u7<<16);
      } else {
        w4.x = (uint_t)bf16r(inb_f[(size_t)(c0+0)*HW+base]) | ((uint_t)bf16r(inb_f[(size_t)(c0+1)*HW+base])<<16);
        w4.y = (uint_t)bf16r(inb_f[(size_t)(c0+2)*HW+base]) | ((uint_t)bf16r(inb_f[(size_t)(c0+3)*HW+base])<<16);
        w4.z = (uint_t)bf16r(inb_f[(size_t)(c0+4)*HW+base]) | ((uint_t)bf16r(inb_f[(size_t)(c0+5)*HW+base])<<16);
        w4.w = (uint_t)bf16r(inb_f[(size_t)(c0+6)*HW+base]) | ((uint_t)bf16r(inb_f[(size_t)(c0+7)*HW+base])<<16);
      }
    }
    *(uint4*)(lds + (size_t)pp*24 + q*8) = w4;
  }
  __syncthreads();
  int l = tid & 63, wid = tid >> 6;
  int kg = l >> 4, li = l & 15;
  int kgc = (kg < 3) ? kg : 2;
  f32x4 zero = {0.f,0.f,0.f,0.f};
  f32x4 acc[4][2];
  #pragma unroll
  for (int i=0;i<4;i++){ acc[i][0]=zero; acc[i][1]=zero; }

  const ushort_t* aln = lds + li*24 + kgc*8 + (size_t)wid*SW_T*24;

  #pragma unroll
  for (int ky=0; ky<K; ky++){
    #pragma unroll
    for (int kx=0; kx<K; kx++){
      int tap = ky*K + kx;
      const ushort_t* wp = wb + (size_t)tap*1024;
      short8v b0 = *(const short8v*)(wp + l*8);
      short8v b1 = *(const short8v*)(wp + 512 + l*8);
      #pragma unroll
      for (int i=0;i<4;i++){
        const ushort_t* ap = aln + (((i&1)*8 + ky)*SW_T + (i>>1)*16 + kx)*24;
        short8v a = *(const short8v*)ap;
        acc[i][0] = __builtin_amdgcn_mfma_f32_16x16x32_bf16(a, b0, acc[i][0], 0, 0, 0);
        acc[i][1] = __builtin_amdgcn_mfma_f32_16x16x32_bf16(a, b1, acc[i][1], 0, 0, 0);
      }
    }
  }
  // ---- stage 2: pw 1x1 via second MFMA, + mean/max ----
  short8v bpw0 = *(const short8v*)(wbpw + l*8);
  short8v bpw1 = *(const short8v*)(wbpw + 512 + l*8);
  uint_t* s = sc[wid];
  float* outb_f = (float*)out + (size_t)blockIdx.z*istrOut;
  ushort_t* outb_b = (ushort_t*)out + (size_t)blockIdx.z*istrOut;
  float* mmb = mm + (size_t)blockIdx.z*istrMM;
  #pragma unroll 1
  for (int i=0;i<4;i++){
    __asm__ volatile("s_waitcnt lgkmcnt(0)" ::: "memory");
    __builtin_amdgcn_sched_barrier(0);
    #pragma unroll
    for (int reg=0; reg<4; reg++){
      float v0 = acc[i][0][reg], v1 = acc[i][1][reg];
      float v0n = __shfl_xor(v0, 1, 64);
      float v1n = __shfl_xor(v1, 1, 64);
      int pxr = kg*4 + reg;
      uint_t packed; int uidx;
      if ((li & 1) == 0){
        packed = (uint_t)bf16r(v0) | ((uint_t)bf16r(v0n) << 16);
        uidx = li >> 1;
      } else {
        packed = (uint_t)bf16r(v1n) | ((uint_t)bf16r(v1) << 16);
        uidx = 8 + (li >> 1);
      }
      s[pxr*20 + uidx] = packed;
    }
    __asm__ volatile("s_waitcnt lgkmcnt(0)" ::: "memory");
    __builtin_amdgcn_sched_barrier(0);
    short8v a2 = *(const short8v*)((const ushort_t*)s + li*40 + kg*8);
    f32x4 d0 = __builtin_amdgcn_mfma_f32_16x16x32_bf16(a2, bpw0, zero, 0, 0, 0);
    f32x4 d1 = __builtin_amdgcn_mfma_f32_16x16x32_bf16(a2, bpw1, zero, 0, 0, 0);
    int gy = blockIdx.y*16 + wid + (i&1)*8;
    int gx = blockIdx.x*32 + (i>>1)*16 + kg*4;
    if (OUTBF){
      uint2 p0; p0.x = (uint_t)bf16r(d0[0]) | ((uint_t)bf16r(d0[1])<<16);
      p0.y = (uint_t)bf16r(d0[2]) | ((uint_t)bf16r(d0[3])<<16);
      *(uint2*)(outb_b + (size_t)li*HW + (size_t)gy*W + gx) = p0;
      if (li < 8){
        uint2 p1; p1.x = (uint_t)bf16r(d1[0]) | ((uint_t)bf16r(d1[1])<<16);
        p1.y = (uint_t)bf16r(d1[2]) | ((uint_t)bf16r(d1[3])<<16);
        *(uint2*)(outb_b + (size_t)(16+li)*HW + (size_t)gy*W + gx) = p1;
      }
    } else {
      *(f32x4*)(outb_f + (size_t)li*HW + (size_t)gy*W + gx) = d0;
      if (li < 8)
        *(f32x4*)(outb_f + (size_t)(16+li)*HW + (size_t)gy*W + gx) = d1;
    }
    f32x4 mx;
    #pragma unroll
    for (int reg=0; reg<4; reg++)
      mx[reg] = fmaxf(d0[reg], (li<8) ? d1[reg] : -3.4e38f);
    #pragma unroll
    for (int m=1; m<16; m<<=1){
      #pragma unroll
      for (int reg=0; reg<4; reg++)
        mx[reg] = fmaxf(mx[reg], __shfl_xor(mx[reg], m, 64));
    }
    if (li == 8)
      *(f32x4*)(mmb + (size_t)gy*W + gx) = d1;           // col 24 = mean (pre-scaled)
    if (li == 0)
      *(f32x4*)(mmb + (size_t)HW + (size_t)gy*W + gx) = mx;
  }
}

// ---------- MFMA ConvTranspose2d(k=4,s=2,p=1), 32x16 out tile ----------
template<bool INBF, bool OUTBF>
__launch_bounds__(512)
__global__ void k_convT_mfma(const void* in, const ushort_t* __restrict__ wb,
                             void* out, int Ho, int Wo, int istrIn, int istrOut){
  const int Hi = Ho>>1, Wi = Wo>>1;
  constexpr int SW_T = 18, NPX = 180;
  __shared__ __align__(16) ushort_t lds[NPX*24];
  int tid = threadIdx.x;
  const float* inb_f = (const float*)in + (size_t)blockIdx.z*istrIn;
  const ushort_t* inb_b = (const ushort_t*)in + (size_t)blockIdx.z*istrIn;
  int X0 = blockIdx.x*32, Y0 = blockIdx.y*16;
  int ix0 = (X0>>1) - 1, iy0 = (Y0>>1) - 1;
  int HWi = Hi*Wi;
  for (int i = tid; i < NPX*3; i += 512){
    int q = i / NPX;
    int pp = i - q*NPX;
    int row = pp / SW_T, col = pp - row*SW_T;
    int gy = iy0 + row, gx = ix0 + col;
    uint4 w4; w4.x=0u; w4.y=0u; w4.z=0u; w4.w=0u;
    if (gy>=0 && gy<Hi && gx>=0 && gx<Wi){
      size_t base = (size_t)gy*Wi + gx;
      int c0 = q*8;
      if (INBF){
        uint_t u0=inb_b[(size_t)(c0+0)*HWi+base], u1=inb_b[(size_t)(c0+1)*HWi+base];
        uint_t u2=inb_b[(size_t)(c0+2)*HWi+base], u3=inb_b[(size_t)(c0+3)*HWi+base];
        uint_t u4=inb_b[(size_t)(c0+4)*HWi+base], u5=inb_b[(size_t)(c0+5)*HWi+base];
        uint_t u6=inb_b[(size_t)(c0+6)*HWi+base], u7=inb_b[(size_t)(c0+7)*HWi+base];
        w4.x = u0 | (u1<<16); w4.y = u2 | (u3<<16); w4.z = u4 | (u5<<16); w4.w = u6 | (u7<<16);
      } else {
        w4.x = (uint_t)bf16r(inb_f[(size_t)(c0+0)*HWi+base]) | ((uint_t)bf16r(inb_f[(size_t)(c0+1)*HWi+base])<<16);
        w4.y = (uint_t)bf16r(inb_f[(size_t)(c0+2)*HWi+base]) | ((uint_t)bf16r(inb_f[(size_t)(c0+3)*HWi+base])<<16);
        w4.z = (uint_t)bf16r(inb_f[(size_t)(c0+4)*HWi+base]) | ((uint_t)bf16r(inb_f[(size_t)(c0+5)*HWi+base])<<16);
        w4.w = (uint_t)bf16r(inb_f[(size_t)(c0+6)*HWi+base]) | ((uint_t)bf16r(inb_f[(size_t)(c0+7)*HWi+base])<<16);
      }
    }
    *(uint4*)(lds + (size_t)pp*24 + q*8) = w4;
  }
  __syncthreads();
  int l = tid & 63, wid = tid >> 6;
  int kg = l >> 4, li = l & 15;
  int kgc = (kg < 3) ? kg : 2;
  f32x4 zero = {0.f,0.f,0.f,0.f};
  f32x4 acc[4][2];
  #pragma unroll
  for (int i=0;i<4;i++){ acc[i][0]=zero; acc[i][1]=zero; }

  const ushort_t* aln = lds + li*24 + kgc*8;

  #pragma unroll
  for (int i=0;i<4;i++){
    int g = wid + 8*i;
    int r = g & 15, q = g >> 4;
    int ky0 = (r+1)&1;
    #pragma unroll
    for (int t2=0;t2<2;t2++){
      int ky = ky0 + 2*t2;
      int liy = ((r+1-ky)>>1) + 1;
      #pragma unroll
      for (int u=0;u<2;u++){
        int kx = (q ? 0 : 1) + 2*u;
        int lixb = ((q+1-kx)>>1) + 1;
        int tap = ky*4 + kx;
        const ushort_t* wp = wb + (size_t)tap*1024;
        short8v b0 = *(const short8v*)(wp + l*8);
        short8v b1 = *(const short8v*)(wp + 512 + l*8);
        short8v a = *(const short8v*)(aln + (liy*SW_T + lixb)*24);
        acc[i][0] = __builtin_amdgcn_mfma_f32_16x16x32_bf16(a, b0, acc[i][0], 0, 0, 0);
        acc[i][1] = __builtin_amdgcn_mfma_f32_16x16x32_bf16(a, b1, acc[i][1], 0, 0, 0);
      }
    }
  }
  float* outb_f = (float*)out + (size_t)blockIdx.z*istrOut;
  ushort_t* outb_b = (ushort_t*)out + (size_t)blockIdx.z*istrOut;
  int HWo = Ho*Wo;
  #pragma unroll
  for (int i=0;i<4;i++){
    int g = wid + 8*i;
    int r = g & 15, q = g >> 4;
    int oy = Y0 + r;
    #pragma unroll
    for (int reg=0; reg<4; reg++){
      int ox = X0 + 2*(kg*4 + reg) + q;
      if (OUTBF){
        outb_b[(size_t)li*HWo + (size_t)oy*Wo + ox] = bf16r(acc[i][0][reg]);
        if (li < 8)
          outb_b[(size_t)(16+li)*HWo + (size_t)oy*Wo + ox] = bf16r(acc[i][1][reg]);
      } else {
        outb_f[(size_t)li*HWo + (size_t)oy*Wo + ox] = acc[i][0][reg];
        if (li < 8)
          outb_f[(size_t)(16+li)*HWo + (size_t)oy*Wo + ox] = acc[i][1][reg];
      }
    }
  }
}

// ---------- MFMA 4x4 s2 p1 downsample, 16x8 out tile ----------
template<bool INBF, bool OUTBF>
__launch_bounds__(512)
__global__ void k_down_mfma(const void* in, const ushort_t* __restrict__ wb,
                            void* out, int Ho, int Wo, int istrIn, int istrOut){
  const int Hi = Ho*2, Wi = Wo*2;
  constexpr int NPX = 18*34;
  __shared__ __align__(16) ushort_t lds[NPX*24];
  int tid = threadIdx.x;
  const float* inb_f = (const float*)in + (size_t)blockIdx.z*istrIn;
  const ushort_t* inb_b = (const ushort_t*)in + (size_t)blockIdx.z*istrIn;
  int X0 = blockIdx.x*16, Y0 = blockIdx.y*8;
  int ix0 = 2*X0 - 1, iy0 = 2*Y0 - 1;
  int HWi = Hi*Wi;
  for (int i = tid; i < NPX*3; i += 512){
    int q = i / NPX;
    int pp = i - q*NPX;
    int row = pp / 34;
    int rem = pp - row*34;
    int par = (rem >= 17) ? 1 : 0;
    int sub = rem - par*17;
    int gx = ix0 + 2*sub + par;
    int gy = iy0 + row;
    uint4 w4; w4.x=0u; w4.y=0u; w4.z=0u; w4.w=0u;
    if (gy>=0 && gy<Hi && gx>=0 && gx<Wi){
      size_t base = (size_t)gy*Wi + gx;
      int c0 = q*8;
      if (INBF){
        uint_t u0=inb_b[(size_t)(c0+0)*HWi+base], u1=inb_b[(size_t)(c0+1)*HWi+base];
        uint_t u2=inb_b[(size_t)(c0+2)*HWi+base], u3=inb_b[(size_t)(c0+3)*HWi+base];
        uint_t u4=inb_b[(size_t)(c0+4)*HWi+base], u5=inb_b[(size_t)(c0+5)*HWi+base];
        uint_t u6=inb_b[(size_t)(c0+6)*HWi+base], u7=inb_b[(size_t)(c0+7)*HWi+base];
        w4.x = u0 | (u1<<16); w4.y = u2 | (u3<<16); w4.z = u4 | (u5<<16); w4.w = u6 | (u7<<16);
      } else {
        w4.x = (uint_t)bf16r(inb_f[(size_t)(c0+0)*HWi+base]) | ((uint_t)bf16r(inb_f[(size_t)(c0+1)*HWi+base])<<16);
        w4.y = (uint_t)bf16r(inb_f[(size_t)(c0+2)*HWi+base]) | ((uint_t)bf16r(inb_f[(size_t)(c0+3)*HWi+base])<<16);
        w4.z = (uint_t)bf16r(inb_f[(size_t)(c0+4)*HWi+base]) | ((uint_t)bf16r(inb_f[(size_t)(c0+5)*HWi+base])<<16);
        w4.w = (uint_t)bf16r(inb_f[(size_t)(c0+6)*HWi+base]) | ((uint_t)bf16r(inb_f[(size_t)(c0+7)*HWi+base])<<16);
      }
    }
    *(uint4*)(lds + (size_t)pp*24 + q*8) = w4;
  }
  __syncthreads();
  int l = tid & 63, wid = tid >> 6;
  int kg = l >> 4, li = l & 15;
  int kgc = (kg < 3) ? kg : 2;
  f32x4 zero = {0.f,0.f,0.f,0.f};
  f32x4 acc0 = zero, acc1 = zero;
  const ushort_t* aln = lds + li*24 + kgc*8 + (size_t)(2*wid)*34*24;
  #pragma unroll
  for (int ky=0; ky<4; ky++){
    #pragma unroll
    for (int kx=0; kx<4; kx++){
      int tap = ky*4 + kx;
      const ushort_t* wp = wb + (size_t)tap*1024;
      short8v b0 = *(const short8v*)(wp + l*8);
      short8v b1 = *(const short8v*)(wp + 512 + l*8);
      short8v a = *(const short8v*)(aln + (ky*34 + (kx&1)*17 + (kx>>1))*24);
      acc0 = __builtin_amdgcn_mfma_f32_16x16x32_bf16(a, b0, acc0, 0, 0, 0);
      acc1 = __builtin_amdgcn_mfma_f32_16x16x32_bf16(a, b1, acc1, 0, 0, 0);
    }
  }
  int HWo = Ho*Wo;
  int oy = Y0 + wid, ox = X0 + kg*4;
  if (OUTBF){
    ushort_t* outb = (ushort_t*)out + (size_t)blockIdx.z*istrOut;
    uint2 p0; p0.x = (uint_t)bf16r(acc0[0]) | ((uint_t)bf16r(acc0[1])<<16);
    p0.y = (uint_t)bf16r(acc0[2]) | ((uint_t)bf16r(acc0[3])<<16);
    *(uint2*)(outb + (size_t)li*HWo + (size_t)oy*Wo + ox) = p0;
    if (li < 8){
      uint2 p1; p1.x = (uint_t)bf16r(acc1[0]) | ((uint_t)bf16r(acc1[1])<<16);
      p1.y = (uint_t)bf16r(acc1[2]) | ((uint_t)bf16r(acc1[3])<<16);
      *(uint2*)(outb + (size_t)(16+li)*HWo + (size_t)oy*Wo + ox) = p1;
    }
  } else {
    float* outb = (float*)out + (size_t)blockIdx.z*istrOut;
    *(f32x4*)(outb + (size_t)li*HWo + (size_t)oy*Wo + ox) = acc0;
    if (li < 8)
      *(f32x4*)(outb + (size_t)(16+li)*HWo + (size_t)oy*Wo + ox) = acc1;
  }
}

// spatial attn + sigmoid + relu + residual add; BF: R/X/out are bf16 planes
template<bool BF>
__global__ void k_attn_res(const void* R_, const float* __restrict__ M,
                           const void* X_, const float* __restrict__ wsa,
                           void* out_, int H, int W, int istr, int istrMM){
  int p = (blockIdx.x*256 + threadIdx.x)*4;
  int HW = H*W;
  if (p >= HW) return;
  int py = p / W, px0 = p % W;
  const float* Mb = M + (size_t)blockIdx.z*istrMM;
  float s[4]={0,0,0,0};
  #pragma unroll
  for (int cc=0;cc<2;cc++){
    const float* Mc = Mb + (size_t)cc*HW;
    #pragma unroll 1
    for (int ky=0;ky<7;ky++){
      int gy = py+ky-3;
      if (gy<0||gy>=H) continue;
      const float* mr = Mc + (size_t)gy*W;
      float mv[10];
      #pragma unroll
      for (int j=0;j<10;j++){
        int gx = px0-3+j;
        mv[j] = (gx>=0 && gx<W) ? mr[gx] : 0.f;
      }
      const float* wr = wsa + (cc*7+ky)*7;
      #pragma unroll
      for (int kx=0;kx<7;kx++){
        float wv = wr[kx];
        #pragma unroll
        for (int px=0;px<4;px++) s[px] = fmaf(mv[kx+px], wv, s[px]);
      }
    }
  }
  float g[4];
  #pragma unroll
  for (int px=0;px<4;px++) g[px] = 1.f/(1.f+expf(-s[px]));
  #pragma unroll
  for (int c=0;c<CH;c++){
    float r0,r1,r2,r3, x0v,x1v,x2v,x3v;
    if (BF){
      const ushort_t* Rb = (const ushort_t*)R_ + (size_t)blockIdx.z*istr + (size_t)c*HW + p;
      const ushort_t* Xb = (const ushort_t*)X_ + (size_t)blockIdx.z*istr + (size_t)c*HW + p;
      uint2 rv = *(const uint2*)Rb;
      uint2 xv = *(const uint2*)Xb;
      r0=bf2f(rv.x&0xffffu); r1=bf2f(rv.x>>16); r2=bf2f(rv.y&0xffffu); r3=bf2f(rv.y>>16);
      x0v=bf2f(xv.x&0xffffu); x1v=bf2f(xv.x>>16); x2v=bf2f(xv.y&0xffffu); x3v=bf2f(xv.y>>16);
    } else {
      const float* Rb = (const float*)R_ + (size_t)blockIdx.z*istr + (size_t)c*HW + p;
      const float* Xb = (const float*)X_ + (size_t)blockIdx.z*istr + (size_t)c*HW + p;
      float4 rv = *(const float4*)Rb;
      float4 xv = *(const float4*)Xb;
      r0=rv.x; r1=rv.y; r2=rv.z; r3=rv.w;
      x0v=xv.x; x1v=xv.y; x2v=xv.z; x3v=xv.w;
    }
    float o0 = x0v + fmaxf(r0*g[0], 0.f);
    float o1 = x1v + fmaxf(r1*g[1], 0.f);
    float o2 = x2v + fmaxf(r2*g[2], 0.f);
    float o3 = x3v + fmaxf(r3*g[3], 0.f);
    if (BF){
      ushort_t* Ob = (ushort_t*)out_ + (size_t)blockIdx.z*istr + (size_t)c*HW + p;
      uint2 ov;
      ov.x = (uint_t)bf16r(o0) | ((uint_t)bf16r(o1)<<16);
      ov.y = (uint_t)bf16r(o2) | ((uint_t)bf16r(o3)<<16);
      *(uint2*)Ob = ov;
    } else {
      float* Ob = (float*)out_ + (size_t)blockIdx.z*istr + (size_t)c*HW + p;
      float4 ov; ov.x=o0; ov.y=o1; ov.z=o2; ov.w=o3;
      *(float4*)Ob = ov;
    }
  }
}

// variant: residual computed from XL*wexp; BF: R/out bf16
template<bool BF>
__global__ void k_attn_res_x(const void* R_, const float* __restrict__ M,
                             const float* __restrict__ XL, const float* __restrict__ wsa,
                             const float* __restrict__ wexp,
                             void* out_, int H, int W, int istr, int istrMM){
  int p = (blockIdx.x*256 + threadIdx.x)*4;
  int HW = H*W;
  if (p >= HW) return;
  int py = p / W, px0 = p % W;
  const float* Mb = M + (size_t)blockIdx.z*istrMM;
  float s[4]={0,0,0,0};
  #pragma unroll
  for (int cc=0;cc<2;cc++){
    const float* Mc = Mb + (size_t)cc*HW;
    #pragma unroll 1
    for (int ky=0;ky<7;ky++){
      int gy = py+ky-3;
      if (gy<0||gy>=H) continue;
      const float* mr = Mc + (size_t)gy*W;
      float mv[10];
      #pragma unroll
      for (int j=0;j<10;j++){
        int gx = px0-3+j;
        mv[j] = (gx>=0 && gx<W) ? mr[gx] : 0.f;
      }
      const float* wr = wsa + (cc*7+ky)*7;
      #pragma unroll
      for (int kx=0;kx<7;kx++){
        float wv = wr[kx];
        #pragma unroll
        for (int px=0;px<4;px++) s[px] = fmaf(mv[kx+px], wv, s[px]);
      }
    }
  }
  float g[4];
  #pragma unroll
  for (int px=0;px<4;px++) g[px] = 1.f/(1.f+expf(-s[px]));
  float4 xl4 = *(const float4*)(XL + (size_t)blockIdx.z*HW + p);
  #pragma unroll
  for (int c=0;c<CH;c++){
    float wc = wexp[c];
    float r0,r1,r2,r3;
    if (BF){
      const ushort_t* Rb = (const ushort_t*)R_ + (size_t)blockIdx.z*istr + (size_t)c*HW + p;
      uint2 rv = *(const uint2*)Rb;
      r0=bf2f(rv.x&0xffffu); r1=bf2f(rv.x>>16); r2=bf2f(rv.y&0xffffu); r3=bf2f(rv.y>>16);
    } else {
      const float* Rb = (const float*)R_ + (size_t)blockIdx.z*istr + (size_t)c*HW + p;
      float4 rv = *(const float4*)Rb;
      r0=rv.x; r1=rv.y; r2=rv.z; r3=rv.w;
    }
    float o0 = xl4.x*wc + fmaxf(r0*g[0], 0.f);
    float o1 = xl4.y*wc + fmaxf(r1*g[1], 0.f);
    float o2 = xl4.z*wc + fmaxf(r2*g[2], 0.f);
    float o3 = xl4.w*wc + fmaxf(r3*g[3], 0.f);
    if (BF){
      ushort_t* Ob = (ushort_t*)out_ + (size_t)blockIdx.z*istr + (size_t)c*HW + p;
      uint2 ov;
      ov.x = (uint_t)bf16r(o0) | ((uint_t)bf16r(o1)<<16);
      ov.y = (uint_t)bf16r(o2) | ((uint_t)bf16r(o3)<<16);
      *(uint2*)Ob = ov;
    } else {
      float* Ob = (float*)out_ + (size_t)blockIdx.z*istr + (size_t)c*HW + p;
      float4 ov; ov.x=o0; ov.y=o1; ov.z=o2; ov.w=o3;
      *(float4*)Ob = ov;
    }
  }
}

// FUSED attn_res(dt) + final
__global__ void k_attn_final(const ushort_t* __restrict__ R, const float* __restrict__ M,
                             const ushort_t* __restrict__ X, const float* __restrict__ wsa,
                             const float* __restrict__ wout, const float* __restrict__ xl,
                             float* __restrict__ outMask, float* __restrict__ outClean,
                             int H, int W, int istr, int istrMM){
  int p = (blockIdx.x*256 + threadIdx.x)*4;
  int HW = H*W;
  if (p >= HW) return;
  int py = p / W, px0 = p % W;
  const float* Mb = M + (size_t)blockIdx.z*istrMM;
  float s[4]={0,0,0,0};
  #pragma unroll
  for (int cc=0;cc<2;cc++){
    const float* Mc = Mb + (size_t)cc*HW;
    #pragma unroll 1
    for (int ky=0;ky<7;ky++){
      int gy = py+ky-3;
      if (gy<0||gy>=H) continue;
      const float* mr = Mc + (size_t)gy*W;
      float mv[10];
      #pragma unroll
      for (int j=0;j<10;j++){
        int gx = px0-3+j;
        mv[j] = (gx>=0 && gx<W) ? mr[gx] : 0.f;
      }
      const float* wr = wsa + (cc*7+ky)*7;
      #pragma unroll
      for (int kx=0;kx<7;kx++){
        float wv = wr[kx];
        #pragma unroll
        for (int px=0;px<4;px++) s[px] = fmaf(mv[kx+px], wv, s[px]);
      }
    }
  }
  float g[4];
  #pragma unroll
  for (int px=0;px<4;px++) g[px] = 1.f/(1.f+expf(-s[px]));
  float m0=0.f,m1=0.f,m2=0.f,m3=0.f;
  #pragma unroll
  for (int c=0;c<CH;c++){
    const ushort_t* Rb = R + (size_t)blockIdx.z*istr + (size_t)c*HW + p;
    const ushort_t* Xb = X + (size_t)blockIdx.z*istr + (size_t)c*HW + p;
    uint2 rv = *(const uint2*)Rb;
    uint2 xv = *(const uint2*)Xb;
    float wc = wout[c];
    float o0 = bf2f(xv.x&0xffffu) + fmaxf(bf2f(rv.x&0xffffu)*g[0], 0.f);
    float o1 = bf2f(xv.x>>16)     + fmaxf(bf2f(rv.x>>16)*g[1], 0.f);
    float o2 = bf2f(xv.y&0xffffu) + fmaxf(bf2f(rv.y&0xffffu)*g[2], 0.f);
    float o3 = bf2f(xv.y>>16)     + fmaxf(bf2f(rv.y>>16)*g[3], 0.f);
    m0 = fmaf(o0,wc,m0); m1 = fmaf(o1,wc,m1); m2 = fmaf(o2,wc,m2); m3 = fmaf(o3,wc,m3);
  }
  float4 xlv = *(const float4*)(xl + (size_t)blockIdx.z*HW + p);
  float4 mo; mo.x=m0; mo.y=m1; mo.z=m2; mo.w=m3;
  float4 co; co.x=xlv.x-m0; co.y=xlv.y-m1; co.z=xlv.z-m2; co.w=xlv.w-m3;
  *(float4*)(outMask + (size_t)blockIdx.z*HW + p) = mo;
  *(float4*)(outClean + (size_t)blockIdx.z*HW + p) = co;
}

// 1x1 conv 48->24 over concat(A,B); BF: all planes bf16
template<bool BF>
__global__ void k_squeeze(const void* inA_, const void* inB_,
                          const float* __restrict__ wT, void* out_, int HW, int istr){
  int p = (blockIdx.x*256 + threadIdx.x)*4;
  if (p >= HW) return;
  float acc[CH][4];
  #pragma unroll
  for (int co=0;co<CH;co++){ acc[co][0]=0;acc[co][1]=0;acc[co][2]=0;acc[co][3]=0; }
  #pragma unroll 1
  for (int ci=0;ci<48;ci++){
    float v0,v1,v2,v3;
    if (BF){
      const ushort_t* src = (ci<24)
        ? ((const ushort_t*)inA_ + (size_t)blockIdx.z*istr + (size_t)ci*HW + p)
        : ((const ushort_t*)inB_ + (size_t)blockIdx.z*istr + (size_t)(ci-24)*HW + p);
      uint2 rv = *(const uint2*)src;
      v0=bf2f(rv.x&0xffffu); v1=bf2f(rv.x>>16); v2=bf2f(rv.y&0xffffu); v3=bf2f(rv.y>>16);
    } else {
      const float* src = (ci<24)
        ? ((const float*)inA_ + (size_t)blockIdx.z*istr + (size_t)ci*HW + p)
        : ((const float*)inB_ + (size_t)blockIdx.z*istr + (size_t)(ci-24)*HW + p);
      float4 rv = *(const float4*)src;
      v0=rv.x; v1=rv.y; v2=rv.z; v3=rv.w;
    }
    const float* wp = wT + ci*24;
    #pragma unroll
    for (int co=0;co<CH;co++){
      float wv = wp[co];
      acc[co][0] = fmaf(v0, wv, acc[co][0]);
      acc[co][1] = fmaf(v1, wv, acc[co][1]);
      acc[co][2] = fmaf(v2, wv, acc[co][2]);
      acc[co][3] = fmaf(v3, wv, acc[co][3]);
    }
  }
  #pragma unroll
  for (int co=0;co<CH;co++){
    if (BF){
      ushort_t* ob = (ushort_t*)out_ + (size_t)blockIdx.z*istr + (size_t)co*HW + p;
      uint2 ov;
      ov.x = (uint_t)bf16r(acc[co][0]) | ((uint_t)bf16r(acc[co][1])<<16);
      ov.y = (uint_t)bf16r(acc[co][2]) | ((uint_t)bf16r(acc[co][3])<<16);
      *(uint2*)ob = ov;
    } else {
      float* ob = (float*)out_ + (size_t)blockIdx.z*istr + (size_t)co*HW + p;
      float4 o; o.x=acc[co][0]; o.y=acc[co][1]; o.z=acc[co][2]; o.w=acc[co][3];
      *(float4*)ob = o;
    }
  }
}

__global__ void k_quant(const float* __restrict__ enc, const float* __restrict__ embed,
                        float* __restrict__ qt, float* __restrict__ diffAcc, int HW, int istr){
  __shared__ float em[256*28];
  __shared__ float red[4];
  {
    int j = threadIdx.x;
    float s = 0.f;
    #pragma unroll
    for (int c=0;c<CH;c++){
      float e = embed[c*256+j];
      em[j*28+c] = -2.0f*e;
      s = fmaf(e,e,s);
    }
    em[j*28+24] = s; em[j*28+25]=0.f; em[j*28+26]=0.f; em[j*28+27]=0.f;
  }
  __syncthreads();
  int p = blockIdx.x*256 + threadIdx.x;
  const float* eb = enc + (size_t)blockIdx.z*istr;
  float f[CH];
  #pragma unroll
  for (int c=0;c<CH;c++) f[c] = eb[(size_t)c*HW + p];
  float best = 3.4e38f; int bj = 0;
  #pragma unroll 1
  for (int j=0;j<256;j++){
    const float4* row = (const float4*)&em[j*28];
    float s = em[j*28+24];
    #pragma unroll
    for (int q4=0;q4<6;q4++){
      float4 r = row[q4];
      s = fmaf(f[q4*4+0], r.x, s);
      s = fmaf(f[q4*4+1], r.y, s);
      s = fmaf(f[q4*4+2], r.z, s);
      s = fmaf(f[q4*4+3], r.w, s);
    }
    if (s < best){ best = s; bj = j; }
  }
  float* qb = qt + (size_t)blockIdx.z*istr;
  float d = 0.f;
  #pragma unroll
  for (int c=0;c<CH;c++){
    float q = embed[c*256+bj];
    qb[(size_t)c*HW + p] = q;
    float e = q - f[c];
    d = fmaf(e,e,d);
  }
  #pragma unroll
  for (int off=32; off>0; off>>=1) d += __shfl_down(d, off, 64);
  int lane = threadIdx.x & 63, wv = threadIdx.x >> 6;
  if (lane==0) red[wv] = d;
  __syncthreads();
  if (threadIdx.x==0) atomicAdd(diffAcc, red[0]+red[1]+red[2]+red[3]);
}

__global__ void k_diff(const float* __restrict__ acc, float* __restrict__ out){
  out[0] = acc[0]*(1.f/3145728.f) + acc[1]*(1.f/786432.f);
}

// =======================================================================
extern "C" void kernel_launch(void* const* d_in, const int* in_sizes, int n_in,
                              void* d_out, int out_size, void* d_ws, size_t ws_size,
                              hipStream_t stream) {
  const float* x        = (const float*)d_in[0];
  const float* embed2   = (const float*)d_in[1];
  const float* embed3   = (const float*)d_in[2];
  const float* w_img_in = (const float*)d_in[3];
  const float* w_img_out= (const float*)d_in[4];
  const float* w_out_dd = (const float*)d_in[5];
  const float* w_out_dm = (const float*)d_in[6];
  const float* w_out_dt = (const float*)d_in[7];
  const float* w_out_ed = (const float*)d_in[8];
  const float* w_out_em = (const float*)d_in[9];
  const float* w_out_et = (const float*)d_in[10];
  const float* w_pw_dd  = (const float*)d_in[11];
  const float* w_pw_dm  = (const float*)d_in[12];
  const float* w_pw_dt  = (const float*)d_in[13];
  const float* w_pw_ed  = (const float*)d_in[14];
  const float* w_pw_em  = (const float*)d_in[15];
  const float* w_pw_et  = (const float*)d_in[16];
  const float* w_res_dd = (const float*)d_in[17];
  const float* w_res_dm = (const float*)d_in[18];
  const float* w_res_dt = (const float*)d_in[19];
  const float* w_res_ed = (const float*)d_in[20];
  const float* w_res_em = (const float*)d_in[21];
  const float* w_res_et = (const float*)d_in[22];
  const float* w_sa_dd  = (const float*)d_in[23];
  const float* w_sa_dm  = (const float*)d_in[24];
  const float* w_sa_dt  = (const float*)d_in[25];
  const float* w_sa_ed  = (const float*)d_in[26];
  const float* w_sa_em  = (const float*)d_in[27];
  const float* w_sa_et  = (const float*)d_in[28];
  const float* w_squ1   = (const float*)d_in[29];
  const float* w_squ2   = (const float*)d_in[30];
  (void)in_sizes; (void)n_in; (void)out_size;

  const int HW512 = 512*512, HW256 = 256*256, HW128 = 128*128, HW64 = 64*64;
  const int S512 = 24*HW512, S256 = 24*HW256, S128 = 24*HW128, S64 = 24*HW64;

  float* ws = (float*)d_ws;
  float* OUT = (float*)d_out;
  size_t F = ws_size / sizeof(float);

  float* WT      = ws;
  float* wt_squ1 = WT + 154368;
  float* wt_squ2 = WT + 155520;

  ushort_t* WB = (ushort_t*)(ws + 160000);
  ushort_t* wb_et7   = WB;
  ushort_t* wb_dt7   = WB + 50176;
  ushort_t* wb_em5   = WB + 100352;
  ushort_t* wb_dm5   = WB + 125952;
  ushort_t* wb_pw_et = WB + 151552;
  ushort_t* wb_pw_em = WB + 152576;
  ushort_t* wb_pw_dm = WB + 153600;
  ushort_t* wb_pw_dt = WB + 154624;
  ushort_t* wb4_dd   = WB + 155648;
  ushort_t* wb4_dm   = WB + 172032;
  ushort_t* wb4_dt   = WB + 188416;
  ushort_t* wb4d_et  = WB + 204800;
  ushort_t* wb4d_em  = WB + 221184;
  ushort_t* wb4d_ed  = WB + 237568;
  ushort_t* wb_ed3   = WB + 253952;
  ushort_t* wb_dd3   = WB + 263168;
  ushort_t* wb_pw_ed = WB + 272384;
  ushort_t* wb_pw_dd = WB + 273408;

  const size_t ABASE = 300000;

  auto needBatched = [&](size_t CB)->size_t{
    size_t u_f = (CB*(size_t)S512 + 1)/2;
    if ((size_t)4*S256 > u_f) u_f = (size_t)4*S256;
    if ((size_t)8*S128 > u_f) u_f = (size_t)8*S128;
    return ABASE + 2097152 + (size_t)4*S256 + 3145728 + 786432 + CB*524288 + 2*u_f + 2;
  };
  int CB = 0;
  if (F >= needBatched(8)) CB = 8;
  else if (F >= needBatched(4)) CB = 4;
  else if (F >= needBatched(2)) CB = 2;
  const size_t NEED_B = ABASE + 15925250;
  if (CB == 0 && F < NEED_B) return;

  float *XL, *E2, *Q2, *E3, *Q3, *MM, *DIFF, *U1, *U2;
  ushort_t* E1b;
  if (CB > 0){
    size_t off = ABASE;
    size_t u_f = (CB*(size_t)S512 + 1)/2;
    if ((size_t)4*S256 > u_f) u_f = (size_t)4*S256;
    if ((size_t)8*S128 > u_f) u_f = (size_t)8*S128;
    XL = ws + off; off += 2097152;
    E1b = (ushort_t*)(ws + off); off += (size_t)4*S256;
    Q2 = ws + off; off += 3145728;
    Q3 = ws + off; off += 786432;
    MM = ws + off; off += CB*524288;
    U1 = ws + off; off += u_f;
    U2 = ws + off; off += u_f;
    DIFF = ws + off;
    E2 = OUT;
    E3 = OUT + 3145728;
  } else {
    size_t off = ABASE;
    XL = ws + off; off += 262144;
    U1 = ws + off; off += 6291456;
    U2 = ws + off; off += 6291456;
    E1b = (ushort_t*)(ws + off); off += 1572864;
    E2 = ws + off; off += 393216;
    Q2 = ws + off; off += 393216;
    E3 = ws + off; off += 98304;
    Q3 = ws + off; off += 98304;
    MM = ws + off; off += 524288;
    DIFF = ws + off;
  }
  ushort_t* U1b = (ushort_t*)U1;
  ushort_t* U2b = (ushort_t*)U2;

  // ---- merged weight reorder (single launch) ----
  WPtrs P;
  P.res_et=w_res_et; P.res_dt=w_res_dt; P.res_em=w_res_em; P.res_dm=w_res_dm;
  P.res_ed=w_res_ed; P.res_dd=w_res_dd;
  P.pw_et=w_pw_et; P.pw_em=w_pw_em; P.pw_dm=w_pw_dm; P.pw_dt=w_pw_dt;
  P.pw_ed=w_pw_ed; P.pw_dd=w_pw_dd;
  P.out_dd=w_out_dd; P.out_dm=w_out_dm; P.out_dt=w_out_dt;
  P.out_et=w_out_et; P.out_em=w_out_em; P.out_ed=w_out_ed;
  P.squ1=w_squ1; P.squ2=w_squ2;
  k_reorder<<<dim3(1082), 256, 0, stream>>>(P, WB, wt_squ1, wt_squ2);

  hipMemsetAsync(DIFF, 0, 2*sizeof(float), stream);

  // ---- phase 1: input -> enc1 (E1 bf16) ----
  auto phase1 = [&](int c0, int nz, float* XLp, ushort_t* E1p){
    k_lap<<<dim3(HW512/256,1,nz), 256, 0, stream>>>(x + (size_t)c0*3*HW512, XLp, 512, 512);
    k_conv_mfma<7,true,false,true><<<dim3(16,32,nz), 512, 0, stream>>>(
        XLp, wb_et7, wb_pw_et, w_img_in, U2b, MM, 512, 512, HW512, S512, 2*HW512);
    k_attn_res_x<true><<<dim3(HW512/1024,1,nz), 256, 0, stream>>>(
        U2b, MM, XLp, w_sa_et, w_img_in, U1b, 512, 512, S512, 2*HW512);
    k_down_mfma<true,true><<<dim3(16,32,nz), 512, 0, stream>>>(U1b, wb4d_et, E1p, 256, 256, S512, S256);
  };

  // ---- deep: enc1 -> squ1 output ----
  auto deep = [&](int nb, ushort_t* E1p, float* SAp, float* SBp, float* E2p, float* Q2p,
                  float* E3p, float* Q3p, float* MMp, ushort_t* D1p){
    ushort_t* SAb = (ushort_t*)SAp;
    ushort_t* SBb = (ushort_t*)SBp;
    int mm256 = 2*HW256, mm128 = 2*HW128;
    k_conv_mfma<5,false,true,true><<<dim3(8,16,nb), 512, 0, stream>>>(
        E1p, wb_em5, wb_pw_em, nullptr, SAb, MMp, 256, 256, S256, S256, mm256);
    k_attn_res<true><<<dim3(HW256/1024,1,nb), 256, 0, stream>>>(SAb, MMp, E1p, w_sa_em, SBb, 256, 256, S256, mm256);
    k_down_mfma<true,false><<<dim3(8,16,nb), 512, 0, stream>>>(SBb, wb4d_em, E2p, 128, 128, S256, S128);
    k_conv_mfma<3,false,false,false><<<dim3(4,8,nb), 512, 0, stream>>>(
        E2p, wb_ed3, wb_pw_ed, nullptr, SAp, MMp, 128, 128, S128, S128, mm128);
    k_attn_res<false><<<dim3(HW128/1024,1,nb), 256, 0, stream>>>(SAp, MMp, E2p, w_sa_ed, SBp, 128, 128, S128, mm128);
    k_down_mfma<false,false><<<dim3(4,8,nb), 512, 0, stream>>>(SBp, wb4d_ed, E3p, 64, 64, S128, S64);
    k_quant<<<dim3(HW128/256,1,nb), 256, 0, stream>>>(E2p, embed2, Q2p, DIFF+0, HW128, S128);
    k_quant<<<dim3(HW64/256,1,nb), 256, 0, stream>>>(E3p, embed3, Q3p, DIFF+1, HW64, S64);
    k_convT_mfma<false,false><<<dim3(4,8,nb), 512, 0, stream>>>(Q3p, wb4_dd, SAp, 128, 128, S64, S128);
    k_conv_mfma<3,false,false,false><<<dim3(4,8,nb), 512, 0, stream>>>(
        SAp, wb_dd3, wb_pw_dd, nullptr, SBp, MMp, 128, 128, S128, S128, mm128);
    k_attn_res<false><<<dim3(HW128/1024,1,nb), 256, 0, stream>>>(SBp, MMp, SAp, w_sa_dd, SAp, 128, 128, S128, mm128);
    k_squeeze<false><<<dim3(HW128/1024,1,nb), 256, 0, stream>>>(SAp, Q2p, wt_squ2, SBp, HW128, S128);
    k_convT_mfma<false,true><<<dim3(8,16,nb), 512, 0, stream>>>(SBp, wb4_dm, SAb, 256, 256, S128, S256);
    k_conv_mfma<5,false,true,true><<<dim3(8,16,nb), 512, 0, stream>>>(
        SAb, wb_dm5, wb_pw_dm, nullptr, SBb, MMp, 256, 256, S256, S256, mm256);
    k_attn_res<true><<<dim3(HW256/1024,1,nb), 256, 0, stream>>>(SBb, MMp, SAb, w_sa_dm, SAb, 256, 256, S256, mm256);
    k_squeeze<true><<<dim3(HW256/1024,1,nb), 256, 0, stream>>>(SAb, E1p, wt_squ1, D1p, HW256, S256);
  };

  // ---- phase 3: D1 (bf16) -> outputs ----
  auto phase3 = [&](int c0, int nz, const ushort_t* D1p, const float* XLp){
    k_convT_mfma<true,true><<<dim3(16,32,nz), 512, 0, stream>>>(D1p, wb4_dt, U1b, 512, 512, S256, S512);
    k_conv_mfma<7,false,true,true><<<dim3(16,32,nz), 512, 0, stream>>>(
        U1b, wb_dt7, wb_pw_dt, nullptr, U2b, MM, 512, 512, S512, S512, 2*HW512);
    k_attn_final<<<dim3(HW512/1024,1,nz), 256, 0, stream>>>(
        U2b, MM, U1b, w_sa_dt, w_img_out, XLp,
        OUT + (size_t)c0*HW512, OUT + 2097152 + (size_t)c0*HW512,
        512, 512, S512, 2*HW512);
  };

  if (CB > 0){
    for (int c0=0;c0<8;c0+=CB)
      phase1(c0, CB, XL + (size_t)c0*HW512, E1b + (size_t)c0*S256);
    deep(8, E1b, U1, U2, E2, Q2, E3, Q3, MM, E1b);
    for (int c0=0;c0<8;c0+=CB)
      phase3(c0, CB, E1b + (size_t)c0*S256, XL + (size_t)c0*HW512);
  } else {
    for (int b=0;b<8;b++){
      phase1(b, 1, XL, E1b);
      deep(1, E1b, U1, U2, E2, Q2, E3, Q3, MM, (ushort_t*)U2);
      phase3(b, 1, (ushort_t*)U2, XL);
    }
  }

  k_diff<<<1, 1, 0, stream>>>(DIFF, OUT + 4194304);
}